// Round 3
// baseline (3306.805 us; speedup 1.0000x reference)
//
#include <hip/hip_runtime.h>
#include <hip/hip_bf16.h>
#include <math.h>

#define Bb 8
#define Nn 2048
#define Ee 4096
#define Dd 256
#define HOPS 3

typedef __attribute__((ext_vector_type(4))) float f32x4;
typedef __attribute__((ext_vector_type(8))) short s16x8;
typedef __attribute__((ext_vector_type(4))) short s16x4;

__device__ __forceinline__ short f2bf(float f){
  union{float f; unsigned u;} x; x.f=f;
  unsigned r = (x.u + 0x7fffu + ((x.u>>16)&1u)) >> 16;
  return (short)r;
}
__device__ __forceinline__ float bf2f(short h){
  union{unsigned u; float f;} x; x.u = ((unsigned)(unsigned short)h) << 16; return x.f;
}

enum { AM_N=0, AM_T, AM_C2, AM_CN, AM_G4, AM_RC };
enum { EPI_NONE=0, EPI_RELUB, EPI_AGG, EPI_SIG, EPI_GATE, EPI_TANH };

#define LDK 40   // padded LDS k-stride (shorts): 80B rows, 16B-aligned b128 frag reads

// C[M,Nd] = A_eff[M,K] @ B_eff[K,Nd], bf16 MFMA, fp32 accum. 128x128 tile, 4 waves.
// SPLIT=true: bf16x3 split-precision (hi/lo) — err ~2^-18/term instead of 2^-9.
// AM_N: A [M,K] row-major (lda). AM_T: A stored [K,M] (lda = its row stride).
// AM_C2/CN: A_eff = concat(A,A2) along k (K=512), pitch 256.
// AM_G4: concat(A, A2, A*A2, A-A2) (K=1024). AM_RC: concat(A*A2, A3) (K=512).
// BW=true: B stored [Nd,K] row-major (weights). BW=false: B stored [K,Nd].
template<int AMODE, bool BW, bool SPLIT, int EPI>
__global__ __launch_bounds__(256) void gemm_kernel(
    const float* __restrict__ A, const float* __restrict__ A2, const float* __restrict__ A3,
    const float* __restrict__ Bm, float* __restrict__ C,
    const float* __restrict__ aux1, const float* __restrict__ aux2, const float* __restrict__ bias,
    int M, int Nd, int K, int lda, int ldb, int ldc,
    long sA, long sB, long sC, long sAux1, long sAux2)
{
  const int bz = blockIdx.z;
  A += bz * sA; Bm += bz * sB; C += bz * sC;
  if (aux1) aux1 += bz * sAux1;
  if (aux2) aux2 += bz * sAux2;
  const int m0 = blockIdx.y * 128;
  const int n0 = blockIdx.x * 128;

  constexpr int HL = 128 * LDK;
  __shared__ short As[128 * LDK * (SPLIT ? 2 : 1)];
  __shared__ short Bs[128 * LDK * (SPLIT ? 2 : 1)];

  const int tid = threadIdx.x;
  const int wid = tid >> 6, lane = tid & 63;
  const int wm = (wid >> 1) * 64, wn = (wid & 1) * 64;
  const int r = lane & 15, g = lane >> 4;

  f32x4 acc[4][4];
  #pragma unroll
  for (int i = 0; i < 4; i++)
    #pragma unroll
    for (int j = 0; j < 4; j++) acc[i][j] = (f32x4){0.f, 0.f, 0.f, 0.f};

  // store one f32x4 as bf16 hi (and lo residual if SPLIT)
  auto stq = [&](short* dst, f32x4 v) {
    s16x4 h = { f2bf(v.x), f2bf(v.y), f2bf(v.z), f2bf(v.w) };
    *(s16x4*)dst = h;
    if (SPLIT) {
      s16x4 l = { f2bf(v.x - bf2f(h.x)), f2bf(v.y - bf2f(h.y)),
                  f2bf(v.z - bf2f(h.z)), f2bf(v.w - bf2f(h.w)) };
      *(s16x4*)(dst + HL) = l;
    }
  };

  for (int k0 = 0; k0 < K; k0 += 32) {
    // ---- stage A -> As[m][k]
    if (AMODE == AM_N) {
      const int row = tid >> 1, kq = (tid & 1) * 16;
      const float* src = A + (long)(m0 + row) * lda + k0 + kq;
      #pragma unroll
      for (int u = 0; u < 4; u++)
        stq(&As[row * LDK + kq + 4 * u], *(const f32x4*)(src + 4 * u));
    } else if (AMODE == AM_T) {
      const int rr = tid & 127, kh = (tid >> 7) * 16;
      const float* src = A + (long)(k0 + kh) * lda + m0 + rr;
      short th[16], tl[16];
      #pragma unroll
      for (int j = 0; j < 16; j++) {
        float tv = src[(long)j * lda];
        th[j] = f2bf(tv);
        if (SPLIT) tl[j] = f2bf(tv - bf2f(th[j]));
      }
      #pragma unroll
      for (int q = 0; q < 4; q++) {
        *(s16x4*)&As[rr * LDK + kh + 4 * q] = (s16x4){ th[4*q], th[4*q+1], th[4*q+2], th[4*q+3] };
        if (SPLIT)
          *(s16x4*)&As[HL + rr * LDK + kh + 4 * q] = (s16x4){ tl[4*q], tl[4*q+1], tl[4*q+2], tl[4*q+3] };
      }
    } else {
      // fused feature staging: sources have pitch 256
      const int row = tid >> 1, kq = (tid & 1) * 16;
      const int kk = k0 + kq, q = kk >> 8, kd = kk & 255;
      const long base = (long)(m0 + row) * 256 + kd;
      #pragma unroll
      for (int u = 0; u < 4; u++) {
        f32x4 v;
        if (AMODE == AM_C2 || AMODE == AM_CN) {
          v = *(const f32x4*)((q == 0 ? A : A2) + base + 4 * u);
        } else if (AMODE == AM_G4) {
          if (q == 0)      v = *(const f32x4*)(A  + base + 4 * u);
          else if (q == 1) v = *(const f32x4*)(A2 + base + 4 * u);
          else {
            f32x4 x = *(const f32x4*)(A  + base + 4 * u);
            f32x4 y = *(const f32x4*)(A2 + base + 4 * u);
            v = (q == 2) ? x * y : x - y;
          }
        } else { // AM_RC
          if (q == 0) {
            f32x4 x = *(const f32x4*)(A  + base + 4 * u);
            f32x4 y = *(const f32x4*)(A2 + base + 4 * u);
            v = x * y;
          } else v = *(const f32x4*)(A3 + base + 4 * u);
        }
        stq(&As[row * LDK + kq + 4 * u], v);
      }
    }
    // ---- stage B -> Bs[n][k]
    if (BW) {
      const int row = tid >> 1, kq = (tid & 1) * 16;
      const float* src = Bm + (long)(n0 + row) * ldb + k0 + kq;
      #pragma unroll
      for (int u = 0; u < 4; u++)
        stq(&Bs[row * LDK + kq + 4 * u], *(const f32x4*)(src + 4 * u));
    } else {
      const int rr = tid & 127, kh = (tid >> 7) * 16;
      const float* src = Bm + (long)(k0 + kh) * ldb + n0 + rr;
      short th[16], tl[16];
      #pragma unroll
      for (int j = 0; j < 16; j++) {
        float tv = src[(long)j * ldb];
        th[j] = f2bf(tv);
        if (SPLIT) tl[j] = f2bf(tv - bf2f(th[j]));
      }
      #pragma unroll
      for (int q = 0; q < 4; q++) {
        *(s16x4*)&Bs[rr * LDK + kh + 4 * q] = (s16x4){ th[4*q], th[4*q+1], th[4*q+2], th[4*q+3] };
        if (SPLIT)
          *(s16x4*)&Bs[HL + rr * LDK + kh + 4 * q] = (s16x4){ tl[4*q], tl[4*q+1], tl[4*q+2], tl[4*q+3] };
      }
    }
    __syncthreads();

    s16x8 ah[4], bh[4], al[4], bl[4];
    #pragma unroll
    for (int i = 0; i < 4; i++) {
      ah[i] = *(const s16x8*)&As[(wm + i*16 + r) * LDK + g * 8];
      if (SPLIT) al[i] = *(const s16x8*)&As[HL + (wm + i*16 + r) * LDK + g * 8];
    }
    #pragma unroll
    for (int j = 0; j < 4; j++) {
      bh[j] = *(const s16x8*)&Bs[(wn + j*16 + r) * LDK + g * 8];
      if (SPLIT) bl[j] = *(const s16x8*)&Bs[HL + (wn + j*16 + r) * LDK + g * 8];
    }
    #pragma unroll
    for (int i = 0; i < 4; i++)
      #pragma unroll
      for (int j = 0; j < 4; j++) {
        acc[i][j] = __builtin_amdgcn_mfma_f32_16x16x32_bf16(ah[i], bh[j], acc[i][j], 0, 0, 0);
        if (SPLIT) {
          acc[i][j] = __builtin_amdgcn_mfma_f32_16x16x32_bf16(ah[i], bl[j], acc[i][j], 0, 0, 0);
          acc[i][j] = __builtin_amdgcn_mfma_f32_16x16x32_bf16(al[i], bh[j], acc[i][j], 0, 0, 0);
        }
      }
    __syncthreads();
  }

  // ---- epilogue: C layout col=lane&15, row=(lane>>4)*4+t
  #pragma unroll
  for (int i = 0; i < 4; i++) {
    #pragma unroll
    for (int j = 0; j < 4; j++) {
      #pragma unroll
      for (int t = 0; t < 4; t++) {
        const int row = m0 + wm + i * 16 + g * 4 + t;
        const int col = n0 + wn + j * 16 + r;
        const long idx = (long)row * ldc + col;
        float v = acc[i][j][t];
        if (EPI == EPI_RELUB)     { v += bias[col]; v = v > 0.f ? v : 0.f; }
        else if (EPI == EPI_AGG)  { v = (v + aux1[idx]) * aux2[row]; }
        else if (EPI == EPI_SIG)  { v = 1.f / (1.f + __expf(-v)); }
        else if (EPI == EPI_GATE) { v += bias[col];
                                    float z = 1.f / (1.f + __expf(-v));
                                    v = (1.f - z) * aux1[idx] + z * aux2[idx]; }
        else if (EPI == EPI_TANH) { v = tanhf(v); }
        C[idx] = v;
      }
    }
  }
}

// rno[b*N+n] = 1/(1+sum_e e2n[b,n,e]) — one wave per row
__global__ void rowsum_kernel(const float* __restrict__ e2n, float* __restrict__ out) {
  const int gw = blockIdx.x * 4 + (threadIdx.x >> 6);
  const int lane = threadIdx.x & 63;
  const float* p = e2n + (long)gw * Ee;
  float s = 0.f;
  for (int e = lane; e < Ee; e += 64) s += p[e];
  #pragma unroll
  for (int off = 32; off; off >>= 1) s += __shfl_down(s, off);
  if (lane == 0) out[gw] = 1.f / (1.f + s);
}

// partial column sums of n2e over e-chunks
__global__ void colsum_kernel(const float* __restrict__ n2e, float* __restrict__ part) {
  const int n = blockIdx.x * 256 + threadIdx.x;
  const int c = blockIdx.y, b = blockIdx.z;
  const float* p = n2e + (long)b * Ee * Nn + (long)c * (Ee / 16) * Nn + n;
  float s = 0.f;
  for (int e = 0; e < Ee / 16; e++) s += p[(long)e * Nn];
  part[((long)b * 16 + c) * Nn + n] = s;
}

__global__ void colfin_kernel(const float* __restrict__ part, float* __restrict__ rni) {
  const int i = blockIdx.x * 256 + threadIdx.x;   // over B*N
  const int b = i >> 11, n = i & 2047;
  float s = 0.f;
  #pragma unroll
  for (int c = 0; c < 16; c++) s += part[((long)b * 16 + c) * Nn + n];
  rni[i] = 1.f / (1.f + s);
}

__global__ void copy_kernel(const float* __restrict__ src, float* __restrict__ dst) {
  const long i = (long)blockIdx.x * 256 + threadIdx.x;
  dst[i] = src[i];
}

__global__ void gruf_kernel(const float* __restrict__ u, const float* __restrict__ m,
                            float* __restrict__ cur) {
  const long i = (long)blockIdx.x * 256 + threadIdx.x;
  const float uu = u[i];
  cur[i] = (1.f - uu) * cur[i] + uu * m[i];
}

__global__ void maxpool1(const float* __restrict__ pooled, float* __restrict__ part) {
  const int d = threadIdx.x, c = blockIdx.x, b = blockIdx.y;
  const float* p = pooled + ((long)b * Nn + c * 256) * Dd + d;
  float m = -INFINITY;
  for (int n = 0; n < 256; n++) m = fmaxf(m, p[(long)n * Dd]);
  part[(b * 8 + c) * Dd + d] = m;
}

__global__ void maxpool2(const float* __restrict__ part, float* __restrict__ out1) {
  const int d = threadIdx.x, b = blockIdx.x;
  float m = -INFINITY;
  #pragma unroll
  for (int c = 0; c < 8; c++) m = fmaxf(m, part[(b * 8 + c) * Dd + d]);
  out1[b * Dd + d] = m;
}

__global__ void transpose_kernel(const float* __restrict__ cur, float* __restrict__ out0) {
  const long i = (long)blockIdx.x * 256 + threadIdx.x;  // over N*B*D (output order)
  const int d = i & 255;
  const long nb = i >> 8;
  const int b = nb & 7;
  const long n = nb >> 3;
  out0[i] = cur[((long)b * Nn + n) * Dd + d];
}

extern "C" void kernel_launch(void* const* d_in, const int* in_sizes, int n_in,
                              void* d_out, int out_size, void* d_ws, size_t ws_size,
                              hipStream_t stream) {
  const float* node_vec = (const float*)d_in[0];
  const float* edge_vec = (const float*)d_in[1];   // [B,E,D] == flat [B*E,256]
  const float* n2e      = (const float*)d_in[2];   // [B,E,N]
  const float* e2n      = (const float*)d_in[3];   // [B,N,E]
  const float* W_fuse   = (const float*)d_in[5];   // [256,512]
  const float* b_fuse   = (const float*)d_in[6];
  const float* W_z      = (const float*)d_in[7];   // [256,1024]
  const float* b_z      = (const float*)d_in[8];
  const float* W_u      = (const float*)d_in[9];   // [256,512]
  const float* W_r      = (const float*)d_in[10];
  const float* W_m      = (const float*)d_in[11];
  const float* W_max    = (const float*)d_in[12];  // [256,256]

  const long ND  = (long)Bb * Nn * Dd;   // 4194304
  const long ED  = (long)Bb * Ee * Dd;   // 8388608
  const long NDb = (long)Nn * Dd;
  const long EDb = (long)Ee * Dd;
  const int  BE  = Bb * Ee;              // 32768
  const int  BN  = Bb * Nn;              // 16384

  // workspace layout (~119 MB total)
  float* ws      = (float*)d_ws;
  float* rno     = ws;                     // 16384
  float* rni     = rno + BN;               // 16384
  float* colpart = rni + BN;               // 16*BN = 262144
  float* maxpart = colpart + 16L * BN;     // 16384
  float* cur     = maxpart + BN;           // ND
  float* outv    = cur + ND;               // ND
  float* inv     = outv + ND;              // ND
  float* E1      = inv + ND;               // ED
  float* E2      = E1 + ED;                // ED
  float* nv      = E1;                     // ND   (aliases E1 after edge phase)
  float* ub      = E1 + ND;                // ND
  float* rb      = E2;                     // ND
  float* mb      = E2 + ND;                // ND

  float* out0 = (float*)d_out;
  float* out1 = out0 + ND;

  copy_kernel<<<ND / 256, 256, 0, stream>>>(node_vec, cur);
  rowsum_kernel<<<BN / 4, 256, 0, stream>>>(e2n, rno);
  colsum_kernel<<<dim3(Nn / 256, 16, Bb), 256, 0, stream>>>(n2e, colpart);
  colfin_kernel<<<BN / 256, 256, 0, stream>>>(colpart, rni);

  for (int h = 0; h < HOPS; h++) {
    // EO1[b,e,d] = sum_n n2e[b,e,n]*cur[b,n,d]  -> E1   [signed B -> SPLIT]
    gemm_kernel<AM_N, false, true, EPI_NONE><<<dim3(2, Ee / 128, Bb), 256, 0, stream>>>(
        n2e, nullptr, nullptr, cur, E1, nullptr, nullptr, nullptr,
        Ee, 256, Nn, Nn, 256, 256, (long)Ee * Nn, NDb, EDb, 0, 0);
    // EO2 = relu(concat(EO1, edge_vec) @ W_fuse^T + b_fuse) -> E2   [SPLIT]
    gemm_kernel<AM_C2, true, true, EPI_RELUB><<<dim3(2, BE / 128, 1), 256, 0, stream>>>(
        E1, edge_vec, nullptr, W_fuse, E2, nullptr, nullptr, b_fuse,
        BE, 256, 512, 0, 512, 256, 0, 0, 0, 0, 0);
    // out_vec = (e2n @ EO2 + cur) * rno -> outv   [nonneg x nonneg -> plain bf16]
    gemm_kernel<AM_N, false, false, EPI_AGG><<<dim3(2, Nn / 128, Bb), 256, 0, stream>>>(
        e2n, nullptr, nullptr, E2, outv, cur, rno, nullptr,
        Nn, 256, Ee, Ee, 256, 256, (long)Nn * Ee, EDb, NDb, NDb, (long)Nn);
    // EI1[b,e,d] = sum_n e2n[b,n,e]*cur[b,n,d]  (A transposed) -> E1   [SPLIT]
    gemm_kernel<AM_T, false, true, EPI_NONE><<<dim3(2, Ee / 128, Bb), 256, 0, stream>>>(
        e2n, nullptr, nullptr, cur, E1, nullptr, nullptr, nullptr,
        Ee, 256, Nn, Ee, 256, 256, (long)Nn * Ee, NDb, EDb, 0, 0);
    // EI2 = relu(concat(EI1, edge_vec) @ W_fuse^T + b_fuse) -> E2   [SPLIT]
    gemm_kernel<AM_C2, true, true, EPI_RELUB><<<dim3(2, BE / 128, 1), 256, 0, stream>>>(
        E1, edge_vec, nullptr, W_fuse, E2, nullptr, nullptr, b_fuse,
        BE, 256, 512, 0, 512, 256, 0, 0, 0, 0, 0);
    // in_vec = (n2e^T @ EI2 + cur) * rni -> inv   [plain bf16]
    gemm_kernel<AM_T, false, false, EPI_AGG><<<dim3(2, Nn / 128, Bb), 256, 0, stream>>>(
        n2e, nullptr, nullptr, E2, inv, cur, rni, nullptr,
        Nn, 256, Ee, Nn, 256, 256, (long)Ee * Nn, EDb, NDb, NDb, (long)Nn);
    // nv = (1-z)*inv + z*outv, z = sigmoid(G4 @ W_z^T + b_z)   -> nv (=E1)  [SPLIT]
    gemm_kernel<AM_G4, true, true, EPI_GATE><<<dim3(2, BN / 128, 1), 256, 0, stream>>>(
        inv, outv, nullptr, W_z, nv, inv, outv, b_z,
        BN, 256, 1024, 0, 1024, 256, 0, 0, 0, 0, 0);
    // u = sigmoid(concat(cur,nv) @ W_u^T) -> ub   [SPLIT]
    gemm_kernel<AM_CN, true, true, EPI_SIG><<<dim3(2, BN / 128, 1), 256, 0, stream>>>(
        cur, nv, nullptr, W_u, ub, nullptr, nullptr, nullptr,
        BN, 256, 512, 0, 512, 256, 0, 0, 0, 0, 0);
    // r = sigmoid(concat(cur,nv) @ W_r^T) -> rb   [SPLIT]
    gemm_kernel<AM_CN, true, true, EPI_SIG><<<dim3(2, BN / 128, 1), 256, 0, stream>>>(
        cur, nv, nullptr, W_r, rb, nullptr, nullptr, nullptr,
        BN, 256, 512, 0, 512, 256, 0, 0, 0, 0, 0);
    // m = tanh(concat(r*cur, nv) @ W_m^T) -> mb   [SPLIT]
    gemm_kernel<AM_RC, true, true, EPI_TANH><<<dim3(2, BN / 128, 1), 256, 0, stream>>>(
        rb, cur, nv, W_m, mb, nullptr, nullptr, nullptr,
        BN, 256, 512, 0, 512, 256, 0, 0, 0, 0, 0);
    // cur = (1-u)*cur + u*m
    gruf_kernel<<<ND / 256, 256, 0, stream>>>(ub, mb, cur);
  }

  // graph pooling: pooled = cur @ W_max^T -> E1, then max over n   [SPLIT]
  gemm_kernel<AM_N, true, true, EPI_NONE><<<dim3(2, BN / 128, 1), 256, 0, stream>>>(
      cur, nullptr, nullptr, W_max, E1, nullptr, nullptr, nullptr,
      BN, 256, 256, 256, 256, 256, 0, 0, 0, 0, 0);
  maxpool1<<<dim3(8, Bb), 256, 0, stream>>>(E1, maxpart);
  maxpool2<<<Bb, 256, 0, stream>>>(maxpart, out1);

  transpose_kernel<<<ND / 256, 256, 0, stream>>>(cur, out0);
}

// Round 4
// 2924.489 us; speedup vs baseline: 1.1307x; 1.1307x over previous
//
#include <hip/hip_runtime.h>
#include <hip/hip_bf16.h>
#include <math.h>

#define Bb 8
#define Nn 2048
#define Ee 4096
#define Dd 256
#define HOPS 3

typedef __attribute__((ext_vector_type(4))) float f32x4;
typedef __attribute__((ext_vector_type(8))) short s16x8;
typedef __attribute__((ext_vector_type(4))) short s16x4;

__device__ __forceinline__ short f2bf(float f){
  union{float f; unsigned u;} x; x.f=f;
  unsigned r = (x.u + 0x7fffu + ((x.u>>16)&1u)) >> 16;
  return (short)r;
}
__device__ __forceinline__ float bf2f(short h){
  union{unsigned u; float f;} x; x.u = ((unsigned)(unsigned short)h) << 16; return x.f;
}

enum { AM_N=0, AM_T, AM_C2, AM_CN, AM_G4, AM_RC };
enum { EPI_NONE=0, EPI_RELUB, EPI_AGG, EPI_SIG, EPI_GATE, EPI_TANH };

#define LDK 40   // padded LDS k-stride (shorts): 80B rows, 16B-aligned b128 frag reads

// C[M,Nd] = A_eff[M,K] @ B_eff[K,Nd], bf16 MFMA, fp32 accum.
// Tile 64x128 (M x N), 4 waves in 2x2, each wave 32x64 -> 2x4 MFMA frags.
// Grid = 2x the 128-tile version -> >=2 blocks/CU (occupancy fix, round 4).
// SPLIT=true: bf16x3 split-precision (hi/lo) — err ~2^-18/term instead of 2^-9.
// AM_N: A [M,K] row-major (lda). AM_T: A stored [K,M] (lda = its row stride).
// AM_C2/CN: A_eff = concat(A,A2) along k (K=512), pitch 256.
// AM_G4: concat(A, A2, A*A2, A-A2) (K=1024). AM_RC: concat(A*A2, A3) (K=512).
// BW=true: B stored [Nd,K] row-major (weights). BW=false: B stored [K,Nd].
template<int AMODE, bool BW, bool SPLIT, int EPI>
__global__ __launch_bounds__(256) void gemm_kernel(
    const float* __restrict__ A, const float* __restrict__ A2, const float* __restrict__ A3,
    const float* __restrict__ Bm, float* __restrict__ C,
    const float* __restrict__ aux1, const float* __restrict__ aux2, const float* __restrict__ bias,
    int M, int Nd, int K, int lda, int ldb, int ldc,
    long sA, long sB, long sC, long sAux1, long sAux2)
{
  const int bz = blockIdx.z;
  A += bz * sA; Bm += bz * sB; C += bz * sC;
  if (aux1) aux1 += bz * sAux1;
  if (aux2) aux2 += bz * sAux2;
  const int m0 = blockIdx.y * 64;
  const int n0 = blockIdx.x * 128;

  constexpr int HLA = 64 * LDK;
  constexpr int HLB = 128 * LDK;
  __shared__ short As[64 * LDK * (SPLIT ? 2 : 1)];
  __shared__ short Bs[128 * LDK * (SPLIT ? 2 : 1)];

  const int tid = threadIdx.x;
  const int wid = tid >> 6, lane = tid & 63;
  const int wm = (wid >> 1) * 32, wn = (wid & 1) * 64;
  const int r = lane & 15, g = lane >> 4;

  f32x4 acc[2][4];
  #pragma unroll
  for (int i = 0; i < 2; i++)
    #pragma unroll
    for (int j = 0; j < 4; j++) acc[i][j] = (f32x4){0.f, 0.f, 0.f, 0.f};

  // store one f32x4 as bf16 hi (and lo residual if SPLIT); HL = half-offset
  auto stq = [&](short* dst, int HL, f32x4 v) {
    s16x4 h = { f2bf(v.x), f2bf(v.y), f2bf(v.z), f2bf(v.w) };
    *(s16x4*)dst = h;
    if (SPLIT) {
      s16x4 l = { f2bf(v.x - bf2f(h.x)), f2bf(v.y - bf2f(h.y)),
                  f2bf(v.z - bf2f(h.z)), f2bf(v.w - bf2f(h.w)) };
      *(s16x4*)(dst + HL) = l;
    }
  };

  for (int k0 = 0; k0 < K; k0 += 32) {
    // ---- stage A -> As[m][k]  (64 rows x 32 k)
    if (AMODE == AM_N) {
      const int row0 = tid >> 3, kq = (tid & 7) * 4;   // 32 rows/pass, 2 passes
      #pragma unroll
      for (int p = 0; p < 2; p++) {
        const int row = row0 + 32 * p;
        f32x4 v = *(const f32x4*)(A + (long)(m0 + row) * lda + k0 + kq);
        stq(&As[row * LDK + kq], HLA, v);
      }
    } else if (AMODE == AM_T) {
      const int rr = tid & 63, kh = (tid >> 6) * 8;    // 64 m-cols, 8 k-rows each
      const float* src = A + (long)(k0 + kh) * lda + m0 + rr;
      short th[8], tl[8];
      #pragma unroll
      for (int j = 0; j < 8; j++) {
        float tv = src[(long)j * lda];
        th[j] = f2bf(tv);
        if (SPLIT) tl[j] = f2bf(tv - bf2f(th[j]));
      }
      #pragma unroll
      for (int q = 0; q < 2; q++) {
        *(s16x4*)&As[rr * LDK + kh + 4 * q] = (s16x4){ th[4*q], th[4*q+1], th[4*q+2], th[4*q+3] };
        if (SPLIT)
          *(s16x4*)&As[HLA + rr * LDK + kh + 4 * q] = (s16x4){ tl[4*q], tl[4*q+1], tl[4*q+2], tl[4*q+3] };
      }
    } else {
      // fused feature staging: sources have pitch 256; 8 floats (2 x f32x4) per thread
      const int row = tid >> 2, kq = (tid & 3) * 8;
      const int kk = k0 + kq, q = kk >> 8, kd = kk & 255;
      const long base = (long)(m0 + row) * 256 + kd;
      #pragma unroll
      for (int u = 0; u < 2; u++) {
        f32x4 v;
        if (AMODE == AM_C2 || AMODE == AM_CN) {
          v = *(const f32x4*)((q == 0 ? A : A2) + base + 4 * u);
        } else if (AMODE == AM_G4) {
          if (q == 0)      v = *(const f32x4*)(A  + base + 4 * u);
          else if (q == 1) v = *(const f32x4*)(A2 + base + 4 * u);
          else {
            f32x4 x = *(const f32x4*)(A  + base + 4 * u);
            f32x4 y = *(const f32x4*)(A2 + base + 4 * u);
            v = (q == 2) ? x * y : x - y;
          }
        } else { // AM_RC
          if (q == 0) {
            f32x4 x = *(const f32x4*)(A  + base + 4 * u);
            f32x4 y = *(const f32x4*)(A2 + base + 4 * u);
            v = x * y;
          } else v = *(const f32x4*)(A3 + base + 4 * u);
        }
        stq(&As[row * LDK + kq + 4 * u], HLA, v);
      }
    }
    // ---- stage B -> Bs[n][k]  (128 rows x 32 k)
    if (BW) {
      const int row = tid >> 1, kq = (tid & 1) * 16;
      const float* src = Bm + (long)(n0 + row) * ldb + k0 + kq;
      #pragma unroll
      for (int u = 0; u < 4; u++)
        stq(&Bs[row * LDK + kq + 4 * u], HLB, *(const f32x4*)(src + 4 * u));
    } else {
      const int rr = tid & 127, kh = (tid >> 7) * 16;
      const float* src = Bm + (long)(k0 + kh) * ldb + n0 + rr;
      short th[16], tl[16];
      #pragma unroll
      for (int j = 0; j < 16; j++) {
        float tv = src[(long)j * ldb];
        th[j] = f2bf(tv);
        if (SPLIT) tl[j] = f2bf(tv - bf2f(th[j]));
      }
      #pragma unroll
      for (int q = 0; q < 4; q++) {
        *(s16x4*)&Bs[rr * LDK + kh + 4 * q] = (s16x4){ th[4*q], th[4*q+1], th[4*q+2], th[4*q+3] };
        if (SPLIT)
          *(s16x4*)&Bs[HLB + rr * LDK + kh + 4 * q] = (s16x4){ tl[4*q], tl[4*q+1], tl[4*q+2], tl[4*q+3] };
      }
    }
    __syncthreads();

    s16x8 ah[2], bh[4], al[2], bl[4];
    #pragma unroll
    for (int i = 0; i < 2; i++) {
      ah[i] = *(const s16x8*)&As[(wm + i*16 + r) * LDK + g * 8];
      if (SPLIT) al[i] = *(const s16x8*)&As[HLA + (wm + i*16 + r) * LDK + g * 8];
    }
    #pragma unroll
    for (int j = 0; j < 4; j++) {
      bh[j] = *(const s16x8*)&Bs[(wn + j*16 + r) * LDK + g * 8];
      if (SPLIT) bl[j] = *(const s16x8*)&Bs[HLB + (wn + j*16 + r) * LDK + g * 8];
    }
    #pragma unroll
    for (int i = 0; i < 2; i++)
      #pragma unroll
      for (int j = 0; j < 4; j++) {
        acc[i][j] = __builtin_amdgcn_mfma_f32_16x16x32_bf16(ah[i], bh[j], acc[i][j], 0, 0, 0);
        if (SPLIT) {
          acc[i][j] = __builtin_amdgcn_mfma_f32_16x16x32_bf16(ah[i], bl[j], acc[i][j], 0, 0, 0);
          acc[i][j] = __builtin_amdgcn_mfma_f32_16x16x32_bf16(al[i], bh[j], acc[i][j], 0, 0, 0);
        }
      }
    __syncthreads();
  }

  // ---- epilogue: C layout col=lane&15, row=(lane>>4)*4+t
  #pragma unroll
  for (int i = 0; i < 2; i++) {
    #pragma unroll
    for (int j = 0; j < 4; j++) {
      #pragma unroll
      for (int t = 0; t < 4; t++) {
        const int row = m0 + wm + i * 16 + g * 4 + t;
        const int col = n0 + wn + j * 16 + r;
        const long idx = (long)row * ldc + col;
        float v = acc[i][j][t];
        if (EPI == EPI_RELUB)     { v += bias[col]; v = v > 0.f ? v : 0.f; }
        else if (EPI == EPI_AGG)  { v = (v + aux1[idx]) * aux2[row]; }
        else if (EPI == EPI_SIG)  { v = 1.f / (1.f + __expf(-v)); }
        else if (EPI == EPI_GATE) { v += bias[col];
                                    float z = 1.f / (1.f + __expf(-v));
                                    v = (1.f - z) * aux1[idx] + z * aux2[idx]; }
        else if (EPI == EPI_TANH) { v = tanhf(v); }
        C[idx] = v;
      }
    }
  }
}

// rno[b*N+n] = 1/(1+sum_e e2n[b,n,e]) — one wave per row
__global__ void rowsum_kernel(const float* __restrict__ e2n, float* __restrict__ out) {
  const int gw = blockIdx.x * 4 + (threadIdx.x >> 6);
  const int lane = threadIdx.x & 63;
  const float* p = e2n + (long)gw * Ee;
  float s = 0.f;
  for (int e = lane; e < Ee; e += 64) s += p[e];
  #pragma unroll
  for (int off = 32; off; off >>= 1) s += __shfl_down(s, off);
  if (lane == 0) out[gw] = 1.f / (1.f + s);
}

// partial column sums of n2e over e-chunks
__global__ void colsum_kernel(const float* __restrict__ n2e, float* __restrict__ part) {
  const int n = blockIdx.x * 256 + threadIdx.x;
  const int c = blockIdx.y, b = blockIdx.z;
  const float* p = n2e + (long)b * Ee * Nn + (long)c * (Ee / 16) * Nn + n;
  float s = 0.f;
  for (int e = 0; e < Ee / 16; e++) s += p[(long)e * Nn];
  part[((long)b * 16 + c) * Nn + n] = s;
}

__global__ void colfin_kernel(const float* __restrict__ part, float* __restrict__ rni) {
  const int i = blockIdx.x * 256 + threadIdx.x;   // over B*N
  const int b = i >> 11, n = i & 2047;
  float s = 0.f;
  #pragma unroll
  for (int c = 0; c < 16; c++) s += part[((long)b * 16 + c) * Nn + n];
  rni[i] = 1.f / (1.f + s);
}

__global__ void copy_kernel(const float* __restrict__ src, float* __restrict__ dst) {
  const long i = (long)blockIdx.x * 256 + threadIdx.x;
  dst[i] = src[i];
}

__global__ void gruf_kernel(const float* __restrict__ u, const float* __restrict__ m,
                            float* __restrict__ cur) {
  const long i = (long)blockIdx.x * 256 + threadIdx.x;
  const float uu = u[i];
  cur[i] = (1.f - uu) * cur[i] + uu * m[i];
}

__global__ void maxpool1(const float* __restrict__ pooled, float* __restrict__ part) {
  const int d = threadIdx.x, c = blockIdx.x, b = blockIdx.y;
  const float* p = pooled + ((long)b * Nn + c * 256) * Dd + d;
  float m = -INFINITY;
  for (int n = 0; n < 256; n++) m = fmaxf(m, p[(long)n * Dd]);
  part[(b * 8 + c) * Dd + d] = m;
}

__global__ void maxpool2(const float* __restrict__ part, float* __restrict__ out1) {
  const int d = threadIdx.x, b = blockIdx.x;
  float m = -INFINITY;
  #pragma unroll
  for (int c = 0; c < 8; c++) m = fmaxf(m, part[(b * 8 + c) * Dd + d]);
  out1[b * Dd + d] = m;
}

__global__ void transpose_kernel(const float* __restrict__ cur, float* __restrict__ out0) {
  const long i = (long)blockIdx.x * 256 + threadIdx.x;  // over N*B*D (output order)
  const int d = i & 255;
  const long nb = i >> 8;
  const int b = nb & 7;
  const long n = nb >> 3;
  out0[i] = cur[((long)b * Nn + n) * Dd + d];
}

extern "C" void kernel_launch(void* const* d_in, const int* in_sizes, int n_in,
                              void* d_out, int out_size, void* d_ws, size_t ws_size,
                              hipStream_t stream) {
  const float* node_vec = (const float*)d_in[0];
  const float* edge_vec = (const float*)d_in[1];   // [B,E,D] == flat [B*E,256]
  const float* n2e      = (const float*)d_in[2];   // [B,E,N]
  const float* e2n      = (const float*)d_in[3];   // [B,N,E]
  const float* W_fuse   = (const float*)d_in[5];   // [256,512]
  const float* b_fuse   = (const float*)d_in[6];
  const float* W_z      = (const float*)d_in[7];   // [256,1024]
  const float* b_z      = (const float*)d_in[8];
  const float* W_u      = (const float*)d_in[9];   // [256,512]
  const float* W_r      = (const float*)d_in[10];
  const float* W_m      = (const float*)d_in[11];
  const float* W_max    = (const float*)d_in[12];  // [256,256]

  const long ND  = (long)Bb * Nn * Dd;   // 4194304
  const long ED  = (long)Bb * Ee * Dd;   // 8388608
  const long NDb = (long)Nn * Dd;
  const long EDb = (long)Ee * Dd;
  const int  BE  = Bb * Ee;              // 32768
  const int  BN  = Bb * Nn;              // 16384

  // workspace layout (~119 MB total)
  float* ws      = (float*)d_ws;
  float* rno     = ws;                     // 16384
  float* rni     = rno + BN;               // 16384
  float* colpart = rni + BN;               // 16*BN = 262144
  float* maxpart = colpart + 16L * BN;     // 16384
  float* cur     = maxpart + BN;           // ND
  float* outv    = cur + ND;               // ND
  float* inv     = outv + ND;              // ND
  float* E1      = inv + ND;               // ED
  float* E2      = E1 + ED;                // ED
  float* nv      = E1;                     // ND   (aliases E1 after edge phase)
  float* ub      = E1 + ND;                // ND
  float* rb      = E2;                     // ND
  float* mb      = E2 + ND;                // ND

  float* out0 = (float*)d_out;
  float* out1 = out0 + ND;

  copy_kernel<<<ND / 256, 256, 0, stream>>>(node_vec, cur);
  rowsum_kernel<<<BN / 4, 256, 0, stream>>>(e2n, rno);
  colsum_kernel<<<dim3(Nn / 256, 16, Bb), 256, 0, stream>>>(n2e, colpart);
  colfin_kernel<<<BN / 256, 256, 0, stream>>>(colpart, rni);

  for (int h = 0; h < HOPS; h++) {
    // EO1[b,e,d] = sum_n n2e[b,e,n]*cur[b,n,d]  -> E1   [SPLIT]
    gemm_kernel<AM_N, false, true, EPI_NONE><<<dim3(2, Ee / 64, Bb), 256, 0, stream>>>(
        n2e, nullptr, nullptr, cur, E1, nullptr, nullptr, nullptr,
        Ee, 256, Nn, Nn, 256, 256, (long)Ee * Nn, NDb, EDb, 0, 0);
    // EO2 = relu(concat(EO1, edge_vec) @ W_fuse^T + b_fuse) -> E2   [SPLIT]
    gemm_kernel<AM_C2, true, true, EPI_RELUB><<<dim3(2, BE / 64, 1), 256, 0, stream>>>(
        E1, edge_vec, nullptr, W_fuse, E2, nullptr, nullptr, b_fuse,
        BE, 256, 512, 0, 512, 256, 0, 0, 0, 0, 0);
    // out_vec = (e2n @ EO2 + cur) * rno -> outv   [nonneg x nonneg -> plain bf16]
    gemm_kernel<AM_N, false, false, EPI_AGG><<<dim3(2, Nn / 64, Bb), 256, 0, stream>>>(
        e2n, nullptr, nullptr, E2, outv, cur, rno, nullptr,
        Nn, 256, Ee, Ee, 256, 256, (long)Nn * Ee, EDb, NDb, NDb, (long)Nn);
    // EI1[b,e,d] = sum_n e2n[b,n,e]*cur[b,n,d]  (A transposed) -> E1   [SPLIT]
    gemm_kernel<AM_T, false, true, EPI_NONE><<<dim3(2, Ee / 64, Bb), 256, 0, stream>>>(
        e2n, nullptr, nullptr, cur, E1, nullptr, nullptr, nullptr,
        Ee, 256, Nn, Ee, 256, 256, (long)Nn * Ee, NDb, EDb, 0, 0);
    // EI2 = relu(concat(EI1, edge_vec) @ W_fuse^T + b_fuse) -> E2   [SPLIT]
    gemm_kernel<AM_C2, true, true, EPI_RELUB><<<dim3(2, BE / 64, 1), 256, 0, stream>>>(
        E1, edge_vec, nullptr, W_fuse, E2, nullptr, nullptr, b_fuse,
        BE, 256, 512, 0, 512, 256, 0, 0, 0, 0, 0);
    // in_vec = (n2e^T @ EI2 + cur) * rni -> inv   [plain bf16]
    gemm_kernel<AM_T, false, false, EPI_AGG><<<dim3(2, Nn / 64, Bb), 256, 0, stream>>>(
        n2e, nullptr, nullptr, E2, inv, cur, rni, nullptr,
        Nn, 256, Ee, Nn, 256, 256, (long)Ee * Nn, EDb, NDb, NDb, (long)Nn);
    // nv = (1-z)*inv + z*outv, z = sigmoid(G4 @ W_z^T + b_z)   -> nv (=E1)  [SPLIT]
    gemm_kernel<AM_G4, true, true, EPI_GATE><<<dim3(2, BN / 64, 1), 256, 0, stream>>>(
        inv, outv, nullptr, W_z, nv, inv, outv, b_z,
        BN, 256, 1024, 0, 1024, 256, 0, 0, 0, 0, 0);
    // u = sigmoid(concat(cur,nv) @ W_u^T) -> ub   [SPLIT]
    gemm_kernel<AM_CN, true, true, EPI_SIG><<<dim3(2, BN / 64, 1), 256, 0, stream>>>(
        cur, nv, nullptr, W_u, ub, nullptr, nullptr, nullptr,
        BN, 256, 512, 0, 512, 256, 0, 0, 0, 0, 0);
    // r = sigmoid(concat(cur,nv) @ W_r^T) -> rb   [SPLIT]
    gemm_kernel<AM_CN, true, true, EPI_SIG><<<dim3(2, BN / 64, 1), 256, 0, stream>>>(
        cur, nv, nullptr, W_r, rb, nullptr, nullptr, nullptr,
        BN, 256, 512, 0, 512, 256, 0, 0, 0, 0, 0);
    // m = tanh(concat(r*cur, nv) @ W_m^T) -> mb   [SPLIT]
    gemm_kernel<AM_RC, true, true, EPI_TANH><<<dim3(2, BN / 64, 1), 256, 0, stream>>>(
        rb, cur, nv, W_m, mb, nullptr, nullptr, nullptr,
        BN, 256, 512, 0, 512, 256, 0, 0, 0, 0, 0);
    // cur = (1-u)*cur + u*m
    gruf_kernel<<<ND / 256, 256, 0, stream>>>(ub, mb, cur);
  }

  // graph pooling: pooled = cur @ W_max^T -> E1, then max over n   [SPLIT]
  gemm_kernel<AM_N, true, true, EPI_NONE><<<dim3(2, BN / 64, 1), 256, 0, stream>>>(
      cur, nullptr, nullptr, W_max, E1, nullptr, nullptr, nullptr,
      BN, 256, 256, 256, 256, 256, 0, 0, 0, 0, 0);
  maxpool1<<<dim3(8, Bb), 256, 0, stream>>>(E1, maxpart);
  maxpool2<<<Bb, 256, 0, stream>>>(maxpart, out1);

  transpose_kernel<<<ND / 256, 256, 0, stream>>>(cur, out0);
}

// Round 6
// 2572.781 us; speedup vs baseline: 1.2853x; 1.1367x over previous
//
#include <hip/hip_runtime.h>
#include <math.h>

#define Bb 8
#define Nn 2048
#define Ee 4096
#define Dd 256
#define HOPS 3
#define LDK 40   // padded LDS k-stride (16-bit elems): 80B rows, 16B-aligned b128 frags

typedef __attribute__((ext_vector_type(4))) float f32x4;
typedef _Float16 f16;
typedef __attribute__((ext_vector_type(8))) _Float16 f16x8;
typedef __attribute__((ext_vector_type(4))) _Float16 f16x4;
typedef __attribute__((ext_vector_type(8))) short s16x8;
typedef __attribute__((ext_vector_type(4))) short s16x4;

__device__ __forceinline__ short f2bf(float f){
  union{float f; unsigned u;} x; x.f=f;
  unsigned r = (x.u + 0x7fffu + ((x.u>>16)&1u)) >> 16;
  return (short)r;
}
__device__ __forceinline__ float bf2f(short h){
  union{unsigned u; float f;} x; x.u = ((unsigned)(unsigned short)h) << 16; return x.f;
}

enum { HN=0, HT=1, HC2=2 };            // hgemm A modes
enum { OF=0, OH=1, OHT=2 };            // hgemm output: f32 / f16 / f16-transposed
enum { EP_NONE=0, EP_RELUB, EP_AGG };  // hgemm epilogues
enum { SM_CN=0, SM_G4, SM_RC };        // sgemm A modes
enum { SE_GATE=0, SE_SIG, SE_TANH };   // sgemm epilogues

// ---------------- fp16 MFMA GEMM: tile 64x128, BK=32, 4 waves 2x2 ----------------
// SPL bit0: B has lo plane at +bLo (split-fp16, 2nd MFMA). bit1: A has lo at +aLo.
// Split is applied to SYSTEMATIC-error operands only (weights / node state);
// adjacency & edge buffers stay single fp16 (errors attenuate ~1/sqrt(E) in the
// non-negative aggregation).
template<int AMODE, bool AH, int SPL, int EPI, int OUTM>
__global__ __launch_bounds__(256) void hgemm(
    const void* __restrict__ Av, const f16* __restrict__ A2,
    const f16* __restrict__ Bh, void* __restrict__ Cv,
    const float* __restrict__ aux1, const float* __restrict__ aux2,
    const float* __restrict__ bias,
    int M, int Nd, int K, int lda, int ldb, int ldc,
    long sA, long sB, long sC, long sAux1, long sAux2,
    long aLo, long bLo)
{
  const int bz = blockIdx.z;
  const char* Ab = (const char*)Av + (AH ? bz * sA * 2 : bz * sA * 4);
  if (A2) A2 += bz * sA;
  Bh += bz * sB;
  char* Cb = (char*)Cv + ((OUTM == OF) ? bz * sC * 4 : bz * sC * 2);
  if (aux1) aux1 += bz * sAux1;
  if (aux2) aux2 += bz * sAux2;
  const int m0 = blockIdx.y * 64;
  const int n0 = blockIdx.x * 128;

  constexpr int HLA = 64 * LDK;
  constexpr int HLB = 128 * LDK;
  __shared__ f16 As[64 * LDK * ((SPL & 2) ? 2 : 1)];
  __shared__ f16 Bs[128 * LDK * ((SPL & 1) ? 2 : 1)];

  const int tid = threadIdx.x;
  const int wid = tid >> 6, lane = tid & 63;
  const int wm = (wid >> 1) * 32, wn = (wid & 1) * 64;
  const int r = lane & 15, g = lane >> 4;

  f32x4 acc[2][4];
  #pragma unroll
  for (int i = 0; i < 2; i++)
    #pragma unroll
    for (int j = 0; j < 4; j++) acc[i][j] = (f32x4){0.f, 0.f, 0.f, 0.f};

  for (int k0 = 0; k0 < K; k0 += 32) {
    // ---- stage A -> As[m][k] (64x32)
    if (AMODE == HN) {
      if (AH) {
        const f16* Ah = (const f16*)Ab;
        const int row = tid >> 2, kc = (tid & 3) * 8;
        const long off = (long)(m0 + row) * lda + k0 + kc;
        *(f16x8*)&As[row * LDK + kc] = *(const f16x8*)&Ah[off];
        if (SPL & 2)
          *(f16x8*)&As[HLA + row * LDK + kc] = *(const f16x8*)&Ah[aLo + off];
      } else {
        const float* Af = (const float*)Ab;
        const int row0 = tid >> 3, kc = (tid & 7) * 4;
        #pragma unroll
        for (int p = 0; p < 2; p++) {
          const int row = row0 + 32 * p;
          f32x4 v = *(const f32x4*)&Af[(long)(m0 + row) * lda + k0 + kc];
          *(f16x4*)&As[row * LDK + kc] = (f16x4){(f16)v.x, (f16)v.y, (f16)v.z, (f16)v.w};
        }
      }
    } else if (AMODE == HT) {
      const int rr = tid & 63, kh = (tid >> 6) * 8;
      if (AH) {
        const long base = (long)(k0 + kh) * lda + m0 + rr;
        const f16* src = &((const f16*)Ab)[base];
        f16x8 t;
        #pragma unroll
        for (int j = 0; j < 8; j++) t[j] = src[(long)j * lda];
        *(f16x8*)&As[rr * LDK + kh] = t;
        if (SPL & 2) {
          const f16* srcl = &((const f16*)Ab)[aLo + base];
          f16x8 tl;
          #pragma unroll
          for (int j = 0; j < 8; j++) tl[j] = srcl[(long)j * lda];
          *(f16x8*)&As[HLA + rr * LDK + kh] = tl;
        }
      } else {
        const float* src = &((const float*)Ab)[(long)(k0 + kh) * lda + m0 + rr];
        f16x8 t;
        #pragma unroll
        for (int j = 0; j < 8; j++) t[j] = (f16)src[(long)j * lda];
        *(f16x8*)&As[rr * LDK + kh] = t;
      }
    } else { // HC2: concat(A[.,0:256], A2[.,0:256]) halves, K=512
      const int row = tid >> 2, kc = (tid & 3) * 8;
      const int kk = k0 + kc;
      const f16* src = (kk < 256) ? &((const f16*)Ab)[(long)(m0 + row) * 256 + kk]
                                  : &A2[(long)(m0 + row) * 256 + (kk - 256)];
      *(f16x8*)&As[row * LDK + kc] = *(const f16x8*)src;
    }
    // ---- stage B -> Bs[n][k] (128x32): direct half copy (+ lo plane if split)
    {
      const int row = tid >> 1, kc = (tid & 1) * 16;
      const long off = (long)(n0 + row) * ldb + k0 + kc;
      *(f16x8*)&Bs[row * LDK + kc]     = *(const f16x8*)&Bh[off];
      *(f16x8*)&Bs[row * LDK + kc + 8] = *(const f16x8*)&Bh[off + 8];
      if (SPL & 1) {
        *(f16x8*)&Bs[HLB + row * LDK + kc]     = *(const f16x8*)&Bh[bLo + off];
        *(f16x8*)&Bs[HLB + row * LDK + kc + 8] = *(const f16x8*)&Bh[bLo + off + 8];
      }
    }
    __syncthreads();

    f16x8 af[2], bf[4], alo[2], blo[4];
    #pragma unroll
    for (int i = 0; i < 2; i++) {
      af[i] = *(const f16x8*)&As[(wm + i*16 + r) * LDK + g * 8];
      if (SPL & 2) alo[i] = *(const f16x8*)&As[HLA + (wm + i*16 + r) * LDK + g * 8];
    }
    #pragma unroll
    for (int j = 0; j < 4; j++) {
      bf[j] = *(const f16x8*)&Bs[(wn + j*16 + r) * LDK + g * 8];
      if (SPL & 1) blo[j] = *(const f16x8*)&Bs[HLB + (wn + j*16 + r) * LDK + g * 8];
    }
    #pragma unroll
    for (int i = 0; i < 2; i++)
      #pragma unroll
      for (int j = 0; j < 4; j++) {
        acc[i][j] = __builtin_amdgcn_mfma_f32_16x16x32_f16(af[i], bf[j], acc[i][j], 0, 0, 0);
        if (SPL & 1)
          acc[i][j] = __builtin_amdgcn_mfma_f32_16x16x32_f16(af[i], blo[j], acc[i][j], 0, 0, 0);
        if (SPL & 2)
          acc[i][j] = __builtin_amdgcn_mfma_f32_16x16x32_f16(alo[i], bf[j], acc[i][j], 0, 0, 0);
      }
    __syncthreads();
  }

  // ---- epilogue: C map col=lane&15, row=(lane>>4)*4+t
  #pragma unroll
  for (int i = 0; i < 2; i++) {
    #pragma unroll
    for (int j = 0; j < 4; j++) {
      const int rowb = m0 + wm + i * 16 + g * 4;
      const int col = n0 + wn + j * 16 + r;
      if (OUTM == OHT) {
        f16x4 hv;
        #pragma unroll
        for (int t = 0; t < 4; t++) {
          float v = acc[i][j][t];
          if (EPI == EP_RELUB) { v += bias[col]; v = v > 0.f ? v : 0.f; }
          hv[t] = (f16)v;
        }
        *(f16x4*)&((f16*)Cb)[(long)col * ldc + rowb] = hv;
      } else {
        #pragma unroll
        for (int t = 0; t < 4; t++) {
          const int row = rowb + t;
          const long idx = (long)row * ldc + col;
          float v = acc[i][j][t];
          if (EPI == EP_RELUB)    { v += bias[col]; v = v > 0.f ? v : 0.f; }
          else if (EPI == EP_AGG) { v = (v + aux1[idx]) * aux2[row]; }
          if (OUTM == OH) ((f16*)Cb)[idx] = (f16)v;
          else            ((float*)Cb)[idx] = v;
        }
      }
    }
  }
}

// ---------------- split-bf16 gate GEMM (validated numerics), tile 64x128 ----------------
template<int AMODE, int EPI>
__global__ __launch_bounds__(256) void sgemm(
    const float* __restrict__ A, const float* __restrict__ A2, const float* __restrict__ A3,
    const float* __restrict__ Bm, const float* __restrict__ Bm2, float* __restrict__ C,
    const float* __restrict__ aux1, const float* __restrict__ aux2, const float* __restrict__ bias,
    int Nd, int K, int lda, int ldb, int ldc)
{
  const int m0 = blockIdx.y * 64;
  const int n0 = blockIdx.x * 128;

  constexpr int HLA = 64 * LDK;
  constexpr int HLB = 128 * LDK;
  __shared__ short As[64 * LDK * 2];
  __shared__ short Bs[128 * LDK * 2];

  const int tid = threadIdx.x;
  const int wid = tid >> 6, lane = tid & 63;
  const int wm = (wid >> 1) * 32, wn = (wid & 1) * 64;
  const int r = lane & 15, g = lane >> 4;

  f32x4 acc[2][4];
  #pragma unroll
  for (int i = 0; i < 2; i++)
    #pragma unroll
    for (int j = 0; j < 4; j++) acc[i][j] = (f32x4){0.f, 0.f, 0.f, 0.f};

  auto stq = [&](short* dst, int HL, f32x4 v) {
    s16x4 h = { f2bf(v.x), f2bf(v.y), f2bf(v.z), f2bf(v.w) };
    *(s16x4*)dst = h;
    s16x4 l = { f2bf(v.x - bf2f(h.x)), f2bf(v.y - bf2f(h.y)),
                f2bf(v.z - bf2f(h.z)), f2bf(v.w - bf2f(h.w)) };
    *(s16x4*)(dst + HL) = l;
  };

  for (int k0 = 0; k0 < K; k0 += 32) {
    { // A staging (fused features)
      const int row = tid >> 2, kq = (tid & 3) * 8;
      const int kk = k0 + kq, q = kk >> 8, kd = kk & 255;
      const long base = (long)(m0 + row) * 256 + kd;
      const long baseA = (long)(m0 + row) * lda + kd;
      #pragma unroll
      for (int u = 0; u < 2; u++) {
        f32x4 v;
        if (AMODE == SM_CN) {
          v = (q == 0) ? *(const f32x4*)(A + base + 4 * u)
                       : *(const f32x4*)(A2 + base + 4 * u);
        } else if (AMODE == SM_G4) {
          if (q == 0)      v = *(const f32x4*)(A  + base + 4 * u);
          else if (q == 1) v = *(const f32x4*)(A2 + base + 4 * u);
          else {
            f32x4 x = *(const f32x4*)(A  + base + 4 * u);
            f32x4 y = *(const f32x4*)(A2 + base + 4 * u);
            v = (q == 2) ? x * y : x - y;
          }
        } else { // SM_RC
          if (q == 0) {
            f32x4 x = *(const f32x4*)(A  + baseA + 4 * u);
            f32x4 y = *(const f32x4*)(A2 + base + 4 * u);
            v = x * y;
          } else v = *(const f32x4*)(A3 + base + 4 * u);
        }
        stq(&As[row * LDK + kq + 4 * u], HLA, v);
      }
    }
    { // B staging (fp32 weights, split)
      const int row = tid >> 1, kq = (tid & 1) * 16;
      const int rowg = n0 + row;
      const float* src = (Bm2 != nullptr && rowg >= 256)
                         ? &Bm2[(long)(rowg - 256) * ldb + k0 + kq]
                         : &Bm[(long)rowg * ldb + k0 + kq];
      #pragma unroll
      for (int u = 0; u < 4; u++)
        stq(&Bs[row * LDK + kq + 4 * u], HLB, *(const f32x4*)(src + 4 * u));
    }
    __syncthreads();

    s16x8 ah[2], bh[4], al[2], bl[4];
    #pragma unroll
    for (int i = 0; i < 2; i++) {
      ah[i] = *(const s16x8*)&As[(wm + i*16 + r) * LDK + g * 8];
      al[i] = *(const s16x8*)&As[HLA + (wm + i*16 + r) * LDK + g * 8];
    }
    #pragma unroll
    for (int j = 0; j < 4; j++) {
      bh[j] = *(const s16x8*)&Bs[(wn + j*16 + r) * LDK + g * 8];
      bl[j] = *(const s16x8*)&Bs[HLB + (wn + j*16 + r) * LDK + g * 8];
    }
    #pragma unroll
    for (int i = 0; i < 2; i++)
      #pragma unroll
      for (int j = 0; j < 4; j++) {
        acc[i][j] = __builtin_amdgcn_mfma_f32_16x16x32_bf16(ah[i], bh[j], acc[i][j], 0, 0, 0);
        acc[i][j] = __builtin_amdgcn_mfma_f32_16x16x32_bf16(ah[i], bl[j], acc[i][j], 0, 0, 0);
        acc[i][j] = __builtin_amdgcn_mfma_f32_16x16x32_bf16(al[i], bh[j], acc[i][j], 0, 0, 0);
      }
    __syncthreads();
  }

  #pragma unroll
  for (int i = 0; i < 2; i++) {
    #pragma unroll
    for (int j = 0; j < 4; j++) {
      #pragma unroll
      for (int t = 0; t < 4; t++) {
        const int row = m0 + wm + i * 16 + g * 4 + t;
        const int col = n0 + wn + j * 16 + r;
        float v = acc[i][j][t];
        if (EPI == SE_GATE) {
          v += bias[col];
          float z = 1.f / (1.f + __expf(-v));
          const long ix = (long)row * 256 + col;
          v = (1.f - z) * aux1[ix] + z * aux2[ix];
        } else if (EPI == SE_SIG) {
          v = 1.f / (1.f + __expf(-v));
        } else { // SE_TANH
          v = tanhf(v);
        }
        C[(long)row * ldc + col] = v;
      }
    }
  }
}

// ---------------- small kernels ----------------

__global__ void cvt_n2e_colsum(const float* __restrict__ n2e, f16* __restrict__ n2e_h,
                               float* __restrict__ part) {
  const int n = blockIdx.x * 256 + threadIdx.x;
  const int c = blockIdx.y, b = blockIdx.z;
  const long base = (long)b * Ee * Nn + (long)c * 256 * Nn + n;
  float s = 0.f;
  for (int e = 0; e < 256; e++) {
    float v = n2e[base + (long)e * Nn];
    n2e_h[base + (long)e * Nn] = (f16)v;
    s += v;
  }
  part[((long)b * 16 + c) * Nn + n] = s;
}

__global__ void cvt_e2n_rowsum(const float* __restrict__ e2n, f16* __restrict__ e2n_h,
                               float* __restrict__ rno) {
  const long row = blockIdx.x;
  const int tid = threadIdx.x, lane = tid & 63, wid = tid >> 6;
  const float* p = e2n + row * Ee;
  f16* ph = e2n_h + row * Ee;
  float s = 0.f;
  for (int e = tid; e < Ee; e += 256) { float v = p[e]; ph[e] = (f16)v; s += v; }
  #pragma unroll
  for (int off = 32; off; off >>= 1) s += __shfl_down(s, off);
  __shared__ float wsum[4];
  if (lane == 0) wsum[wid] = s;
  __syncthreads();
  if (tid == 0) rno[row] = 1.f / (1.f + wsum[0] + wsum[1] + wsum[2] + wsum[3]);
}

__global__ void rowsum_kernel(const float* __restrict__ e2n, float* __restrict__ out) {
  const int gw = blockIdx.x * 4 + (threadIdx.x >> 6);
  const int lane = threadIdx.x & 63;
  const float* p = e2n + (long)gw * Ee;
  float s = 0.f;
  for (int e = lane; e < Ee; e += 64) s += p[e];
  #pragma unroll
  for (int off = 32; off; off >>= 1) s += __shfl_down(s, off);
  if (lane == 0) out[gw] = 1.f / (1.f + s);
}
__global__ void colsum_kernel(const float* __restrict__ n2e, float* __restrict__ part) {
  const int n = blockIdx.x * 256 + threadIdx.x;
  const int c = blockIdx.y, b = blockIdx.z;
  const float* p = n2e + (long)b * Ee * Nn + (long)c * 256 * Nn + n;
  float s = 0.f;
  for (int e = 0; e < 256; e++) s += p[(long)e * Nn];
  part[((long)b * 16 + c) * Nn + n] = s;
}
__global__ void colfin_kernel(const float* __restrict__ part, float* __restrict__ rni) {
  const int i = blockIdx.x * 256 + threadIdx.x;
  const int b = i >> 11, n = i & 2047;
  float s = 0.f;
  #pragma unroll
  for (int c = 0; c < 16; c++) s += part[((long)b * 16 + c) * Nn + n];
  rni[i] = 1.f / (1.f + s);
}

__global__ void cvt_half(const float* __restrict__ src, f16* __restrict__ dst) {
  const long i4 = (long)blockIdx.x * 256 + threadIdx.x;
  f32x4 v = *(const f32x4*)&src[i4 * 4];
  *(f16x4*)&dst[i4 * 4] = (f16x4){(f16)v.x, (f16)v.y, (f16)v.z, (f16)v.w};
}

// split conversion: hi plane at dst, lo plane at dst+loOff
__global__ void cvt_half_split(const float* __restrict__ src, f16* __restrict__ dst, long loOff) {
  const long i4 = (long)blockIdx.x * 256 + threadIdx.x;
  f32x4 v = *(const f32x4*)&src[i4 * 4];
  f16x4 h = {(f16)v.x, (f16)v.y, (f16)v.z, (f16)v.w};
  *(f16x4*)&dst[i4 * 4] = h;
  f16x4 l = {(f16)(v.x - (float)h[0]), (f16)(v.y - (float)h[1]),
             (f16)(v.z - (float)h[2]), (f16)(v.w - (float)h[3])};
  *(f16x4*)&dst[loOff + i4 * 4] = l;
}

__global__ void init_cur(const float* __restrict__ node_vec, float* __restrict__ cur,
                         f16* __restrict__ cur_h, long loOff) {
  const long i4 = (long)blockIdx.x * 256 + threadIdx.x;
  f32x4 v = *(const f32x4*)&node_vec[i4 * 4];
  *(f32x4*)&cur[i4 * 4] = v;
  f16x4 h = {(f16)v.x, (f16)v.y, (f16)v.z, (f16)v.w};
  *(f16x4*)&cur_h[i4 * 4] = h;
  f16x4 l = {(f16)(v.x - (float)h[0]), (f16)(v.y - (float)h[1]),
             (f16)(v.z - (float)h[2]), (f16)(v.w - (float)h[3])};
  *(f16x4*)&cur_h[loOff + i4 * 4] = l;
}

// cur [B*N,256] f32 -> cur_hT hi/lo planes [B][256][2048] halves
__global__ void transposeT(const float* __restrict__ cur, f16* __restrict__ curT, long loOff) {
  __shared__ f16 th[64][72];
  __shared__ f16 tl[64][72];
  const int b = blockIdx.z, nt = blockIdx.x * 64, dt = blockIdx.y * 64;
  const int tid = threadIdx.x;
  const int nl = tid >> 2, d0 = (tid & 3) * 16;
  const float* src = cur + ((long)b * Nn + nt + nl) * 256 + dt + d0;
  #pragma unroll
  for (int u = 0; u < 4; u++) {
    f32x4 v = *(const f32x4*)(src + 4 * u);
    f16x4 h = {(f16)v.x, (f16)v.y, (f16)v.z, (f16)v.w};
    *(f16x4*)&th[nl][d0 + 4 * u] = h;
    f16x4 l = {(f16)(v.x - (float)h[0]), (f16)(v.y - (float)h[1]),
               (f16)(v.z - (float)h[2]), (f16)(v.w - (float)h[3])};
    *(f16x4*)&tl[nl][d0 + 4 * u] = l;
  }
  __syncthreads();
  const int dl = tid >> 2, n0l = (tid & 3) * 16;
  f16x8 o0, o1, p0, p1;
  #pragma unroll
  for (int v = 0; v < 8; v++) {
    o0[v] = th[n0l + v][dl];     o1[v] = th[n0l + 8 + v][dl];
    p0[v] = tl[n0l + v][dl];     p1[v] = tl[n0l + 8 + v][dl];
  }
  f16* dst = curT + (long)b * (256 * Nn) + (long)(dt + dl) * Nn + nt + n0l;
  *(f16x8*)dst = o0;
  *(f16x8*)(dst + 8) = o1;
  *(f16x8*)(dst + loOff) = p0;
  *(f16x8*)(dst + loOff + 8) = p1;
}

__global__ void gruf_kernel(const float* __restrict__ urb, const float* __restrict__ m,
                            float* __restrict__ cur, f16* __restrict__ cur_h, long loOff) {
  const long i = (long)blockIdx.x * 256 + threadIdx.x;
  const long bn = i >> 8; const int d = i & 255;
  const float uu = urb[bn * 512 + d];
  const float v = (1.f - uu) * cur[i] + uu * m[i];
  cur[i] = v;
  f16 h = (f16)v;
  cur_h[i] = h;
  cur_h[loOff + i] = (f16)(v - (float)h);
}

__global__ void maxpool1(const float* __restrict__ pooled, float* __restrict__ part) {
  const int d = threadIdx.x, c = blockIdx.x, b = blockIdx.y;
  const float* p = pooled + ((long)b * Nn + c * 256) * Dd + d;
  float m = -INFINITY;
  for (int n = 0; n < 256; n++) m = fmaxf(m, p[(long)n * Dd]);
  part[(b * 8 + c) * Dd + d] = m;
}
__global__ void maxpool2(const float* __restrict__ part, float* __restrict__ out1) {
  const int d = threadIdx.x, b = blockIdx.x;
  float m = -INFINITY;
  #pragma unroll
  for (int c = 0; c < 8; c++) m = fmaxf(m, part[(b * 8 + c) * Dd + d]);
  out1[b * Dd + d] = m;
}
__global__ void transpose_out(const float* __restrict__ cur, float* __restrict__ out0) {
  const long i = (long)blockIdx.x * 256 + threadIdx.x;
  const int d = i & 255;
  const long nb = i >> 8;
  const int b = nb & 7;
  const long n = nb >> 3;
  out0[i] = cur[((long)b * Nn + n) * Dd + d];
}

extern "C" void kernel_launch(void* const* d_in, const int* in_sizes, int n_in,
                              void* d_out, int out_size, void* d_ws, size_t ws_size,
                              hipStream_t stream) {
  const float* node_vec = (const float*)d_in[0];
  const float* edge_vec = (const float*)d_in[1];
  const float* n2e      = (const float*)d_in[2];   // [B,E,N]
  const float* e2n      = (const float*)d_in[3];   // [B,N,E]
  const float* W_fuse   = (const float*)d_in[5];   // [256,512]
  const float* b_fuse   = (const float*)d_in[6];
  const float* W_z      = (const float*)d_in[7];   // [256,1024]
  const float* b_z      = (const float*)d_in[8];
  const float* W_u      = (const float*)d_in[9];
  const float* W_r      = (const float*)d_in[10];
  const float* W_m      = (const float*)d_in[11];
  const float* W_max    = (const float*)d_in[12];  // [256,256]

  const long ND  = (long)Bb * Nn * Dd;   // 4194304
  const long EDb = (long)Ee * Dd;        // 1048576
  const long NDb = (long)Nn * Dd;        // 524288
  const long ED  = (long)Bb * EDb;       // 8388608
  const long ADJ = (long)Bb * Ee * Nn;   // 67108864
  const int  BN  = Bb * Nn;

  // ---- arena ----
  char* p = (char*)d_ws;
  auto alloc = [&](size_t bytes) { char* r = p; p += (bytes + 255) & ~(size_t)255; return r; };

  const size_t need_full =
      (size_t)2 * ADJ * 2                  // n2e_h, e2n_h
      + (size_t)3 * ED * 2                 // ev_h, E1h, E2T
      + (size_t)4 * ND * 2                 // cur_h (2 planes), cur_hT (2 planes)
      + (size_t)(2 * 131072 + 2 * 65536) * 2
      + (size_t)5 * ND * 4                 // cur,outv,inv,nv,mb
      + (size_t)BN * 512 * 4               // urb
      + (size_t)(2 * BN + 16 * BN + BN) * 4
      + 64 * 1024;
  const bool full = ws_size >= need_full;

  f16 *n2e_h = nullptr, *e2n_h = nullptr;
  if (full) {
    n2e_h = (f16*)alloc(ADJ * 2);
    e2n_h = (f16*)alloc(ADJ * 2);
  }
  f16* ev_h    = (f16*)alloc(ED * 2);
  f16* E1h     = (f16*)alloc(ED * 2);
  f16* E2T     = (f16*)alloc(ED * 2);
  f16* cur_h   = (f16*)alloc(2 * ND * 2);      // hi + lo planes
  f16* cur_hT  = (f16*)alloc(2 * ND * 2);      // hi + lo planes
  f16* Wf_h    = (f16*)alloc(2 * 131072 * 2);  // hi + lo
  f16* Wmax_h  = (f16*)alloc(2 * 65536 * 2);   // hi + lo
  float* cur   = (float*)alloc(ND * 4);
  float* outv  = (float*)alloc(ND * 4);
  float* inv   = (float*)alloc(ND * 4);
  float* nv    = (float*)alloc(ND * 4);
  float* urb   = (float*)alloc((size_t)BN * 512 * 4);
  float* mb    = (float*)alloc(ND * 4);
  float* rno   = (float*)alloc(BN * 4);
  float* rni   = (float*)alloc(BN * 4);
  float* colpart = (float*)alloc((size_t)16 * BN * 4);
  float* maxpart = (float*)alloc(BN * 4);

  float* out0 = (float*)d_out;
  float* out1 = out0 + ND;

  // ---- one-time conversions + norms ----
  if (full) {
    cvt_n2e_colsum<<<dim3(Nn / 256, 16, Bb), 256, 0, stream>>>(n2e, n2e_h, colpart);
    colfin_kernel<<<BN / 256, 256, 0, stream>>>(colpart, rni);
    cvt_e2n_rowsum<<<BN, 256, 0, stream>>>(e2n, e2n_h, rno);
  } else {
    colsum_kernel<<<dim3(Nn / 256, 16, Bb), 256, 0, stream>>>(n2e, colpart);
    colfin_kernel<<<BN / 256, 256, 0, stream>>>(colpart, rni);
    rowsum_kernel<<<BN / 4, 256, 0, stream>>>(e2n, rno);
  }
  cvt_half<<<(int)(ED / 1024), 256, 0, stream>>>(edge_vec, ev_h);
  cvt_half_split<<<131072 / 1024, 256, 0, stream>>>(W_fuse, Wf_h, 131072);
  cvt_half_split<<<65536 / 1024, 256, 0, stream>>>(W_max, Wmax_h, 65536);
  init_cur<<<(int)(ND / 1024), 256, 0, stream>>>(node_vec, cur, cur_h, ND);
  transposeT<<<dim3(Nn / 64, 4, Bb), 256, 0, stream>>>(cur, cur_hT, ND);

  for (int h = 0; h < HOPS; h++) {
    // EO1 = n2e @ cur -> E1h (f16); B = cur_hT split (systematic operand)
    if (full)
      hgemm<HN, true, 1, EP_NONE, OH><<<dim3(2, Ee / 64, Bb), 256, 0, stream>>>(
          n2e_h, nullptr, cur_hT, E1h, nullptr, nullptr, nullptr,
          Ee, 256, Nn, Nn, Nn, 256, (long)Ee * Nn, NDb, EDb, 0, 0, 0, ND);
    else
      hgemm<HN, false, 1, EP_NONE, OH><<<dim3(2, Ee / 64, Bb), 256, 0, stream>>>(
          n2e, nullptr, cur_hT, E1h, nullptr, nullptr, nullptr,
          Ee, 256, Nn, Nn, Nn, 256, (long)Ee * Nn, NDb, EDb, 0, 0, 0, ND);
    // EO2 = relu(concat(E1, ev) @ Wf^T + b) -> E2T; B = Wf split (systematic)
    hgemm<HC2, true, 1, EP_RELUB, OHT><<<dim3(2, Ee / 64, Bb), 256, 0, stream>>>(
        E1h, ev_h, Wf_h, E2T, nullptr, nullptr, b_fuse,
        Ee, 256, 512, 256, 512, Ee, EDb, 0, EDb, 0, 0, 0, 131072);
    // out_vec = (e2n @ EO2 + cur) * rno -> outv; nonneg aggregation (attenuated)
    if (full)
      hgemm<HN, true, 0, EP_AGG, OF><<<dim3(2, Nn / 64, Bb), 256, 0, stream>>>(
          e2n_h, nullptr, E2T, outv, cur, rno, nullptr,
          Nn, 256, Ee, Ee, Ee, 256, (long)Nn * Ee, EDb, NDb, NDb, (long)Nn, 0, 0);
    else
      hgemm<HN, false, 0, EP_AGG, OF><<<dim3(2, Nn / 64, Bb), 256, 0, stream>>>(
          e2n, nullptr, E2T, outv, cur, rno, nullptr,
          Nn, 256, Ee, Ee, Ee, 256, (long)Nn * Ee, EDb, NDb, NDb, (long)Nn, 0, 0);
    // EI1 = e2n^T @ cur -> E1h; B = cur_hT split
    if (full)
      hgemm<HT, true, 1, EP_NONE, OH><<<dim3(2, Ee / 64, Bb), 256, 0, stream>>>(
          e2n_h, nullptr, cur_hT, E1h, nullptr, nullptr, nullptr,
          Ee, 256, Nn, Ee, Nn, 256, (long)Nn * Ee, NDb, EDb, 0, 0, 0, ND);
    else
      hgemm<HT, false, 1, EP_NONE, OH><<<dim3(2, Ee / 64, Bb), 256, 0, stream>>>(
          e2n, nullptr, cur_hT, E1h, nullptr, nullptr, nullptr,
          Ee, 256, Nn, Ee, Nn, 256, (long)Nn * Ee, NDb, EDb, 0, 0, 0, ND);
    // EI2 -> E2T
    hgemm<HC2, true, 1, EP_RELUB, OHT><<<dim3(2, Ee / 64, Bb), 256, 0, stream>>>(
        E1h, ev_h, Wf_h, E2T, nullptr, nullptr, b_fuse,
        Ee, 256, 512, 256, 512, Ee, EDb, 0, EDb, 0, 0, 0, 131072);
    // in_vec = (n2e^T @ EI2 + cur) * rni -> inv
    if (full)
      hgemm<HT, true, 0, EP_AGG, OF><<<dim3(2, Nn / 64, Bb), 256, 0, stream>>>(
          n2e_h, nullptr, E2T, inv, cur, rni, nullptr,
          Nn, 256, Ee, Nn, Ee, 256, (long)Ee * Nn, EDb, NDb, NDb, (long)Nn, 0, 0);
    else
      hgemm<HT, false, 0, EP_AGG, OF><<<dim3(2, Nn / 64, Bb), 256, 0, stream>>>(
          n2e, nullptr, E2T, inv, cur, rni, nullptr,
          Nn, 256, Ee, Nn, Ee, 256, (long)Ee * Nn, EDb, NDb, NDb, (long)Nn, 0, 0);
    // gated fusion: nv = (1-z)*inv + z*outv  [split-bf16]
    sgemm<SM_G4, SE_GATE><<<dim3(2, BN / 64, 1), 256, 0, stream>>>(
        inv, outv, nullptr, W_z, nullptr, nv, inv, outv, b_z, 256, 1024, 256, 1024, 256);
    // u|r = sigmoid(concat(cur,nv) @ [W_u;W_r]^T) -> urb [BN,512]
    sgemm<SM_CN, SE_SIG><<<dim3(4, BN / 64, 1), 256, 0, stream>>>(
        cur, nv, nullptr, W_u, W_r, urb, nullptr, nullptr, nullptr, 512, 512, 256, 512, 512);
    // m = tanh(concat(r*cur, nv) @ W_m^T) -> mb
    sgemm<SM_RC, SE_TANH><<<dim3(2, BN / 64, 1), 256, 0, stream>>>(
        urb + 256, cur, nv, W_m, nullptr, mb, nullptr, nullptr, nullptr, 256, 512, 512, 512, 256);
    // cur = (1-u)*cur + u*m  (+ split halves)
    gruf_kernel<<<(int)(ND / 256), 256, 0, stream>>>(urb, mb, cur, cur_h, ND);
    if (h < HOPS - 1)
      transposeT<<<dim3(Nn / 64, 4, Bb), 256, 0, stream>>>(cur, cur_hT, ND);
  }

  // pooled = cur @ W_max^T -> urb (f32); both operands split (output-1 path)
  hgemm<HN, true, 3, EP_NONE, OF><<<dim3(2, BN / 64, 1), 256, 0, stream>>>(
      cur_h, nullptr, Wmax_h, urb, nullptr, nullptr, nullptr,
      BN, 256, 256, 256, 256, 256, 0, 0, 0, 0, 0, ND, 65536);
  maxpool1<<<dim3(8, Bb), 256, 0, stream>>>(urb, maxpart);
  maxpool2<<<Bb, 256, 0, stream>>>(maxpart, out1);

  transpose_out<<<(int)(ND / 256), 256, 0, stream>>>(cur, out0);
}

// Round 7
// 2233.046 us; speedup vs baseline: 1.4808x; 1.1521x over previous
//
#include <hip/hip_runtime.h>
#include <math.h>

#define Bb 8
#define Nn 2048
#define Ee 4096
#define Dd 256
#define HOPS 3
#define LDK 40   // sgemm LDS k-stride (16-bit elems)

typedef __attribute__((ext_vector_type(4))) float f32x4;
typedef _Float16 f16;
typedef __attribute__((ext_vector_type(8))) _Float16 f16x8;
typedef __attribute__((ext_vector_type(4))) _Float16 f16x4;
typedef __attribute__((ext_vector_type(8))) short s16x8;
typedef __attribute__((ext_vector_type(4))) short s16x4;

__device__ __forceinline__ short f2bf(float f){
  union{float f; unsigned u;} x; x.f=f;
  unsigned r = (x.u + 0x7fffu + ((x.u>>16)&1u)) >> 16;
  return (short)r;
}
__device__ __forceinline__ float bf2f(short h){
  union{unsigned u; float f;} x; x.u = ((unsigned)(unsigned short)h) << 16; return x.f;
}

enum { HN=0, HT=1, HC2=2 };            // hgemm A modes
enum { OF=0, OH=1, OHT=2 };            // hgemm output: f32 / f16 / f16-transposed
enum { EP_NONE=0, EP_RELUB, EP_AGG };  // hgemm epilogues
enum { SM_CN=0, SM_G4, SM_RC };        // sgemm A modes
enum { SE_GATE=0, SE_SIG, SE_TANH };   // sgemm epilogues

// ---------------- fp16 MFMA GEMM: tile 64x128, BK=64, 4 waves 2x2 ----------------
// Reg-staged double buffer (2-phase): issue tile t+1 global loads BEFORE tile t
// MFMA; LDS write after the post-MFMA barrier. SPL bit0: B lo plane at +bLo;
// bit1: A lo plane at +aLo (split-fp16 for systematic-error operands).
template<int AMODE, bool AH, int SPL, int EPI, int OUTM>
__global__ __launch_bounds__(256) void hgemm(
    const void* __restrict__ Av, const f16* __restrict__ A2,
    const f16* __restrict__ Bh, void* __restrict__ Cv,
    const float* __restrict__ aux1, const float* __restrict__ aux2,
    const float* __restrict__ bias,
    int M, int Nd, int K, int lda, int ldb, int ldc,
    long sA, long sB, long sC, long sAux1, long sAux2,
    long aLo, long bLo)
{
  const int bz = blockIdx.z;
  const char* Ab = (const char*)Av + (AH ? bz * sA * 2 : bz * sA * 4);
  if (A2) A2 += bz * sA;
  Bh += bz * sB;
  char* Cb = (char*)Cv + ((OUTM == OF) ? bz * sC * 4 : bz * sC * 2);
  if (aux1) aux1 += bz * sAux1;
  if (aux2) aux2 += bz * sAux2;
  const int m0 = blockIdx.y * 64;
  const int n0 = blockIdx.x * 128;

  constexpr int LK = 72;                 // 144B rows: frag reads ~2-way banks
  constexpr int HLA = 64 * LK;
  constexpr int HLB = 128 * LK;
  __shared__ f16 As[64 * LK * ((SPL & 2) ? 2 : 1)];
  __shared__ f16 Bs[128 * LK * ((SPL & 1) ? 2 : 1)];

  const int tid = threadIdx.x;
  const int wid = tid >> 6, lane = tid & 63;
  const int wm = (wid >> 1) * 32, wn = (wid & 1) * 64;
  const int r = lane & 15, g = lane >> 4;

  f32x4 acc[2][4];
  #pragma unroll
  for (int i = 0; i < 2; i++)
    #pragma unroll
    for (int j = 0; j < 4; j++) acc[i][j] = (f32x4){0.f, 0.f, 0.f, 0.f};

  f16x8 ra0, ra1, rl0, rl1;   // staged A (16 halves + lo)
  f16x8 rb[4], rbl[4];        // staged B (32 halves + lo)

  auto loadA = [&](int k0) {
    if (AMODE == HN && AH) {
      const f16* Ah = (const f16*)Ab;
      const int row = tid >> 2, kc = (tid & 3) * 16;
      const long off = (long)(m0 + row) * lda + k0 + kc;
      ra0 = *(const f16x8*)&Ah[off];
      ra1 = *(const f16x8*)&Ah[off + 8];
      if (SPL & 2) { rl0 = *(const f16x8*)&Ah[aLo + off]; rl1 = *(const f16x8*)&Ah[aLo + off + 8]; }
    } else if (AMODE == HN && !AH) {
      const float* Af = (const float*)Ab;
      const int row = tid >> 2, kc = (tid & 3) * 16;
      const float* s = &Af[(long)(m0 + row) * lda + k0 + kc];
      f32x4 v0 = *(const f32x4*)s,       v1 = *(const f32x4*)(s + 4);
      f32x4 v2 = *(const f32x4*)(s + 8), v3 = *(const f32x4*)(s + 12);
      ra0 = (f16x8){(f16)v0.x,(f16)v0.y,(f16)v0.z,(f16)v0.w,(f16)v1.x,(f16)v1.y,(f16)v1.z,(f16)v1.w};
      ra1 = (f16x8){(f16)v2.x,(f16)v2.y,(f16)v2.z,(f16)v2.w,(f16)v3.x,(f16)v3.y,(f16)v3.z,(f16)v3.w};
    } else if (AMODE == HT) {
      const int mm = tid & 63, kh = (tid >> 6) * 16;
      if (AH) {
        const f16* s = &((const f16*)Ab)[(long)(k0 + kh) * lda + m0 + mm];
        #pragma unroll
        for (int j = 0; j < 8; j++) ra0[j] = s[(long)j * lda];
        #pragma unroll
        for (int j = 0; j < 8; j++) ra1[j] = s[(long)(j + 8) * lda];
      } else {
        const float* s = &((const float*)Ab)[(long)(k0 + kh) * lda + m0 + mm];
        #pragma unroll
        for (int j = 0; j < 8; j++) ra0[j] = (f16)s[(long)j * lda];
        #pragma unroll
        for (int j = 0; j < 8; j++) ra1[j] = (f16)s[(long)(j + 8) * lda];
      }
    } else { // HC2: concat(A, A2) halves along k, pitch 256
      const int row = tid >> 2, kc = (tid & 3) * 16;
      const int kk = k0 + kc;
      const f16* s = (kk < 256) ? &((const f16*)Ab)[(long)(m0 + row) * 256 + kk]
                                : &A2[(long)(m0 + row) * 256 + (kk - 256)];
      ra0 = ((const f16x8*)s)[0];
      ra1 = ((const f16x8*)s)[1];
    }
  };
  auto storeA = [&]() {
    if (AMODE == HT) {
      const int mm = tid & 63, kh = (tid >> 6) * 16;
      *(f16x8*)&As[mm * LK + kh] = ra0;
      *(f16x8*)&As[mm * LK + kh + 8] = ra1;
    } else {
      const int row = tid >> 2, kc = (tid & 3) * 16;
      *(f16x8*)&As[row * LK + kc] = ra0;
      *(f16x8*)&As[row * LK + kc + 8] = ra1;
      if (SPL & 2) {
        *(f16x8*)&As[HLA + row * LK + kc] = rl0;
        *(f16x8*)&As[HLA + row * LK + kc + 8] = rl1;
      }
    }
  };
  auto loadB = [&](int k0) {
    const int row = tid >> 1, kc = (tid & 1) * 32;
    const long off = (long)(n0 + row) * ldb + k0 + kc;
    #pragma unroll
    for (int u = 0; u < 4; u++) rb[u] = *(const f16x8*)&Bh[off + 8 * u];
    if (SPL & 1) {
      #pragma unroll
      for (int u = 0; u < 4; u++) rbl[u] = *(const f16x8*)&Bh[bLo + off + 8 * u];
    }
  };
  auto storeB = [&]() {
    const int row = tid >> 1, kc = (tid & 1) * 32;
    #pragma unroll
    for (int u = 0; u < 4; u++) *(f16x8*)&Bs[row * LK + kc + 8 * u] = rb[u];
    if (SPL & 1) {
      #pragma unroll
      for (int u = 0; u < 4; u++) *(f16x8*)&Bs[HLB + row * LK + kc + 8 * u] = rbl[u];
    }
  };

  loadA(0); loadB(0);
  storeA(); storeB();
  __syncthreads();

  const int NT = K >> 6;
  for (int t = 0; t < NT; t++) {
    const bool more = (t + 1 < NT);
    if (more) { loadA((t + 1) << 6); loadB((t + 1) << 6); }  // issue early: hides under MFMA
    #pragma unroll
    for (int ks = 0; ks < 2; ks++) {
      f16x8 af[2], bf[4], afl[2], bfl[4];
      #pragma unroll
      for (int i = 0; i < 2; i++) {
        af[i] = *(const f16x8*)&As[(wm + i*16 + r) * LK + ks*32 + g*8];
        if (SPL & 2) afl[i] = *(const f16x8*)&As[HLA + (wm + i*16 + r) * LK + ks*32 + g*8];
      }
      #pragma unroll
      for (int j = 0; j < 4; j++) {
        bf[j] = *(const f16x8*)&Bs[(wn + j*16 + r) * LK + ks*32 + g*8];
        if (SPL & 1) bfl[j] = *(const f16x8*)&Bs[HLB + (wn + j*16 + r) * LK + ks*32 + g*8];
      }
      #pragma unroll
      for (int i = 0; i < 2; i++)
        #pragma unroll
        for (int j = 0; j < 4; j++) {
          acc[i][j] = __builtin_amdgcn_mfma_f32_16x16x32_f16(af[i], bf[j], acc[i][j], 0, 0, 0);
          if (SPL & 1)
            acc[i][j] = __builtin_amdgcn_mfma_f32_16x16x32_f16(af[i], bfl[j], acc[i][j], 0, 0, 0);
          if (SPL & 2)
            acc[i][j] = __builtin_amdgcn_mfma_f32_16x16x32_f16(afl[i], bf[j], acc[i][j], 0, 0, 0);
        }
    }
    __syncthreads();
    if (more) { storeA(); storeB(); __syncthreads(); }
  }

  // ---- epilogue: C map col=lane&15, row=(lane>>4)*4+t
  #pragma unroll
  for (int i = 0; i < 2; i++) {
    #pragma unroll
    for (int j = 0; j < 4; j++) {
      const int rowb = m0 + wm + i * 16 + g * 4;
      const int col = n0 + wn + j * 16 + r;
      if (OUTM == OHT) {
        f16x4 hv;
        #pragma unroll
        for (int t = 0; t < 4; t++) {
          float v = acc[i][j][t];
          if (EPI == EP_RELUB) { v += bias[col]; v = v > 0.f ? v : 0.f; }
          hv[t] = (f16)v;
        }
        *(f16x4*)&((f16*)Cb)[(long)col * ldc + rowb] = hv;
      } else {
        #pragma unroll
        for (int t = 0; t < 4; t++) {
          const int row = rowb + t;
          const long idx = (long)row * ldc + col;
          float v = acc[i][j][t];
          if (EPI == EP_RELUB)    { v += bias[col]; v = v > 0.f ? v : 0.f; }
          else if (EPI == EP_AGG) { v = (v + aux1[idx]) * aux2[row]; }
          if (OUTM == OH) ((f16*)Cb)[idx] = (f16)v;
          else            ((float*)Cb)[idx] = v;
        }
      }
    }
  }
}

// ---------------- split-bf16 gate GEMM (validated numerics), tile 64x128 ----------------
template<int AMODE, int EPI>
__global__ __launch_bounds__(256) void sgemm(
    const float* __restrict__ A, const float* __restrict__ A2, const float* __restrict__ A3,
    const float* __restrict__ Bm, const float* __restrict__ Bm2, float* __restrict__ C,
    const float* __restrict__ aux1, const float* __restrict__ aux2, const float* __restrict__ bias,
    int Nd, int K, int lda, int ldb, int ldc)
{
  const int m0 = blockIdx.y * 64;
  const int n0 = blockIdx.x * 128;

  constexpr int HLA = 64 * LDK;
  constexpr int HLB = 128 * LDK;
  __shared__ short As[64 * LDK * 2];
  __shared__ short Bs[128 * LDK * 2];

  const int tid = threadIdx.x;
  const int wid = tid >> 6, lane = tid & 63;
  const int wm = (wid >> 1) * 32, wn = (wid & 1) * 64;
  const int r = lane & 15, g = lane >> 4;

  f32x4 acc[2][4];
  #pragma unroll
  for (int i = 0; i < 2; i++)
    #pragma unroll
    for (int j = 0; j < 4; j++) acc[i][j] = (f32x4){0.f, 0.f, 0.f, 0.f};

  auto stq = [&](short* dst, int HL, f32x4 v) {
    s16x4 h = { f2bf(v.x), f2bf(v.y), f2bf(v.z), f2bf(v.w) };
    *(s16x4*)dst = h;
    s16x4 l = { f2bf(v.x - bf2f(h.x)), f2bf(v.y - bf2f(h.y)),
                f2bf(v.z - bf2f(h.z)), f2bf(v.w - bf2f(h.w)) };
    *(s16x4*)(dst + HL) = l;
  };

  for (int k0 = 0; k0 < K; k0 += 32) {
    { // A staging (fused features)
      const int row = tid >> 2, kq = (tid & 3) * 8;
      const int kk = k0 + kq, q = kk >> 8, kd = kk & 255;
      const long base = (long)(m0 + row) * 256 + kd;
      const long baseA = (long)(m0 + row) * lda + kd;
      #pragma unroll
      for (int u = 0; u < 2; u++) {
        f32x4 v;
        if (AMODE == SM_CN) {
          v = (q == 0) ? *(const f32x4*)(A + base + 4 * u)
                       : *(const f32x4*)(A2 + base + 4 * u);
        } else if (AMODE == SM_G4) {
          if (q == 0)      v = *(const f32x4*)(A  + base + 4 * u);
          else if (q == 1) v = *(const f32x4*)(A2 + base + 4 * u);
          else {
            f32x4 x = *(const f32x4*)(A  + base + 4 * u);
            f32x4 y = *(const f32x4*)(A2 + base + 4 * u);
            v = (q == 2) ? x * y : x - y;
          }
        } else { // SM_RC
          if (q == 0) {
            f32x4 x = *(const f32x4*)(A  + baseA + 4 * u);
            f32x4 y = *(const f32x4*)(A2 + base + 4 * u);
            v = x * y;
          } else v = *(const f32x4*)(A3 + base + 4 * u);
        }
        stq(&As[row * LDK + kq + 4 * u], HLA, v);
      }
    }
    { // B staging (fp32 weights, split)
      const int row = tid >> 1, kq = (tid & 1) * 16;
      const int rowg = n0 + row;
      const float* src = (Bm2 != nullptr && rowg >= 256)
                         ? &Bm2[(long)(rowg - 256) * ldb + k0 + kq]
                         : &Bm[(long)rowg * ldb + k0 + kq];
      #pragma unroll
      for (int u = 0; u < 4; u++)
        stq(&Bs[row * LDK + kq + 4 * u], HLB, *(const f32x4*)(src + 4 * u));
    }
    __syncthreads();

    s16x8 ah[2], bh[4], al[2], bl[4];
    #pragma unroll
    for (int i = 0; i < 2; i++) {
      ah[i] = *(const s16x8*)&As[(wm + i*16 + r) * LDK + g * 8];
      al[i] = *(const s16x8*)&As[HLA + (wm + i*16 + r) * LDK + g * 8];
    }
    #pragma unroll
    for (int j = 0; j < 4; j++) {
      bh[j] = *(const s16x8*)&Bs[(wn + j*16 + r) * LDK + g * 8];
      bl[j] = *(const s16x8*)&Bs[HLB + (wn + j*16 + r) * LDK + g * 8];
    }
    #pragma unroll
    for (int i = 0; i < 2; i++)
      #pragma unroll
      for (int j = 0; j < 4; j++) {
        acc[i][j] = __builtin_amdgcn_mfma_f32_16x16x32_bf16(ah[i], bh[j], acc[i][j], 0, 0, 0);
        acc[i][j] = __builtin_amdgcn_mfma_f32_16x16x32_bf16(ah[i], bl[j], acc[i][j], 0, 0, 0);
        acc[i][j] = __builtin_amdgcn_mfma_f32_16x16x32_bf16(al[i], bh[j], acc[i][j], 0, 0, 0);
      }
    __syncthreads();
  }

  #pragma unroll
  for (int i = 0; i < 2; i++) {
    #pragma unroll
    for (int j = 0; j < 4; j++) {
      #pragma unroll
      for (int t = 0; t < 4; t++) {
        const int row = m0 + wm + i * 16 + g * 4 + t;
        const int col = n0 + wn + j * 16 + r;
        float v = acc[i][j][t];
        if (EPI == SE_GATE) {
          v += bias[col];
          float z = 1.f / (1.f + __expf(-v));
          const long ix = (long)row * 256 + col;
          v = (1.f - z) * aux1[ix] + z * aux2[ix];
        } else if (EPI == SE_SIG) {
          v = 1.f / (1.f + __expf(-v));
        } else { // SE_TANH
          v = tanhf(v);
        }
        C[(long)row * ldc + col] = v;
      }
    }
  }
}

// ---------------- small kernels ----------------

__global__ void cvt_n2e_colsum(const float* __restrict__ n2e, f16* __restrict__ n2e_h,
                               float* __restrict__ part) {
  const int n = blockIdx.x * 256 + threadIdx.x;
  const int c = blockIdx.y, b = blockIdx.z;
  const long base = (long)b * Ee * Nn + (long)c * 256 * Nn + n;
  float s = 0.f;
  for (int e = 0; e < 256; e++) {
    float v = n2e[base + (long)e * Nn];
    n2e_h[base + (long)e * Nn] = (f16)v;
    s += v;
  }
  part[((long)b * 16 + c) * Nn + n] = s;
}

__global__ void cvt_e2n_rowsum(const float* __restrict__ e2n, f16* __restrict__ e2n_h,
                               float* __restrict__ rno) {
  const long row = blockIdx.x;
  const int tid = threadIdx.x, lane = tid & 63, wid = tid >> 6;
  const float* p = e2n + row * Ee;
  f16* ph = e2n_h + row * Ee;
  float s = 0.f;
  for (int e = tid; e < Ee; e += 256) { float v = p[e]; ph[e] = (f16)v; s += v; }
  #pragma unroll
  for (int off = 32; off; off >>= 1) s += __shfl_down(s, off);
  __shared__ float wsum[4];
  if (lane == 0) wsum[wid] = s;
  __syncthreads();
  if (tid == 0) rno[row] = 1.f / (1.f + wsum[0] + wsum[1] + wsum[2] + wsum[3]);
}

// f16 [R][C] -> [C][R] transpose, 64x64 LDS tiles
__global__ void adjT(const f16* __restrict__ in, f16* __restrict__ out, int R, int C) {
  __shared__ f16 t[64][72];
  const long boff = (long)blockIdx.z * R * C;
  const int r0 = blockIdx.x * 64, c0 = blockIdx.y * 64;
  const int tid = threadIdx.x;
  const int rl = tid >> 2, cl = (tid & 3) * 16;
  const f16* src = in + boff + (long)(r0 + rl) * C + c0 + cl;
  *(f16x8*)&t[rl][cl]     = *(const f16x8*)src;
  *(f16x8*)&t[rl][cl + 8] = *(const f16x8*)(src + 8);
  __syncthreads();
  const int cl2 = tid >> 2, rl2 = (tid & 3) * 16;
  f16x8 o0, o1;
  #pragma unroll
  for (int v = 0; v < 8; v++) { o0[v] = t[rl2 + v][cl2]; o1[v] = t[rl2 + 8 + v][cl2]; }
  f16* dst = out + boff + (long)(c0 + cl2) * R + r0 + rl2;
  *(f16x8*)dst = o0;
  *(f16x8*)(dst + 8) = o1;
}

__global__ void rowsum_kernel(const float* __restrict__ e2n, float* __restrict__ out) {
  const int gw = blockIdx.x * 4 + (threadIdx.x >> 6);
  const int lane = threadIdx.x & 63;
  const float* p = e2n + (long)gw * Ee;
  float s = 0.f;
  for (int e = lane; e < Ee; e += 64) s += p[e];
  #pragma unroll
  for (int off = 32; off; off >>= 1) s += __shfl_down(s, off);
  if (lane == 0) out[gw] = 1.f / (1.f + s);
}
__global__ void colsum_kernel(const float* __restrict__ n2e, float* __restrict__ part) {
  const int n = blockIdx.x * 256 + threadIdx.x;
  const int c = blockIdx.y, b = blockIdx.z;
  const float* p = n2e + (long)b * Ee * Nn + (long)c * 256 * Nn + n;
  float s = 0.f;
  for (int e = 0; e < 256; e++) s += p[(long)e * Nn];
  part[((long)b * 16 + c) * Nn + n] = s;
}
__global__ void colfin_kernel(const float* __restrict__ part, float* __restrict__ rni) {
  const int i = blockIdx.x * 256 + threadIdx.x;
  const int b = i >> 11, n = i & 2047;
  float s = 0.f;
  #pragma unroll
  for (int c = 0; c < 16; c++) s += part[((long)b * 16 + c) * Nn + n];
  rni[i] = 1.f / (1.f + s);
}

__global__ void cvt_half(const float* __restrict__ src, f16* __restrict__ dst) {
  const long i4 = (long)blockIdx.x * 256 + threadIdx.x;
  f32x4 v = *(const f32x4*)&src[i4 * 4];
  *(f16x4*)&dst[i4 * 4] = (f16x4){(f16)v.x, (f16)v.y, (f16)v.z, (f16)v.w};
}

__global__ void cvt_half_split(const float* __restrict__ src, f16* __restrict__ dst, long loOff) {
  const long i4 = (long)blockIdx.x * 256 + threadIdx.x;
  f32x4 v = *(const f32x4*)&src[i4 * 4];
  f16x4 h = {(f16)v.x, (f16)v.y, (f16)v.z, (f16)v.w};
  *(f16x4*)&dst[i4 * 4] = h;
  f16x4 l = {(f16)(v.x - (float)h[0]), (f16)(v.y - (float)h[1]),
             (f16)(v.z - (float)h[2]), (f16)(v.w - (float)h[3])};
  *(f16x4*)&dst[loOff + i4 * 4] = l;
}

__global__ void init_cur(const float* __restrict__ node_vec, float* __restrict__ cur,
                         f16* __restrict__ cur_h, long loOff) {
  const long i4 = (long)blockIdx.x * 256 + threadIdx.x;
  f32x4 v = *(const f32x4*)&node_vec[i4 * 4];
  *(f32x4*)&cur[i4 * 4] = v;
  f16x4 h = {(f16)v.x, (f16)v.y, (f16)v.z, (f16)v.w};
  *(f16x4*)&cur_h[i4 * 4] = h;
  f16x4 l = {(f16)(v.x - (float)h[0]), (f16)(v.y - (float)h[1]),
             (f16)(v.z - (float)h[2]), (f16)(v.w - (float)h[3])};
  *(f16x4*)&cur_h[loOff + i4 * 4] = l;
}

// cur [B*N,256] f32 -> cur_hT hi/lo planes [B][256][2048] halves
__global__ void transposeT(const float* __restrict__ cur, f16* __restrict__ curT, long loOff) {
  __shared__ f16 th[64][72];
  __shared__ f16 tl[64][72];
  const int b = blockIdx.z, nt = blockIdx.x * 64, dt = blockIdx.y * 64;
  const int tid = threadIdx.x;
  const int nl = tid >> 2, d0 = (tid & 3) * 16;
  const float* src = cur + ((long)b * Nn + nt + nl) * 256 + dt + d0;
  #pragma unroll
  for (int u = 0; u < 4; u++) {
    f32x4 v = *(const f32x4*)(src + 4 * u);
    f16x4 h = {(f16)v.x, (f16)v.y, (f16)v.z, (f16)v.w};
    *(f16x4*)&th[nl][d0 + 4 * u] = h;
    f16x4 l = {(f16)(v.x - (float)h[0]), (f16)(v.y - (float)h[1]),
               (f16)(v.z - (float)h[2]), (f16)(v.w - (float)h[3])};
    *(f16x4*)&tl[nl][d0 + 4 * u] = l;
  }
  __syncthreads();
  const int dl = tid >> 2, n0l = (tid & 3) * 16;
  f16x8 o0, o1, p0, p1;
  #pragma unroll
  for (int v = 0; v < 8; v++) {
    o0[v] = th[n0l + v][dl];     o1[v] = th[n0l + 8 + v][dl];
    p0[v] = tl[n0l + v][dl];     p1[v] = tl[n0l + 8 + v][dl];
  }
  f16* dst = curT + (long)b * (256 * Nn) + (long)(dt + dl) * Nn + nt + n0l;
  *(f16x8*)dst = o0;
  *(f16x8*)(dst + 8) = o1;
  *(f16x8*)(dst + loOff) = p0;
  *(f16x8*)(dst + loOff + 8) = p1;
}

__global__ void gruf_kernel(const float* __restrict__ urb, const float* __restrict__ m,
                            float* __restrict__ cur, f16* __restrict__ cur_h, long loOff) {
  const long i = (long)blockIdx.x * 256 + threadIdx.x;
  const long bn = i >> 8; const int d = i & 255;
  const float uu = urb[bn * 512 + d];
  const float v = (1.f - uu) * cur[i] + uu * m[i];
  cur[i] = v;
  f16 h = (f16)v;
  cur_h[i] = h;
  cur_h[loOff + i] = (f16)(v - (float)h);
}

__global__ void maxpool1(const float* __restrict__ pooled, float* __restrict__ part) {
  const int d = threadIdx.x, c = blockIdx.x, b = blockIdx.y;
  const float* p = pooled + ((long)b * Nn + c * 256) * Dd + d;
  float m = -INFINITY;
  for (int n = 0; n < 256; n++) m = fmaxf(m, p[(long)n * Dd]);
  part[(b * 8 + c) * Dd + d] = m;
}
__global__ void maxpool2(const float* __restrict__ part, float* __restrict__ out1) {
  const int d = threadIdx.x, b = blockIdx.x;
  float m = -INFINITY;
  #pragma unroll
  for (int c = 0; c < 8; c++) m = fmaxf(m, part[(b * 8 + c) * Dd + d]);
  out1[b * Dd + d] = m;
}
__global__ void transpose_out(const float* __restrict__ cur, float* __restrict__ out0) {
  const long i = (long)blockIdx.x * 256 + threadIdx.x;
  const int d = i & 255;
  const long nb = i >> 8;
  const int b = nb & 7;
  const long n = nb >> 3;
  out0[i] = cur[((long)b * Nn + n) * Dd + d];
}

extern "C" void kernel_launch(void* const* d_in, const int* in_sizes, int n_in,
                              void* d_out, int out_size, void* d_ws, size_t ws_size,
                              hipStream_t stream) {
  const float* node_vec = (const float*)d_in[0];
  const float* edge_vec = (const float*)d_in[1];
  const float* n2e      = (const float*)d_in[2];   // [B,E,N]
  const float* e2n      = (const float*)d_in[3];   // [B,N,E]
  const float* W_fuse   = (const float*)d_in[5];   // [256,512]
  const float* b_fuse   = (const float*)d_in[6];
  const float* W_z      = (const float*)d_in[7];   // [256,1024]
  const float* b_z      = (const float*)d_in[8];
  const float* W_u      = (const float*)d_in[9];
  const float* W_r      = (const float*)d_in[10];
  const float* W_m      = (const float*)d_in[11];
  const float* W_max    = (const float*)d_in[12];  // [256,256]

  const long ND  = (long)Bb * Nn * Dd;   // 4194304
  const long EDb = (long)Ee * Dd;        // 1048576
  const long NDb = (long)Nn * Dd;        // 524288
  const long ED  = (long)Bb * EDb;       // 8388608
  const long ADJ = (long)Bb * Ee * Nn;   // 67108864
  const int  BN  = Bb * Nn;

  // ---- arena ----
  char* p = (char*)d_ws;
  auto alloc = [&](size_t bytes) { char* r = p; p += (bytes + 255) & ~(size_t)255; return r; };

  const size_t need_full =
      (size_t)4 * ADJ * 2                  // n2e_h, e2n_h + both transposes
      + (size_t)3 * ED * 2                 // ev_h, E1h, E2T
      + (size_t)4 * ND * 2                 // cur_h, cur_hT (hi+lo each)
      + (size_t)(2 * 131072 + 2 * 65536) * 2
      + (size_t)5 * ND * 4                 // cur,outv,inv,nv,mb
      + (size_t)BN * 512 * 4               // urb
      + (size_t)(2 * BN + 16 * BN + BN) * 4
      + 64 * 1024;
  const bool full = ws_size >= need_full;

  f16 *n2e_h = nullptr, *e2n_h = nullptr, *n2e_hT = nullptr, *e2n_hT = nullptr;
  if (full) {
    n2e_h  = (f16*)alloc(ADJ * 2);   // [B][E][N]
    e2n_h  = (f16*)alloc(ADJ * 2);   // [B][N][E]
    n2e_hT = (f16*)alloc(ADJ * 2);   // [B][N][E]
    e2n_hT = (f16*)alloc(ADJ * 2);   // [B][E][N]
  }
  f16* ev_h    = (f16*)alloc(ED * 2);
  f16* E1h     = (f16*)alloc(ED * 2);
  f16* E2T     = (f16*)alloc(ED * 2);
  f16* cur_h   = (f16*)alloc(2 * ND * 2);      // hi + lo planes
  f16* cur_hT  = (f16*)alloc(2 * ND * 2);      // hi + lo planes
  f16* Wf_h    = (f16*)alloc(2 * 131072 * 2);  // hi + lo
  f16* Wmax_h  = (f16*)alloc(2 * 65536 * 2);   // hi + lo
  float* cur   = (float*)alloc(ND * 4);
  float* outv  = (float*)alloc(ND * 4);
  float* inv   = (float*)alloc(ND * 4);
  float* nv    = (float*)alloc(ND * 4);
  float* urb   = (float*)alloc((size_t)BN * 512 * 4);
  float* mb    = (float*)alloc(ND * 4);
  float* rno   = (float*)alloc(BN * 4);
  float* rni   = (float*)alloc(BN * 4);
  float* colpart = (float*)alloc((size_t)16 * BN * 4);
  float* maxpart = (float*)alloc(BN * 4);

  float* out0 = (float*)d_out;
  float* out1 = out0 + ND;

  // ---- one-time conversions + norms + transposed adjacency caches ----
  if (full) {
    cvt_n2e_colsum<<<dim3(Nn / 256, 16, Bb), 256, 0, stream>>>(n2e, n2e_h, colpart);
    colfin_kernel<<<BN / 256, 256, 0, stream>>>(colpart, rni);
    cvt_e2n_rowsum<<<BN, 256, 0, stream>>>(e2n, e2n_h, rno);
    adjT<<<dim3(Ee / 64, Nn / 64, Bb), 256, 0, stream>>>(n2e_h, n2e_hT, Ee, Nn);
    adjT<<<dim3(Nn / 64, Ee / 64, Bb), 256, 0, stream>>>(e2n_h, e2n_hT, Nn, Ee);
  } else {
    colsum_kernel<<<dim3(Nn / 256, 16, Bb), 256, 0, stream>>>(n2e, colpart);
    colfin_kernel<<<BN / 256, 256, 0, stream>>>(colpart, rni);
    rowsum_kernel<<<BN / 4, 256, 0, stream>>>(e2n, rno);
  }
  cvt_half<<<(int)(ED / 1024), 256, 0, stream>>>(edge_vec, ev_h);
  cvt_half_split<<<131072 / 1024, 256, 0, stream>>>(W_fuse, Wf_h, 131072);
  cvt_half_split<<<65536 / 1024, 256, 0, stream>>>(W_max, Wmax_h, 65536);
  init_cur<<<(int)(ND / 1024), 256, 0, stream>>>(node_vec, cur, cur_h, ND);
  transposeT<<<dim3(Nn / 64, 4, Bb), 256, 0, stream>>>(cur, cur_hT, ND);

  for (int h = 0; h < HOPS; h++) {
    // EO1 = n2e @ cur -> E1h (f16); B = cur_hT split (systematic operand)
    if (full)
      hgemm<HN, true, 1, EP_NONE, OH><<<dim3(2, Ee / 64, Bb), 256, 0, stream>>>(
          n2e_h, nullptr, cur_hT, E1h, nullptr, nullptr, nullptr,
          Ee, 256, Nn, Nn, Nn, 256, (long)Ee * Nn, NDb, EDb, 0, 0, 0, ND);
    else
      hgemm<HN, false, 1, EP_NONE, OH><<<dim3(2, Ee / 64, Bb), 256, 0, stream>>>(
          n2e, nullptr, cur_hT, E1h, nullptr, nullptr, nullptr,
          Ee, 256, Nn, Nn, Nn, 256, (long)Ee * Nn, NDb, EDb, 0, 0, 0, ND);
    // EO2 = relu(concat(E1, ev) @ Wf^T + b) -> E2T; B = Wf split (systematic)
    hgemm<HC2, true, 1, EP_RELUB, OHT><<<dim3(2, Ee / 64, Bb), 256, 0, stream>>>(
        E1h, ev_h, Wf_h, E2T, nullptr, nullptr, b_fuse,
        Ee, 256, 512, 256, 512, Ee, EDb, 0, EDb, 0, 0, 0, 131072);
    // out_vec = (e2n @ EO2 + cur) * rno -> outv; nonneg aggregation (attenuated)
    if (full)
      hgemm<HN, true, 0, EP_AGG, OF><<<dim3(2, Nn / 64, Bb), 256, 0, stream>>>(
          e2n_h, nullptr, E2T, outv, cur, rno, nullptr,
          Nn, 256, Ee, Ee, Ee, 256, (long)Nn * Ee, EDb, NDb, NDb, (long)Nn, 0, 0);
    else
      hgemm<HN, false, 0, EP_AGG, OF><<<dim3(2, Nn / 64, Bb), 256, 0, stream>>>(
          e2n, nullptr, E2T, outv, cur, rno, nullptr,
          Nn, 256, Ee, Ee, Ee, 256, (long)Nn * Ee, EDb, NDb, NDb, (long)Nn, 0, 0);
    // EI1 = e2n^T @ cur -> E1h; A = e2n_hT (coalesced HN), B = cur_hT split
    if (full)
      hgemm<HN, true, 1, EP_NONE, OH><<<dim3(2, Ee / 64, Bb), 256, 0, stream>>>(
          e2n_hT, nullptr, cur_hT, E1h, nullptr, nullptr, nullptr,
          Ee, 256, Nn, Nn, Nn, 256, (long)Ee * Nn, NDb, EDb, 0, 0, 0, ND);
    else
      hgemm<HT, false, 1, EP_NONE, OH><<<dim3(2, Ee / 64, Bb), 256, 0, stream>>>(
          e2n, nullptr, cur_hT, E1h, nullptr, nullptr, nullptr,
          Ee, 256, Nn, Ee, Nn, 256, (long)Nn * Ee, NDb, EDb, 0, 0, 0, ND);
    // EI2 -> E2T
    hgemm<HC2, true, 1, EP_RELUB, OHT><<<dim3(2, Ee / 64, Bb), 256, 0, stream>>>(
        E1h, ev_h, Wf_h, E2T, nullptr, nullptr, b_fuse,
        Ee, 256, 512, 256, 512, Ee, EDb, 0, EDb, 0, 0, 0, 131072);
    // in_vec = (n2e^T @ EI2 + cur) * rni -> inv; A = n2e_hT (coalesced HN)
    if (full)
      hgemm<HN, true, 0, EP_AGG, OF><<<dim3(2, Nn / 64, Bb), 256, 0, stream>>>(
          n2e_hT, nullptr, E2T, inv, cur, rni, nullptr,
          Nn, 256, Ee, Ee, Ee, 256, (long)Nn * Ee, EDb, NDb, NDb, (long)Nn, 0, 0);
    else
      hgemm<HT, false, 0, EP_AGG, OF><<<dim3(2, Nn / 64, Bb), 256, 0, stream>>>(
          n2e, nullptr, E2T, inv, cur, rni, nullptr,
          Nn, 256, Ee, Nn, Ee, 256, (long)Ee * Nn, EDb, NDb, NDb, (long)Nn, 0, 0);
    // gated fusion: nv = (1-z)*inv + z*outv  [split-bf16]
    sgemm<SM_G4, SE_GATE><<<dim3(2, BN / 64, 1), 256, 0, stream>>>(
        inv, outv, nullptr, W_z, nullptr, nv, inv, outv, b_z, 256, 1024, 256, 1024, 256);
    // u|r = sigmoid(concat(cur,nv) @ [W_u;W_r]^T) -> urb [BN,512]
    sgemm<SM_CN, SE_SIG><<<dim3(4, BN / 64, 1), 256, 0, stream>>>(
        cur, nv, nullptr, W_u, W_r, urb, nullptr, nullptr, nullptr, 512, 512, 256, 512, 512);
    // m = tanh(concat(r*cur, nv) @ W_m^T) -> mb
    sgemm<SM_RC, SE_TANH><<<dim3(2, BN / 64, 1), 256, 0, stream>>>(
        urb + 256, cur, nv, W_m, nullptr, mb, nullptr, nullptr, nullptr, 256, 512, 512, 512, 256);
    // cur = (1-u)*cur + u*m  (+ split halves)
    gruf_kernel<<<(int)(ND / 256), 256, 0, stream>>>(urb, mb, cur, cur_h, ND);
    if (h < HOPS - 1)
      transposeT<<<dim3(Nn / 64, 4, Bb), 256, 0, stream>>>(cur, cur_hT, ND);
  }

  // pooled = cur @ W_max^T -> urb (f32); both operands split (output-1 path)
  hgemm<HN, true, 3, EP_NONE, OF><<<dim3(2, BN / 64, 1), 256, 0, stream>>>(
      cur_h, nullptr, Wmax_h, urb, nullptr, nullptr, nullptr,
      BN, 256, 256, 256, 256, 256, 0, 0, 0, 0, 0, ND, 65536);
  maxpool1<<<dim3(8, Bb), 256, 0, stream>>>(urb, maxpart);
  maxpool2<<<Bb, 256, 0, stream>>>(maxpart, out1);

  transpose_out<<<(int)(ND / 256), 256, 0, stream>>>(cur, out0);
}

// Round 8
// 2074.467 us; speedup vs baseline: 1.5941x; 1.0764x over previous
//
#include <hip/hip_runtime.h>
#include <math.h>

#define Bb 8
#define Nn 2048
#define Ee 4096
#define Dd 256
#define HOPS 3
#define LDK 40   // sgemm LDS k-stride (16-bit elems)

typedef __attribute__((ext_vector_type(4))) float f32x4;
typedef _Float16 f16;
typedef __attribute__((ext_vector_type(8))) _Float16 f16x8;
typedef __attribute__((ext_vector_type(4))) _Float16 f16x4;
typedef __attribute__((ext_vector_type(8))) short s16x8;
typedef __attribute__((ext_vector_type(4))) short s16x4;

__device__ __forceinline__ short f2bf(float f){
  union{float f; unsigned u;} x; x.f=f;
  unsigned r = (x.u + 0x7fffu + ((x.u>>16)&1u)) >> 16;
  return (short)r;
}
__device__ __forceinline__ float bf2f(short h){
  union{unsigned u; float f;} x; x.u = ((unsigned)(unsigned short)h) << 16; return x.f;
}

enum { HN=0, HT=1 };                             // hgemm A modes
enum { OF=0, OH=1, OHT=2 };                      // output: f32 / f16 / f16-transposed
enum { EP_NONE=0, EP_BIAS, EP_ADDRELU, EP_AGG }; // hgemm epilogues
enum { SM_CN=0, SM_G4, SM_RC };                  // sgemm A modes
enum { SE_GATE=0, SE_SIG, SE_TANH };             // sgemm epilogues

// ---------------- fp16 MFMA GEMM: tile 64x128, BK=64, 4 waves 2x2 ----------------
// Reg-staged double buffer (2-phase): issue tile t+1 global loads BEFORE tile t
// MFMA; LDS write after the post-MFMA barrier. SPL bit0: B lo plane at +bLo;
// bit1: A lo plane at +aLo (split-fp16 for systematic-error operands).
// maskB / mask1: z-wrap masks for B and aux1 (merged-pair dispatches use z=16
// over two contiguous 8-batch buffers while B/aux1 wrap at 8).
// EP_ADDRELU: v = relu(v + aux1[row*256+col]) (EVW path, pitch 256).
template<int AMODE, bool AH, int SPL, int EPI, int OUTM>
__global__ __launch_bounds__(256) void hgemm(
    const void* __restrict__ Av, const f16* __restrict__ Bh, void* __restrict__ Cv,
    const float* __restrict__ aux1, const float* __restrict__ aux2,
    const float* __restrict__ bias,
    int M, int Nd, int K, int lda, int ldb, int ldc,
    long sA, long sB, long sC, long sAux1, long sAux2,
    long aLo, long bLo, int maskB, int mask1)
{
  const int bz = blockIdx.z;
  const char* Ab = (const char*)Av + (AH ? bz * sA * 2 : bz * sA * 4);
  Bh += (long)(bz & maskB) * sB;
  char* Cb = (char*)Cv + ((OUTM == OF) ? bz * sC * 4 : bz * sC * 2);
  if (aux1) aux1 += (long)(bz & mask1) * sAux1;
  if (aux2) aux2 += bz * sAux2;
  const int m0 = blockIdx.y * 64;
  const int n0 = blockIdx.x * 128;

  constexpr int LK = 72;                 // 144B rows: frag reads ~2-way banks
  constexpr int HLA = 64 * LK;
  constexpr int HLB = 128 * LK;
  __shared__ f16 As[64 * LK * ((SPL & 2) ? 2 : 1)];
  __shared__ f16 Bs[128 * LK * ((SPL & 1) ? 2 : 1)];

  const int tid = threadIdx.x;
  const int wid = tid >> 6, lane = tid & 63;
  const int wm = (wid >> 1) * 32, wn = (wid & 1) * 64;
  const int r = lane & 15, g = lane >> 4;

  f32x4 acc[2][4];
  #pragma unroll
  for (int i = 0; i < 2; i++)
    #pragma unroll
    for (int j = 0; j < 4; j++) acc[i][j] = (f32x4){0.f, 0.f, 0.f, 0.f};

  f16x8 ra0, ra1, rl0, rl1;   // staged A
  f16x8 rb[4], rbl[4];        // staged B

  auto loadA = [&](int k0) {
    if (AMODE == HN && AH) {
      const f16* Ah = (const f16*)Ab;
      const int row = tid >> 2, kc = (tid & 3) * 16;
      const long off = (long)(m0 + row) * lda + k0 + kc;
      ra0 = *(const f16x8*)&Ah[off];
      ra1 = *(const f16x8*)&Ah[off + 8];
      if (SPL & 2) { rl0 = *(const f16x8*)&Ah[aLo + off]; rl1 = *(const f16x8*)&Ah[aLo + off + 8]; }
    } else if (AMODE == HN && !AH) {
      const float* Af = (const float*)Ab;
      const int row = tid >> 2, kc = (tid & 3) * 16;
      const float* s = &Af[(long)(m0 + row) * lda + k0 + kc];
      f32x4 v0 = *(const f32x4*)s,       v1 = *(const f32x4*)(s + 4);
      f32x4 v2 = *(const f32x4*)(s + 8), v3 = *(const f32x4*)(s + 12);
      ra0 = (f16x8){(f16)v0.x,(f16)v0.y,(f16)v0.z,(f16)v0.w,(f16)v1.x,(f16)v1.y,(f16)v1.z,(f16)v1.w};
      ra1 = (f16x8){(f16)v2.x,(f16)v2.y,(f16)v2.z,(f16)v2.w,(f16)v3.x,(f16)v3.y,(f16)v3.z,(f16)v3.w};
    } else { // HT
      const int mm = tid & 63, kh = (tid >> 6) * 16;
      if (AH) {
        const f16* s = &((const f16*)Ab)[(long)(k0 + kh) * lda + m0 + mm];
        #pragma unroll
        for (int j = 0; j < 8; j++) ra0[j] = s[(long)j * lda];
        #pragma unroll
        for (int j = 0; j < 8; j++) ra1[j] = s[(long)(j + 8) * lda];
      } else {
        const float* s = &((const float*)Ab)[(long)(k0 + kh) * lda + m0 + mm];
        #pragma unroll
        for (int j = 0; j < 8; j++) ra0[j] = (f16)s[(long)j * lda];
        #pragma unroll
        for (int j = 0; j < 8; j++) ra1[j] = (f16)s[(long)(j + 8) * lda];
      }
    }
  };
  auto storeA = [&]() {
    if (AMODE == HT) {
      const int mm = tid & 63, kh = (tid >> 6) * 16;
      *(f16x8*)&As[mm * LK + kh] = ra0;
      *(f16x8*)&As[mm * LK + kh + 8] = ra1;
    } else {
      const int row = tid >> 2, kc = (tid & 3) * 16;
      *(f16x8*)&As[row * LK + kc] = ra0;
      *(f16x8*)&As[row * LK + kc + 8] = ra1;
      if (SPL & 2) {
        *(f16x8*)&As[HLA + row * LK + kc] = rl0;
        *(f16x8*)&As[HLA + row * LK + kc + 8] = rl1;
      }
    }
  };
  auto loadB = [&](int k0) {
    const int row = tid >> 1, kc = (tid & 1) * 32;
    const long off = (long)(n0 + row) * ldb + k0 + kc;
    #pragma unroll
    for (int u = 0; u < 4; u++) rb[u] = *(const f16x8*)&Bh[off + 8 * u];
    if (SPL & 1) {
      #pragma unroll
      for (int u = 0; u < 4; u++) rbl[u] = *(const f16x8*)&Bh[bLo + off + 8 * u];
    }
  };
  auto storeB = [&]() {
    const int row = tid >> 1, kc = (tid & 1) * 32;
    #pragma unroll
    for (int u = 0; u < 4; u++) *(f16x8*)&Bs[row * LK + kc + 8 * u] = rb[u];
    if (SPL & 1) {
      #pragma unroll
      for (int u = 0; u < 4; u++) *(f16x8*)&Bs[HLB + row * LK + kc + 8 * u] = rbl[u];
    }
  };

  loadA(0); loadB(0);
  storeA(); storeB();
  __syncthreads();

  const int NT = K >> 6;
  for (int t = 0; t < NT; t++) {
    const bool more = (t + 1 < NT);
    if (more) { loadA((t + 1) << 6); loadB((t + 1) << 6); }  // issue early
    #pragma unroll
    for (int ks = 0; ks < 2; ks++) {
      f16x8 af[2], bf[4], afl[2], bfl[4];
      #pragma unroll
      for (int i = 0; i < 2; i++) {
        af[i] = *(const f16x8*)&As[(wm + i*16 + r) * LK + ks*32 + g*8];
        if (SPL & 2) afl[i] = *(const f16x8*)&As[HLA + (wm + i*16 + r) * LK + ks*32 + g*8];
      }
      #pragma unroll
      for (int j = 0; j < 4; j++) {
        bf[j] = *(const f16x8*)&Bs[(wn + j*16 + r) * LK + ks*32 + g*8];
        if (SPL & 1) bfl[j] = *(const f16x8*)&Bs[HLB + (wn + j*16 + r) * LK + ks*32 + g*8];
      }
      #pragma unroll
      for (int i = 0; i < 2; i++)
        #pragma unroll
        for (int j = 0; j < 4; j++) {
          acc[i][j] = __builtin_amdgcn_mfma_f32_16x16x32_f16(af[i], bf[j], acc[i][j], 0, 0, 0);
          if (SPL & 1)
            acc[i][j] = __builtin_amdgcn_mfma_f32_16x16x32_f16(af[i], bfl[j], acc[i][j], 0, 0, 0);
          if (SPL & 2)
            acc[i][j] = __builtin_amdgcn_mfma_f32_16x16x32_f16(afl[i], bf[j], acc[i][j], 0, 0, 0);
        }
    }
    __syncthreads();
    if (more) { storeA(); storeB(); __syncthreads(); }
  }

  // ---- epilogue: acc map col=lane&15, row=(lane>>4)*4+t
  if (OUTM == OHT) {
    // transpose through LDS (reuse Bs), write 64B-contiguous column segments
    __syncthreads();
    f16* tile = (f16*)Bs;   // [128 cols][72 pad] — fits in Bs
    #pragma unroll
    for (int i = 0; i < 2; i++)
      #pragma unroll
      for (int j = 0; j < 4; j++) {
        const int rowl = wm + i * 16 + g * 4;
        const int coll = wn + j * 16 + r;
        #pragma unroll
        for (int t = 0; t < 4; t++) {
          float v = acc[i][j][t];
          if (EPI == EP_ADDRELU) {
            v += aux1[(long)(m0 + rowl + t) * 256 + n0 + coll];
            v = v > 0.f ? v : 0.f;
          } else if (EPI == EP_BIAS) { v += bias[n0 + coll]; }
          tile[coll * 72 + rowl + t] = (f16)v;
        }
      }
    __syncthreads();
    const int c2 = tid >> 1, rs = (tid & 1) * 32;
    f16* dst = &((f16*)Cb)[(long)(n0 + c2) * ldc + m0 + rs];
    #pragma unroll
    for (int u = 0; u < 4; u++)
      *(f16x8*)(dst + 8 * u) = *(const f16x8*)&tile[c2 * 72 + rs + 8 * u];
  } else {
    #pragma unroll
    for (int i = 0; i < 2; i++) {
      #pragma unroll
      for (int j = 0; j < 4; j++) {
        const int rowb = m0 + wm + i * 16 + g * 4;
        const int col = n0 + wn + j * 16 + r;
        #pragma unroll
        for (int t = 0; t < 4; t++) {
          const int row = rowb + t;
          const long idx = (long)row * ldc + col;
          float v = acc[i][j][t];
          if (EPI == EP_BIAS)         { v += bias[col]; }
          else if (EPI == EP_ADDRELU) { v += aux1[(long)row * 256 + col]; v = v > 0.f ? v : 0.f; }
          else if (EPI == EP_AGG)     { v = (v + aux1[idx]) * aux2[row]; }
          if (OUTM == OH) ((f16*)Cb)[idx] = (f16)v;
          else            ((float*)Cb)[idx] = v;
        }
      }
    }
  }
}

// ---------------- split-bf16 gate GEMM (validated numerics), tile 64x128 ----------------
template<int AMODE, int EPI>
__global__ __launch_bounds__(256) void sgemm(
    const float* __restrict__ A, const float* __restrict__ A2, const float* __restrict__ A3,
    const float* __restrict__ Bm, const float* __restrict__ Bm2, float* __restrict__ C,
    const float* __restrict__ aux1, const float* __restrict__ aux2, const float* __restrict__ bias,
    int Nd, int K, int lda, int ldb, int ldc)
{
  const int m0 = blockIdx.y * 64;
  const int n0 = blockIdx.x * 128;

  constexpr int HLA = 64 * LDK;
  constexpr int HLB = 128 * LDK;
  __shared__ short As[64 * LDK * 2];
  __shared__ short Bs[128 * LDK * 2];

  const int tid = threadIdx.x;
  const int wid = tid >> 6, lane = tid & 63;
  const int wm = (wid >> 1) * 32, wn = (wid & 1) * 64;
  const int r = lane & 15, g = lane >> 4;

  f32x4 acc[2][4];
  #pragma unroll
  for (int i = 0; i < 2; i++)
    #pragma unroll
    for (int j = 0; j < 4; j++) acc[i][j] = (f32x4){0.f, 0.f, 0.f, 0.f};

  auto stq = [&](short* dst, int HL, f32x4 v) {
    s16x4 h = { f2bf(v.x), f2bf(v.y), f2bf(v.z), f2bf(v.w) };
    *(s16x4*)dst = h;
    s16x4 l = { f2bf(v.x - bf2f(h.x)), f2bf(v.y - bf2f(h.y)),
                f2bf(v.z - bf2f(h.z)), f2bf(v.w - bf2f(h.w)) };
    *(s16x4*)(dst + HL) = l;
  };

  for (int k0 = 0; k0 < K; k0 += 32) {
    { // A staging (fused features)
      const int row = tid >> 2, kq = (tid & 3) * 8;
      const int kk = k0 + kq, q = kk >> 8, kd = kk & 255;
      const long base = (long)(m0 + row) * 256 + kd;
      const long baseA = (long)(m0 + row) * lda + kd;
      #pragma unroll
      for (int u = 0; u < 2; u++) {
        f32x4 v;
        if (AMODE == SM_CN) {
          v = (q == 0) ? *(const f32x4*)(A + base + 4 * u)
                       : *(const f32x4*)(A2 + base + 4 * u);
        } else if (AMODE == SM_G4) {
          if (q == 0)      v = *(const f32x4*)(A  + base + 4 * u);
          else if (q == 1) v = *(const f32x4*)(A2 + base + 4 * u);
          else {
            f32x4 x = *(const f32x4*)(A  + base + 4 * u);
            f32x4 y = *(const f32x4*)(A2 + base + 4 * u);
            v = (q == 2) ? x * y : x - y;
          }
        } else { // SM_RC
          if (q == 0) {
            f32x4 x = *(const f32x4*)(A  + baseA + 4 * u);
            f32x4 y = *(const f32x4*)(A2 + base + 4 * u);
            v = x * y;
          } else v = *(const f32x4*)(A3 + base + 4 * u);
        }
        stq(&As[row * LDK + kq + 4 * u], HLA, v);
      }
    }
    { // B staging (fp32 weights, split)
      const int row = tid >> 1, kq = (tid & 1) * 16;
      const int rowg = n0 + row;
      const float* src = (Bm2 != nullptr && rowg >= 256)
                         ? &Bm2[(long)(rowg - 256) * ldb + k0 + kq]
                         : &Bm[(long)rowg * ldb + k0 + kq];
      #pragma unroll
      for (int u = 0; u < 4; u++)
        stq(&Bs[row * LDK + kq + 4 * u], HLB, *(const f32x4*)(src + 4 * u));
    }
    __syncthreads();

    s16x8 ah[2], bh[4], al[2], bl[4];
    #pragma unroll
    for (int i = 0; i < 2; i++) {
      ah[i] = *(const s16x8*)&As[(wm + i*16 + r) * LDK + g * 8];
      al[i] = *(const s16x8*)&As[HLA + (wm + i*16 + r) * LDK + g * 8];
    }
    #pragma unroll
    for (int j = 0; j < 4; j++) {
      bh[j] = *(const s16x8*)&Bs[(wn + j*16 + r) * LDK + g * 8];
      bl[j] = *(const s16x8*)&Bs[HLB + (wn + j*16 + r) * LDK + g * 8];
    }
    #pragma unroll
    for (int i = 0; i < 2; i++)
      #pragma unroll
      for (int j = 0; j < 4; j++) {
        acc[i][j] = __builtin_amdgcn_mfma_f32_16x16x32_bf16(ah[i], bh[j], acc[i][j], 0, 0, 0);
        acc[i][j] = __builtin_amdgcn_mfma_f32_16x16x32_bf16(ah[i], bl[j], acc[i][j], 0, 0, 0);
        acc[i][j] = __builtin_amdgcn_mfma_f32_16x16x32_bf16(al[i], bh[j], acc[i][j], 0, 0, 0);
      }
    __syncthreads();
  }

  #pragma unroll
  for (int i = 0; i < 2; i++) {
    #pragma unroll
    for (int j = 0; j < 4; j++) {
      #pragma unroll
      for (int t = 0; t < 4; t++) {
        const int row = m0 + wm + i * 16 + g * 4 + t;
        const int col = n0 + wn + j * 16 + r;
        float v = acc[i][j][t];
        if (EPI == SE_GATE) {
          v += bias[col];
          float z = 1.f / (1.f + __expf(-v));
          const long ix = (long)row * 256 + col;
          v = (1.f - z) * aux1[ix] + z * aux2[ix];
        } else if (EPI == SE_SIG) {
          v = 1.f / (1.f + __expf(-v));
        } else { // SE_TANH
          v = tanhf(v);
        }
        C[(long)row * ldc + col] = v;
      }
    }
  }
}

// ---------------- small kernels ----------------

__global__ void cvt_n2e_colsum(const float* __restrict__ n2e, f16* __restrict__ n2e_h,
                               float* __restrict__ part) {
  const int n = blockIdx.x * 256 + threadIdx.x;
  const int c = blockIdx.y, b = blockIdx.z;
  const long base = (long)b * Ee * Nn + (long)c * 256 * Nn + n;
  float s = 0.f;
  for (int e = 0; e < 256; e++) {
    float v = n2e[base + (long)e * Nn];
    n2e_h[base + (long)e * Nn] = (f16)v;
    s += v;
  }
  part[((long)b * 16 + c) * Nn + n] = s;
}

__global__ void cvt_e2n_rowsum(const float* __restrict__ e2n, f16* __restrict__ e2n_h,
                               float* __restrict__ rno) {
  const long row = blockIdx.x;
  const int tid = threadIdx.x, lane = tid & 63, wid = tid >> 6;
  const float* p = e2n + row * Ee;
  f16* ph = e2n_h + row * Ee;
  float s = 0.f;
  for (int e = tid; e < Ee; e += 256) { float v = p[e]; ph[e] = (f16)v; s += v; }
  #pragma unroll
  for (int off = 32; off; off >>= 1) s += __shfl_down(s, off);
  __shared__ float wsum[4];
  if (lane == 0) wsum[wid] = s;
  __syncthreads();
  if (tid == 0) rno[row] = 1.f / (1.f + wsum[0] + wsum[1] + wsum[2] + wsum[3]);
}

// f16 [R][C] -> [C][R] transpose, 64x64 LDS tiles
__global__ void adjT(const f16* __restrict__ in, f16* __restrict__ out, int R, int C) {
  __shared__ f16 t[64][72];
  const long boff = (long)blockIdx.z * R * C;
  const int r0 = blockIdx.x * 64, c0 = blockIdx.y * 64;
  const int tid = threadIdx.x;
  const int rl = tid >> 2, cl = (tid & 3) * 16;
  const f16* src = in + boff + (long)(r0 + rl) * C + c0 + cl;
  *(f16x8*)&t[rl][cl]     = *(const f16x8*)src;
  *(f16x8*)&t[rl][cl + 8] = *(const f16x8*)(src + 8);
  __syncthreads();
  const int cl2 = tid >> 2, rl2 = (tid & 3) * 16;
  f16x8 o0, o1;
  #pragma unroll
  for (int v = 0; v < 8; v++) { o0[v] = t[rl2 + v][cl2]; o1[v] = t[rl2 + 8 + v][cl2]; }
  f16* dst = out + boff + (long)(c0 + cl2) * R + r0 + rl2;
  *(f16x8*)dst = o0;
  *(f16x8*)(dst + 8) = o1;
}

__global__ void rowsum_kernel(const float* __restrict__ e2n, float* __restrict__ out) {
  const int gw = blockIdx.x * 4 + (threadIdx.x >> 6);
  const int lane = threadIdx.x & 63;
  const float* p = e2n + (long)gw * Ee;
  float s = 0.f;
  for (int e = lane; e < Ee; e += 64) s += p[e];
  #pragma unroll
  for (int off = 32; off; off >>= 1) s += __shfl_down(s, off);
  if (lane == 0) out[gw] = 1.f / (1.f + s);
}
__global__ void colsum_kernel(const float* __restrict__ n2e, float* __restrict__ part) {
  const int n = blockIdx.x * 256 + threadIdx.x;
  const int c = blockIdx.y, b = blockIdx.z;
  const float* p = n2e + (long)b * Ee * Nn + (long)c * 256 * Nn + n;
  float s = 0.f;
  for (int e = 0; e < 256; e++) s += p[(long)e * Nn];
  part[((long)b * 16 + c) * Nn + n] = s;
}
__global__ void colfin_kernel(const float* __restrict__ part, float* __restrict__ rni) {
  const int i = blockIdx.x * 256 + threadIdx.x;
  const int b = i >> 11, n = i & 2047;
  float s = 0.f;
  #pragma unroll
  for (int c = 0; c < 16; c++) s += part[((long)b * 16 + c) * Nn + n];
  rni[i] = 1.f / (1.f + s);
}

__global__ void cvt_half(const float* __restrict__ src, f16* __restrict__ dst) {
  const long i4 = (long)blockIdx.x * 256 + threadIdx.x;
  f32x4 v = *(const f32x4*)&src[i4 * 4];
  *(f16x4*)&dst[i4 * 4] = (f16x4){(f16)v.x, (f16)v.y, (f16)v.z, (f16)v.w};
}

__global__ void cvt_half_split(const float* __restrict__ src, f16* __restrict__ dst, long loOff) {
  const long i4 = (long)blockIdx.x * 256 + threadIdx.x;
  f32x4 v = *(const f32x4*)&src[i4 * 4];
  f16x4 h = {(f16)v.x, (f16)v.y, (f16)v.z, (f16)v.w};
  *(f16x4*)&dst[i4 * 4] = h;
  f16x4 l = {(f16)(v.x - (float)h[0]), (f16)(v.y - (float)h[1]),
             (f16)(v.z - (float)h[2]), (f16)(v.w - (float)h[3])};
  *(f16x4*)&dst[loOff + i4 * 4] = l;
}

__global__ void init_cur(const float* __restrict__ node_vec, float* __restrict__ cur,
                         f16* __restrict__ cur_h, long loOff) {
  const long i4 = (long)blockIdx.x * 256 + threadIdx.x;
  f32x4 v = *(const f32x4*)&node_vec[i4 * 4];
  *(f32x4*)&cur[i4 * 4] = v;
  f16x4 h = {(f16)v.x, (f16)v.y, (f16)v.z, (f16)v.w};
  *(f16x4*)&cur_h[i4 * 4] = h;
  f16x4 l = {(f16)(v.x - (float)h[0]), (f16)(v.y - (float)h[1]),
             (f16)(v.z - (float)h[2]), (f16)(v.w - (float)h[3])};
  *(f16x4*)&cur_h[loOff + i4 * 4] = l;
}

// cur [B*N,256] f32 -> cur_hT hi/lo planes [B][256][2048] halves
__global__ void transposeT(const float* __restrict__ cur, f16* __restrict__ curT, long loOff) {
  __shared__ f16 th[64][72];
  __shared__ f16 tl[64][72];
  const int b = blockIdx.z, nt = blockIdx.x * 64, dt = blockIdx.y * 64;
  const int tid = threadIdx.x;
  const int nl = tid >> 2, d0 = (tid & 3) * 16;
  const float* src = cur + ((long)b * Nn + nt + nl) * 256 + dt + d0;
  #pragma unroll
  for (int u = 0; u < 4; u++) {
    f32x4 v = *(const f32x4*)(src + 4 * u);
    f16x4 h = {(f16)v.x, (f16)v.y, (f16)v.z, (f16)v.w};
    *(f16x4*)&th[nl][d0 + 4 * u] = h;
    f16x4 l = {(f16)(v.x - (float)h[0]), (f16)(v.y - (float)h[1]),
               (f16)(v.z - (float)h[2]), (f16)(v.w - (float)h[3])};
    *(f16x4*)&tl[nl][d0 + 4 * u] = l;
  }
  __syncthreads();
  const int dl = tid >> 2, n0l = (tid & 3) * 16;
  f16x8 o0, o1, p0, p1;
  #pragma unroll
  for (int v = 0; v < 8; v++) {
    o0[v] = th[n0l + v][dl];     o1[v] = th[n0l + 8 + v][dl];
    p0[v] = tl[n0l + v][dl];     p1[v] = tl[n0l + 8 + v][dl];
  }
  f16* dst = curT + (long)b * (256 * Nn) + (long)(dt + dl) * Nn + nt + n0l;
  *(f16x8*)dst = o0;
  *(f16x8*)(dst + 8) = o1;
  *(f16x8*)(dst + loOff) = p0;
  *(f16x8*)(dst + loOff + 8) = p1;
}

__global__ void gruf_kernel(const float* __restrict__ urb, const float* __restrict__ m,
                            float* __restrict__ cur, f16* __restrict__ cur_h, long loOff) {
  const long i = (long)blockIdx.x * 256 + threadIdx.x;
  const long bn = i >> 8; const int d = i & 255;
  const float uu = urb[bn * 512 + d];
  const float v = (1.f - uu) * cur[i] + uu * m[i];
  cur[i] = v;
  f16 h = (f16)v;
  cur_h[i] = h;
  cur_h[loOff + i] = (f16)(v - (float)h);
}

__global__ void maxpool1(const float* __restrict__ pooled, float* __restrict__ part) {
  const int d = threadIdx.x, c = blockIdx.x, b = blockIdx.y;
  const float* p = pooled + ((long)b * Nn + c * 256) * Dd + d;
  float m = -INFINITY;
  for (int n = 0; n < 256; n++) m = fmaxf(m, p[(long)n * Dd]);
  part[(b * 8 + c) * Dd + d] = m;
}
__global__ void maxpool2(const float* __restrict__ part, float* __restrict__ out1) {
  const int d = threadIdx.x, b = blockIdx.x;
  float m = -INFINITY;
  #pragma unroll
  for (int c = 0; c < 8; c++) m = fmaxf(m, part[(b * 8 + c) * Dd + d]);
  out1[b * Dd + d] = m;
}
__global__ void transpose_out(const float* __restrict__ cur, float* __restrict__ out0) {
  const long i = (long)blockIdx.x * 256 + threadIdx.x;
  const int d = i & 255;
  const long nb = i >> 8;
  const int b = nb & 7;
  const long n = nb >> 3;
  out0[i] = cur[((long)b * Nn + n) * Dd + d];
}

extern "C" void kernel_launch(void* const* d_in, const int* in_sizes, int n_in,
                              void* d_out, int out_size, void* d_ws, size_t ws_size,
                              hipStream_t stream) {
  const float* node_vec = (const float*)d_in[0];
  const float* edge_vec = (const float*)d_in[1];
  const float* n2e      = (const float*)d_in[2];   // [B,E,N]
  const float* e2n      = (const float*)d_in[3];   // [B,N,E]
  const float* W_fuse   = (const float*)d_in[5];   // [256,512]
  const float* b_fuse   = (const float*)d_in[6];
  const float* W_z      = (const float*)d_in[7];   // [256,1024]
  const float* b_z      = (const float*)d_in[8];
  const float* W_u      = (const float*)d_in[9];
  const float* W_r      = (const float*)d_in[10];
  const float* W_m      = (const float*)d_in[11];
  const float* W_max    = (const float*)d_in[12];  // [256,256]

  const long ND  = (long)Bb * Nn * Dd;   // 4194304
  const long EDb = (long)Ee * Dd;        // 1048576
  const long NDb = (long)Nn * Dd;        // 524288
  const long ED  = (long)Bb * EDb;       // 8388608
  const long ADJb = (long)Ee * Nn;       // 8388608 (per batch)
  const long ADJ = (long)Bb * ADJb;      // 67108864
  const int  BN  = Bb * Nn;

  // ---- arena ----
  char* p = (char*)d_ws;
  auto alloc = [&](size_t bytes) { char* r = p; p += (bytes + 255) & ~(size_t)255; return r; };

  const size_t need_full =
      (size_t)4 * ADJ * 2                  // adjEO (n2e_h|e2n_hT), adjAG (e2n_h|n2e_hT)
      + (size_t)ED * 2                     // ev_h
      + (size_t)4 * ED * 2                 // E1h2, E2T2 (16 slabs each)
      + (size_t)ED * 4                     // EVW (f32)
      + (size_t)4 * ND * 2                 // cur_h, cur_hT (hi+lo each)
      + (size_t)(2 * 131072 + 2 * 65536) * 2
      + (size_t)5 * ND * 4                 // cur, outv|inv, nv, mb
      + (size_t)BN * 512 * 4               // urb
      + (size_t)(2 * BN + 16 * BN + BN) * 4
      + 64 * 1024;
  const bool full = ws_size >= need_full;

  // merged-pair adjacency blocks (contiguous 16-slab buffers)
  f16 *adjEO = nullptr, *adjAG = nullptr;   // EO: n2e_h|e2n_hT ; AG: e2n_h|n2e_hT
  f16 *n2e_h = nullptr, *e2n_hT = nullptr, *e2n_h = nullptr, *n2e_hT = nullptr;
  if (full) {
    adjEO = (f16*)alloc((size_t)2 * ADJ * 2);
    adjAG = (f16*)alloc((size_t)2 * ADJ * 2);
    n2e_h = adjEO;  e2n_hT = adjEO + ADJ;
    e2n_h = adjAG;  n2e_hT = adjAG + ADJ;
  }
  f16* ev_h    = (f16*)alloc(ED * 2);
  f16* E1h2    = (f16*)alloc((size_t)2 * ED * 2);  // 16 slabs [Ee][256]
  f16* E2T2    = (f16*)alloc((size_t)2 * ED * 2);  // 16 slabs [256][Ee]
  float* EVW   = (float*)alloc(ED * 4);            // 8 slabs [Ee][256] f32
  f16* cur_h   = (f16*)alloc(2 * ND * 2);          // hi + lo planes
  f16* cur_hT  = (f16*)alloc(2 * ND * 2);          // hi + lo planes
  f16* Wf_h    = (f16*)alloc(2 * 131072 * 2);      // hi + lo
  f16* Wmax_h  = (f16*)alloc(2 * 65536 * 2);       // hi + lo
  float* cur   = (float*)alloc(ND * 4);
  float* outv  = (float*)alloc(2 * ND * 4);        // outv|inv contiguous
  float* inv   = outv + ND;
  float* nv    = (float*)alloc(ND * 4);
  float* urb   = (float*)alloc((size_t)BN * 512 * 4);
  float* mb    = (float*)alloc(ND * 4);
  float* rno   = (float*)alloc(2 * BN * 4);        // rno|rni contiguous
  float* rni   = rno + BN;
  float* colpart = (float*)alloc((size_t)16 * BN * 4);
  float* maxpart = (float*)alloc(BN * 4);

  float* out0 = (float*)d_out;
  float* out1 = out0 + ND;

  // ---- one-time conversions + norms + transposed adjacency caches ----
  if (full) {
    cvt_n2e_colsum<<<dim3(Nn / 256, 16, Bb), 256, 0, stream>>>(n2e, n2e_h, colpart);
    colfin_kernel<<<BN / 256, 256, 0, stream>>>(colpart, rni);
    cvt_e2n_rowsum<<<BN, 256, 0, stream>>>(e2n, e2n_h, rno);
    adjT<<<dim3(Ee / 64, Nn / 64, Bb), 256, 0, stream>>>(n2e_h, n2e_hT, Ee, Nn);
    adjT<<<dim3(Nn / 64, Ee / 64, Bb), 256, 0, stream>>>(e2n_h, e2n_hT, Nn, Ee);
  } else {
    colsum_kernel<<<dim3(Nn / 256, 16, Bb), 256, 0, stream>>>(n2e, colpart);
    colfin_kernel<<<BN / 256, 256, 0, stream>>>(colpart, rni);
    rowsum_kernel<<<BN / 4, 256, 0, stream>>>(e2n, rno);
  }
  cvt_half<<<(int)(ED / 1024), 256, 0, stream>>>(edge_vec, ev_h);
  cvt_half_split<<<131072 / 1024, 256, 0, stream>>>(W_fuse, Wf_h, 131072);
  cvt_half_split<<<65536 / 1024, 256, 0, stream>>>(W_max, Wmax_h, 65536);
  init_cur<<<(int)(ND / 1024), 256, 0, stream>>>(node_vec, cur, cur_h, ND);
  transposeT<<<dim3(Nn / 64, 4, Bb), 256, 0, stream>>>(cur, cur_hT, ND);

  // EVW = ev @ Wf[:,256:]^T + b_fuse  (hop-invariant, K=256, split-B) -> f32
  hgemm<HN, true, 1, EP_BIAS, OF><<<dim3(2, Ee / 64, Bb), 256, 0, stream>>>(
      ev_h, Wf_h + 256, EVW, nullptr, nullptr, b_fuse,
      Ee, 256, 256, 256, 512, 256, EDb, 0, EDb, 0, 0, 0, 131072, 0, 0);

  for (int h = 0; h < HOPS; h++) {
    if (full) {
      // EO1|EI1 = (n2e_h | e2n_hT) @ cur -> E1h2 slabs 0..15 ; B=cur_hT split, wraps@8
      hgemm<HN, true, 1, EP_NONE, OH><<<dim3(2, Ee / 64, 2 * Bb), 256, 0, stream>>>(
          adjEO, cur_hT, E1h2, nullptr, nullptr, nullptr,
          Ee, 256, Nn, Nn, Nn, 256, ADJb, NDb, EDb, 0, 0, 0, ND, 7, 0);
      // EO2|EI2 = relu(E1 @ Wf1^T + EVW) -> E2T2 (f16-T) ; B=Wf split, EVW wraps@8
      hgemm<HN, true, 1, EP_ADDRELU, OHT><<<dim3(2, Ee / 64, 2 * Bb), 256, 0, stream>>>(
          E1h2, Wf_h, E2T2, EVW, nullptr, nullptr,
          Ee, 256, 256, 256, 512, Ee, EDb, 0, EDb, EDb, 0, 0, 131072, 0, 7);
      // out|in = ((e2n_h | n2e_hT) @ E2 + cur) * (rno|rni) -> outv|inv
      hgemm<HN, true, 0, EP_AGG, OF><<<dim3(2, Nn / 64, 2 * Bb), 256, 0, stream>>>(
          adjAG, E2T2, outv, cur, rno, nullptr,
          Nn, 256, Ee, Ee, Ee, 256, ADJb, EDb, NDb, NDb, (long)Nn, 0, 0, 15, 7);
    } else {
      hgemm<HN, false, 1, EP_NONE, OH><<<dim3(2, Ee / 64, Bb), 256, 0, stream>>>(
          n2e, cur_hT, E1h2, nullptr, nullptr, nullptr,
          Ee, 256, Nn, Nn, Nn, 256, ADJb, NDb, EDb, 0, 0, 0, ND, 7, 0);
      hgemm<HT, false, 1, EP_NONE, OH><<<dim3(2, Ee / 64, Bb), 256, 0, stream>>>(
          e2n, cur_hT, E1h2 + ED, nullptr, nullptr, nullptr,
          Ee, 256, Nn, Ee, Nn, 256, ADJb, NDb, EDb, 0, 0, 0, ND, 7, 0);
      hgemm<HN, true, 1, EP_ADDRELU, OHT><<<dim3(2, Ee / 64, 2 * Bb), 256, 0, stream>>>(
          E1h2, Wf_h, E2T2, EVW, nullptr, nullptr,
          Ee, 256, 256, 256, 512, Ee, EDb, 0, EDb, EDb, 0, 0, 131072, 0, 7);
      hgemm<HN, false, 0, EP_AGG, OF><<<dim3(2, Nn / 64, Bb), 256, 0, stream>>>(
          e2n, E2T2, outv, cur, rno, nullptr,
          Nn, 256, Ee, Ee, Ee, 256, (long)Nn * Ee, EDb, NDb, NDb, (long)Nn, 0, 0, 15, 7);
      hgemm<HT, false, 0, EP_AGG, OF><<<dim3(2, Nn / 64, Bb), 256, 0, stream>>>(
          n2e, E2T2 + ED, inv, cur, rni, nullptr,
          Nn, 256, Ee, Nn, Ee, 256, (long)Ee * Nn, EDb, NDb, NDb, (long)Nn, 0, 0, 15, 7);
    }
    // gated fusion: nv = (1-z)*inv + z*outv  [split-bf16]
    sgemm<SM_G4, SE_GATE><<<dim3(2, BN / 64, 1), 256, 0, stream>>>(
        inv, outv, nullptr, W_z, nullptr, nv, inv, outv, b_z, 256, 1024, 256, 1024, 256);
    // u|r = sigmoid(concat(cur,nv) @ [W_u;W_r]^T) -> urb [BN,512]
    sgemm<SM_CN, SE_SIG><<<dim3(4, BN / 64, 1), 256, 0, stream>>>(
        cur, nv, nullptr, W_u, W_r, urb, nullptr, nullptr, nullptr, 512, 512, 256, 512, 512);
    // m = tanh(concat(r*cur, nv) @ W_m^T) -> mb
    sgemm<SM_RC, SE_TANH><<<dim3(2, BN / 64, 1), 256, 0, stream>>>(
        urb + 256, cur, nv, W_m, nullptr, mb, nullptr, nullptr, nullptr, 256, 512, 512, 512, 256);
    // cur = (1-u)*cur + u*m  (+ split halves)
    gruf_kernel<<<(int)(ND / 256), 256, 0, stream>>>(urb, mb, cur, cur_h, ND);
    if (h < HOPS - 1)
      transposeT<<<dim3(Nn / 64, 4, Bb), 256, 0, stream>>>(cur, cur_hT, ND);
  }

  // pooled = cur @ W_max^T -> urb (f32); both operands split (output-1 path)
  hgemm<HN, true, 3, EP_NONE, OF><<<dim3(2, BN / 64, 1), 256, 0, stream>>>(
      cur_h, Wmax_h, urb, nullptr, nullptr, nullptr,
      BN, 256, 256, 256, 256, 256, 0, 0, 0, 0, 0, ND, 65536, 0, 0);
  maxpool1<<<dim3(8, Bb), 256, 0, stream>>>(urb, maxpart);
  maxpool2<<<Bb, 256, 0, stream>>>(maxpart, out1);

  transpose_out<<<(int)(ND / 256), 256, 0, stream>>>(cur, out0);
}

// Round 9
// 1987.798 us; speedup vs baseline: 1.6636x; 1.0436x over previous
//
#include <hip/hip_runtime.h>
#include <math.h>

#define Bb 8
#define Nn 2048
#define Ee 4096
#define Dd 256
#define HOPS 3

typedef __attribute__((ext_vector_type(4))) float f32x4;
typedef _Float16 f16;
typedef __attribute__((ext_vector_type(8))) _Float16 f16x8;
typedef __attribute__((ext_vector_type(4))) _Float16 f16x4;
typedef __attribute__((ext_vector_type(8))) short s16x8;
typedef __attribute__((ext_vector_type(4))) short s16x4;

__device__ __forceinline__ short f2bf(float f){
  union{float f; unsigned u;} x; x.f=f;
  unsigned r = (x.u + 0x7fffu + ((x.u>>16)&1u)) >> 16;
  return (short)r;
}
__device__ __forceinline__ float bf2f(short h){
  union{unsigned u; float f;} x; x.u = ((unsigned)(unsigned short)h) << 16; return x.f;
}
// XOR-swizzle on 16B granules within a row-major [R][64] 16-bit LDS tile (T2)
__device__ __forceinline__ int swz(int row, int idx){ return idx ^ ((row & 7) << 3); }

enum { HN=0, HT=1 };                             // hgemm A modes
enum { OF=0, OH=1, OHT=2 };                      // output: f32 / f16 / f16-transposed
enum { EP_NONE=0, EP_BIAS, EP_ADDRELU, EP_AGG }; // hgemm epilogues
enum { SM_CN=0, SM_G4, SM_RC };                  // ggemm A modes
enum { SE_GATE=0, SE_SIG, SE_TANH };             // ggemm epilogues

// ---------------- fp16 MFMA GEMM: tile 64x128, BK=64, 4 waves 2x2 ----------------
// Reg-staged 2-phase; swizzled LDS (LK=64, 40KB @ SPL=1 -> 4 blocks/CU).
template<int AMODE, bool AH, int SPL, int EPI, int OUTM>
__global__ __launch_bounds__(256) void hgemm(
    const void* __restrict__ Av, const f16* __restrict__ Bh, void* __restrict__ Cv,
    const float* __restrict__ aux1, const float* __restrict__ aux2,
    const float* __restrict__ bias,
    int M, int Nd, int K, int lda, int ldb, int ldc,
    long sA, long sB, long sC, long sAux1, long sAux2,
    long aLo, long bLo, int maskB, int mask1)
{
  const int bz = blockIdx.z;
  const char* Ab = (const char*)Av + (AH ? bz * sA * 2 : bz * sA * 4);
  Bh += (long)(bz & maskB) * sB;
  char* Cb = (char*)Cv + ((OUTM == OF) ? bz * sC * 4 : bz * sC * 2);
  if (aux1) aux1 += (long)(bz & mask1) * sAux1;
  if (aux2) aux2 += bz * sAux2;
  const int m0 = blockIdx.y * 64;
  const int n0 = blockIdx.x * 128;

  constexpr int HLA = 64 * 64;
  constexpr int HLB = 128 * 64;
  __shared__ f16 As[64 * 64 * ((SPL & 2) ? 2 : 1)];
  __shared__ f16 Bs[128 * 64 * ((SPL & 1) ? 2 : 1)];

  const int tid = threadIdx.x;
  const int wid = tid >> 6, lane = tid & 63;
  const int wm = (wid >> 1) * 32, wn = (wid & 1) * 64;
  const int r = lane & 15, g = lane >> 4;

  f32x4 acc[2][4];
  #pragma unroll
  for (int i = 0; i < 2; i++)
    #pragma unroll
    for (int j = 0; j < 4; j++) acc[i][j] = (f32x4){0.f, 0.f, 0.f, 0.f};

  f16x8 ra0, ra1, rl0, rl1;   // staged A
  f16x8 rb[4], rbl[4];        // staged B

  auto loadA = [&](int k0) {
    if (AMODE == HN && AH) {
      const f16* Ah = (const f16*)Ab;
      const int row = tid >> 2, kc = (tid & 3) * 16;
      const long off = (long)(m0 + row) * lda + k0 + kc;
      ra0 = *(const f16x8*)&Ah[off];
      ra1 = *(const f16x8*)&Ah[off + 8];
      if (SPL & 2) { rl0 = *(const f16x8*)&Ah[aLo + off]; rl1 = *(const f16x8*)&Ah[aLo + off + 8]; }
    } else if (AMODE == HN && !AH) {
      const float* Af = (const float*)Ab;
      const int row = tid >> 2, kc = (tid & 3) * 16;
      const float* s = &Af[(long)(m0 + row) * lda + k0 + kc];
      f32x4 v0 = *(const f32x4*)s,       v1 = *(const f32x4*)(s + 4);
      f32x4 v2 = *(const f32x4*)(s + 8), v3 = *(const f32x4*)(s + 12);
      ra0 = (f16x8){(f16)v0.x,(f16)v0.y,(f16)v0.z,(f16)v0.w,(f16)v1.x,(f16)v1.y,(f16)v1.z,(f16)v1.w};
      ra1 = (f16x8){(f16)v2.x,(f16)v2.y,(f16)v2.z,(f16)v2.w,(f16)v3.x,(f16)v3.y,(f16)v3.z,(f16)v3.w};
    } else { // HT (fallback path)
      const int mm = tid & 63, kh = (tid >> 6) * 16;
      if (AH) {
        const f16* s = &((const f16*)Ab)[(long)(k0 + kh) * lda + m0 + mm];
        #pragma unroll
        for (int j = 0; j < 8; j++) ra0[j] = s[(long)j * lda];
        #pragma unroll
        for (int j = 0; j < 8; j++) ra1[j] = s[(long)(j + 8) * lda];
      } else {
        const float* s = &((const float*)Ab)[(long)(k0 + kh) * lda + m0 + mm];
        #pragma unroll
        for (int j = 0; j < 8; j++) ra0[j] = (f16)s[(long)j * lda];
        #pragma unroll
        for (int j = 0; j < 8; j++) ra1[j] = (f16)s[(long)(j + 8) * lda];
      }
    }
  };
  auto storeA = [&]() {
    if (AMODE == HT) {
      const int mm = tid & 63, kh = (tid >> 6) * 16;
      *(f16x8*)&As[swz(mm, mm * 64 + kh)]     = ra0;
      *(f16x8*)&As[swz(mm, mm * 64 + kh + 8)] = ra1;
    } else {
      const int row = tid >> 2, kc = (tid & 3) * 16;
      const int i0 = swz(row, row * 64 + kc), i1 = swz(row, row * 64 + kc + 8);
      *(f16x8*)&As[i0] = ra0;
      *(f16x8*)&As[i1] = ra1;
      if (SPL & 2) { *(f16x8*)&As[HLA + i0] = rl0; *(f16x8*)&As[HLA + i1] = rl1; }
    }
  };
  auto loadB = [&](int k0) {
    const int row = tid >> 1, kc = (tid & 1) * 32;
    const long off = (long)(n0 + row) * ldb + k0 + kc;
    #pragma unroll
    for (int u = 0; u < 4; u++) rb[u] = *(const f16x8*)&Bh[off + 8 * u];
    if (SPL & 1) {
      #pragma unroll
      for (int u = 0; u < 4; u++) rbl[u] = *(const f16x8*)&Bh[bLo + off + 8 * u];
    }
  };
  auto storeB = [&]() {
    const int row = tid >> 1, kc = (tid & 1) * 32;
    #pragma unroll
    for (int u = 0; u < 4; u++) {
      const int bx = swz(row, row * 64 + kc + 8 * u);
      *(f16x8*)&Bs[bx] = rb[u];
      if (SPL & 1) *(f16x8*)&Bs[HLB + bx] = rbl[u];
    }
  };

  loadA(0); loadB(0);
  storeA(); storeB();
  __syncthreads();

  const int NT = K >> 6;
  for (int t = 0; t < NT; t++) {
    const bool more = (t + 1 < NT);
    if (more) { loadA((t + 1) << 6); loadB((t + 1) << 6); }  // issue early
    #pragma unroll
    for (int ks = 0; ks < 2; ks++) {
      f16x8 af[2], bf[4], afl[2], bfl[4];
      #pragma unroll
      for (int i = 0; i < 2; i++) {
        const int rw = wm + i * 16 + r;
        const int ix = swz(rw, rw * 64 + ks * 32 + g * 8);
        af[i] = *(const f16x8*)&As[ix];
        if (SPL & 2) afl[i] = *(const f16x8*)&As[HLA + ix];
      }
      #pragma unroll
      for (int j = 0; j < 4; j++) {
        const int rw = wn + j * 16 + r;
        const int ix = swz(rw, rw * 64 + ks * 32 + g * 8);
        bf[j] = *(const f16x8*)&Bs[ix];
        if (SPL & 1) bfl[j] = *(const f16x8*)&Bs[HLB + ix];
      }
      #pragma unroll
      for (int i = 0; i < 2; i++)
        #pragma unroll
        for (int j = 0; j < 4; j++) {
          acc[i][j] = __builtin_amdgcn_mfma_f32_16x16x32_f16(af[i], bf[j], acc[i][j], 0, 0, 0);
          if (SPL & 1)
            acc[i][j] = __builtin_amdgcn_mfma_f32_16x16x32_f16(af[i], bfl[j], acc[i][j], 0, 0, 0);
          if (SPL & 2)
            acc[i][j] = __builtin_amdgcn_mfma_f32_16x16x32_f16(afl[i], bf[j], acc[i][j], 0, 0, 0);
        }
    }
    __syncthreads();
    if (more) { storeA(); storeB(); __syncthreads(); }
  }

  // ---- epilogue: acc map col=lane&15, row=(lane>>4)*4+t
  if (OUTM == OHT) {
    __syncthreads();
    f16* tile = (f16*)Bs;   // [128 cols][72 pad] scratch
    #pragma unroll
    for (int i = 0; i < 2; i++)
      #pragma unroll
      for (int j = 0; j < 4; j++) {
        const int rowl = wm + i * 16 + g * 4;
        const int coll = wn + j * 16 + r;
        #pragma unroll
        for (int t = 0; t < 4; t++) {
          float v = acc[i][j][t];
          if (EPI == EP_ADDRELU) {
            v += aux1[(long)(m0 + rowl + t) * 256 + n0 + coll];
            v = v > 0.f ? v : 0.f;
          } else if (EPI == EP_BIAS) { v += bias[n0 + coll]; }
          tile[coll * 72 + rowl + t] = (f16)v;
        }
      }
    __syncthreads();
    const int c2 = tid >> 1, rs = (tid & 1) * 32;
    f16* dst = &((f16*)Cb)[(long)(n0 + c2) * ldc + m0 + rs];
    #pragma unroll
    for (int u = 0; u < 4; u++)
      *(f16x8*)(dst + 8 * u) = *(const f16x8*)&tile[c2 * 72 + rs + 8 * u];
  } else {
    #pragma unroll
    for (int i = 0; i < 2; i++) {
      #pragma unroll
      for (int j = 0; j < 4; j++) {
        const int rowb = m0 + wm + i * 16 + g * 4;
        const int col = n0 + wn + j * 16 + r;
        #pragma unroll
        for (int t = 0; t < 4; t++) {
          const int row = rowb + t;
          const long idx = (long)row * ldc + col;
          float v = acc[i][j][t];
          if (EPI == EP_BIAS)         { v += bias[col]; }
          else if (EPI == EP_ADDRELU) { v += aux1[(long)row * 256 + col]; v = v > 0.f ? v : 0.f; }
          else if (EPI == EP_AGG)     { v = (v + aux1[idx]) * aux2[row]; }
          if (OUTM == OH) ((f16*)Cb)[idx] = (f16)v;
          else            ((float*)Cb)[idx] = v;
        }
      }
    }
  }
}

// ------------- split-bf16 gate GEMM, reg-staged 2-phase, tile 64x128, BK=64 -------------
// B = pre-split bf16 weight planes (hi at Bw, lo at Bw+bLo). A features split in regs.
template<int AMODE, int EPI>
__global__ __launch_bounds__(256) void ggemm(
    const float* __restrict__ A, const float* __restrict__ A2, const float* __restrict__ A3,
    const short* __restrict__ Bw, float* __restrict__ C,
    const float* __restrict__ aux1, const float* __restrict__ aux2, const float* __restrict__ bias,
    int Nd, int K, int lda, int ldb, int ldc, long bLo)
{
  const int m0 = blockIdx.y * 64;
  const int n0 = blockIdx.x * 128;
  constexpr int HLA = 64 * 64;
  constexpr int HLB = 128 * 64;
  __shared__ short As[64 * 64 * 2];
  __shared__ short Bs[128 * 64 * 2];

  const int tid = threadIdx.x;
  const int wid = tid >> 6, lane = tid & 63;
  const int wm = (wid >> 1) * 32, wn = (wid & 1) * 64;
  const int r = lane & 15, g = lane >> 4;

  f32x4 acc[2][4];
  #pragma unroll
  for (int i = 0; i < 2; i++)
    #pragma unroll
    for (int j = 0; j < 4; j++) acc[i][j] = (f32x4){0.f, 0.f, 0.f, 0.f};

  s16x4 rah[4], ral[4];
  s16x8 rbh[4], rbl[4];

  auto loadA = [&](int k0) {
    const int row = tid >> 2, kc = (tid & 3) * 16;
    const int kk = k0 + kc, q = kk >> 8, kd = kk & 255;
    const long base = (long)(m0 + row) * 256 + kd;
    const long baseA = (long)(m0 + row) * lda + kd;
    #pragma unroll
    for (int u = 0; u < 4; u++) {
      f32x4 v;
      if (AMODE == SM_CN) {
        v = (q == 0) ? *(const f32x4*)(A + base + 4 * u)
                     : *(const f32x4*)(A2 + base + 4 * u);
      } else if (AMODE == SM_G4) {
        if (q == 0)      v = *(const f32x4*)(A  + base + 4 * u);
        else if (q == 1) v = *(const f32x4*)(A2 + base + 4 * u);
        else {
          f32x4 x = *(const f32x4*)(A  + base + 4 * u);
          f32x4 y = *(const f32x4*)(A2 + base + 4 * u);
          v = (q == 2) ? x * y : x - y;
        }
      } else { // SM_RC
        if (q == 0) {
          f32x4 x = *(const f32x4*)(A  + baseA + 4 * u);
          f32x4 y = *(const f32x4*)(A2 + base + 4 * u);
          v = x * y;
        } else v = *(const f32x4*)(A3 + base + 4 * u);
      }
      s16x4 h = { f2bf(v.x), f2bf(v.y), f2bf(v.z), f2bf(v.w) };
      rah[u] = h;
      ral[u] = (s16x4){ f2bf(v.x - bf2f(h.x)), f2bf(v.y - bf2f(h.y)),
                        f2bf(v.z - bf2f(h.z)), f2bf(v.w - bf2f(h.w)) };
    }
  };
  auto storeA = [&]() {
    const int row = tid >> 2, kc = (tid & 3) * 16;
    const int i0 = swz(row, row * 64 + kc), i1 = swz(row, row * 64 + kc + 8);
    *(s16x4*)&As[i0]     = rah[0]; *(s16x4*)&As[i0 + 4] = rah[1];
    *(s16x4*)&As[i1]     = rah[2]; *(s16x4*)&As[i1 + 4] = rah[3];
    *(s16x4*)&As[HLA + i0]     = ral[0]; *(s16x4*)&As[HLA + i0 + 4] = ral[1];
    *(s16x4*)&As[HLA + i1]     = ral[2]; *(s16x4*)&As[HLA + i1 + 4] = ral[3];
  };
  auto loadB = [&](int k0) {
    const int row = tid >> 1, kc = (tid & 1) * 32;
    const long off = (long)(n0 + row) * ldb + k0 + kc;
    #pragma unroll
    for (int u = 0; u < 4; u++) {
      rbh[u] = *(const s16x8*)&Bw[off + 8 * u];
      rbl[u] = *(const s16x8*)&Bw[bLo + off + 8 * u];
    }
  };
  auto storeB = [&]() {
    const int row = tid >> 1, kc = (tid & 1) * 32;
    #pragma unroll
    for (int u = 0; u < 4; u++) {
      const int bx = swz(row, row * 64 + kc + 8 * u);
      *(s16x8*)&Bs[bx] = rbh[u];
      *(s16x8*)&Bs[HLB + bx] = rbl[u];
    }
  };

  loadA(0); loadB(0);
  storeA(); storeB();
  __syncthreads();

  const int NT = K >> 6;
  for (int t = 0; t < NT; t++) {
    const bool more = (t + 1 < NT);
    if (more) { loadA((t + 1) << 6); loadB((t + 1) << 6); }
    #pragma unroll
    for (int ks = 0; ks < 2; ks++) {
      s16x8 ah[2], al[2], bh[4], bl[4];
      #pragma unroll
      for (int i = 0; i < 2; i++) {
        const int rw = wm + i * 16 + r;
        const int ix = swz(rw, rw * 64 + ks * 32 + g * 8);
        ah[i] = *(const s16x8*)&As[ix];
        al[i] = *(const s16x8*)&As[HLA + ix];
      }
      #pragma unroll
      for (int j = 0; j < 4; j++) {
        const int rw = wn + j * 16 + r;
        const int ix = swz(rw, rw * 64 + ks * 32 + g * 8);
        bh[j] = *(const s16x8*)&Bs[ix];
        bl[j] = *(const s16x8*)&Bs[HLB + ix];
      }
      #pragma unroll
      for (int i = 0; i < 2; i++)
        #pragma unroll
        for (int j = 0; j < 4; j++) {
          acc[i][j] = __builtin_amdgcn_mfma_f32_16x16x32_bf16(ah[i], bh[j], acc[i][j], 0, 0, 0);
          acc[i][j] = __builtin_amdgcn_mfma_f32_16x16x32_bf16(ah[i], bl[j], acc[i][j], 0, 0, 0);
          acc[i][j] = __builtin_amdgcn_mfma_f32_16x16x32_bf16(al[i], bh[j], acc[i][j], 0, 0, 0);
        }
    }
    __syncthreads();
    if (more) { storeA(); storeB(); __syncthreads(); }
  }

  #pragma unroll
  for (int i = 0; i < 2; i++) {
    #pragma unroll
    for (int j = 0; j < 4; j++) {
      #pragma unroll
      for (int t = 0; t < 4; t++) {
        const int row = m0 + wm + i * 16 + g * 4 + t;
        const int col = n0 + wn + j * 16 + r;
        float v = acc[i][j][t];
        if (EPI == SE_GATE) {
          v += bias[col];
          float z = 1.f / (1.f + __expf(-v));
          const long ix = (long)row * 256 + col;
          v = (1.f - z) * aux1[ix] + z * aux2[ix];
        } else if (EPI == SE_SIG) {
          v = 1.f / (1.f + __expf(-v));
        } else { // SE_TANH
          v = tanhf(v);
        }
        C[(long)row * ldc + col] = v;
      }
    }
  }
}

// ---------------- small kernels ----------------

__global__ void cvt_n2e_colsum(const float* __restrict__ n2e, f16* __restrict__ n2e_h,
                               float* __restrict__ part) {
  const int n = blockIdx.x * 256 + threadIdx.x;
  const int c = blockIdx.y, b = blockIdx.z;
  const long base = (long)b * Ee * Nn + (long)c * 256 * Nn + n;
  float s = 0.f;
  for (int e = 0; e < 256; e++) {
    float v = n2e[base + (long)e * Nn];
    n2e_h[base + (long)e * Nn] = (f16)v;
    s += v;
  }
  part[((long)b * 16 + c) * Nn + n] = s;
}

__global__ void cvt_e2n_rowsum(const float* __restrict__ e2n, f16* __restrict__ e2n_h,
                               float* __restrict__ rno) {
  const long row = blockIdx.x;
  const int tid = threadIdx.x, lane = tid & 63, wid = tid >> 6;
  const float* p = e2n + row * Ee;
  f16* ph = e2n_h + row * Ee;
  float s = 0.f;
  for (int e = tid; e < Ee; e += 256) { float v = p[e]; ph[e] = (f16)v; s += v; }
  #pragma unroll
  for (int off = 32; off; off >>= 1) s += __shfl_down(s, off);
  __shared__ float wsum[4];
  if (lane == 0) wsum[wid] = s;
  __syncthreads();
  if (tid == 0) rno[row] = 1.f / (1.f + wsum[0] + wsum[1] + wsum[2] + wsum[3]);
}

// f16 [R][C] -> [C][R] transpose, 64x64 LDS tiles
__global__ void adjT(const f16* __restrict__ in, f16* __restrict__ out, int R, int C) {
  __shared__ f16 t[64][72];
  const long boff = (long)blockIdx.z * R * C;
  const int r0 = blockIdx.x * 64, c0 = blockIdx.y * 64;
  const int tid = threadIdx.x;
  const int rl = tid >> 2, cl = (tid & 3) * 16;
  const f16* src = in + boff + (long)(r0 + rl) * C + c0 + cl;
  *(f16x8*)&t[rl][cl]     = *(const f16x8*)src;
  *(f16x8*)&t[rl][cl + 8] = *(const f16x8*)(src + 8);
  __syncthreads();
  const int cl2 = tid >> 2, rl2 = (tid & 3) * 16;
  f16x8 o0, o1;
  #pragma unroll
  for (int v = 0; v < 8; v++) { o0[v] = t[rl2 + v][cl2]; o1[v] = t[rl2 + 8 + v][cl2]; }
  f16* dst = out + boff + (long)(c0 + cl2) * R + r0 + rl2;
  *(f16x8*)dst = o0;
  *(f16x8*)(dst + 8) = o1;
}

__global__ void rowsum_kernel(const float* __restrict__ e2n, float* __restrict__ out) {
  const int gw = blockIdx.x * 4 + (threadIdx.x >> 6);
  const int lane = threadIdx.x & 63;
  const float* p = e2n + (long)gw * Ee;
  float s = 0.f;
  for (int e = lane; e < Ee; e += 64) s += p[e];
  #pragma unroll
  for (int off = 32; off; off >>= 1) s += __shfl_down(s, off);
  if (lane == 0) out[gw] = 1.f / (1.f + s);
}
__global__ void colsum_kernel(const float* __restrict__ n2e, float* __restrict__ part) {
  const int n = blockIdx.x * 256 + threadIdx.x;
  const int c = blockIdx.y, b = blockIdx.z;
  const float* p = n2e + (long)b * Ee * Nn + (long)c * 256 * Nn + n;
  float s = 0.f;
  for (int e = 0; e < 256; e++) s += p[(long)e * Nn];
  part[((long)b * 16 + c) * Nn + n] = s;
}
__global__ void colfin_kernel(const float* __restrict__ part, float* __restrict__ rni) {
  const int i = blockIdx.x * 256 + threadIdx.x;
  const int b = i >> 11, n = i & 2047;
  float s = 0.f;
  #pragma unroll
  for (int c = 0; c < 16; c++) s += part[((long)b * 16 + c) * Nn + n];
  rni[i] = 1.f / (1.f + s);
}

__global__ void cvt_half(const float* __restrict__ src, f16* __restrict__ dst) {
  const long i4 = (long)blockIdx.x * 256 + threadIdx.x;
  f32x4 v = *(const f32x4*)&src[i4 * 4];
  *(f16x4*)&dst[i4 * 4] = (f16x4){(f16)v.x, (f16)v.y, (f16)v.z, (f16)v.w};
}

__global__ void cvt_half_split(const float* __restrict__ src, f16* __restrict__ dst, long loOff) {
  const long i4 = (long)blockIdx.x * 256 + threadIdx.x;
  f32x4 v = *(const f32x4*)&src[i4 * 4];
  f16x4 h = {(f16)v.x, (f16)v.y, (f16)v.z, (f16)v.w};
  *(f16x4*)&dst[i4 * 4] = h;
  f16x4 l = {(f16)(v.x - (float)h[0]), (f16)(v.y - (float)h[1]),
             (f16)(v.z - (float)h[2]), (f16)(v.w - (float)h[3])};
  *(f16x4*)&dst[loOff + i4 * 4] = l;
}

// fp32 -> split-bf16 (hi plane at dst, lo at dst+loOff)
__global__ void cvt_bf_split(const float* __restrict__ src, short* __restrict__ dst, long loOff) {
  const long i4 = (long)blockIdx.x * 256 + threadIdx.x;
  f32x4 v = *(const f32x4*)&src[i4 * 4];
  s16x4 h = { f2bf(v.x), f2bf(v.y), f2bf(v.z), f2bf(v.w) };
  *(s16x4*)&dst[i4 * 4] = h;
  s16x4 l = { f2bf(v.x - bf2f(h.x)), f2bf(v.y - bf2f(h.y)),
              f2bf(v.z - bf2f(h.z)), f2bf(v.w - bf2f(h.w)) };
  *(s16x4*)&dst[loOff + i4 * 4] = l;
}

__global__ void init_cur(const float* __restrict__ node_vec, float* __restrict__ cur,
                         f16* __restrict__ cur_h, long loOff) {
  const long i4 = (long)blockIdx.x * 256 + threadIdx.x;
  f32x4 v = *(const f32x4*)&node_vec[i4 * 4];
  *(f32x4*)&cur[i4 * 4] = v;
  f16x4 h = {(f16)v.x, (f16)v.y, (f16)v.z, (f16)v.w};
  *(f16x4*)&cur_h[i4 * 4] = h;
  f16x4 l = {(f16)(v.x - (float)h[0]), (f16)(v.y - (float)h[1]),
             (f16)(v.z - (float)h[2]), (f16)(v.w - (float)h[3])};
  *(f16x4*)&cur_h[loOff + i4 * 4] = l;
}

// cur [B*N,256] f32 -> cur_hT hi/lo planes [B][256][2048] halves
__global__ void transposeT(const float* __restrict__ cur, f16* __restrict__ curT, long loOff) {
  __shared__ f16 th[64][72];
  __shared__ f16 tl[64][72];
  const int b = blockIdx.z, nt = blockIdx.x * 64, dt = blockIdx.y * 64;
  const int tid = threadIdx.x;
  const int nl = tid >> 2, d0 = (tid & 3) * 16;
  const float* src = cur + ((long)b * Nn + nt + nl) * 256 + dt + d0;
  #pragma unroll
  for (int u = 0; u < 4; u++) {
    f32x4 v = *(const f32x4*)(src + 4 * u);
    f16x4 h = {(f16)v.x, (f16)v.y, (f16)v.z, (f16)v.w};
    *(f16x4*)&th[nl][d0 + 4 * u] = h;
    f16x4 l = {(f16)(v.x - (float)h[0]), (f16)(v.y - (float)h[1]),
               (f16)(v.z - (float)h[2]), (f16)(v.w - (float)h[3])};
    *(f16x4*)&tl[nl][d0 + 4 * u] = l;
  }
  __syncthreads();
  const int dl = tid >> 2, n0l = (tid & 3) * 16;
  f16x8 o0, o1, p0, p1;
  #pragma unroll
  for (int v = 0; v < 8; v++) {
    o0[v] = th[n0l + v][dl];     o1[v] = th[n0l + 8 + v][dl];
    p0[v] = tl[n0l + v][dl];     p1[v] = tl[n0l + 8 + v][dl];
  }
  f16* dst = curT + (long)b * (256 * Nn) + (long)(dt + dl) * Nn + nt + n0l;
  *(f16x8*)dst = o0;
  *(f16x8*)(dst + 8) = o1;
  *(f16x8*)(dst + loOff) = p0;
  *(f16x8*)(dst + loOff + 8) = p1;
}

__global__ void gruf_kernel(const float* __restrict__ urb, const float* __restrict__ m,
                            float* __restrict__ cur, f16* __restrict__ cur_h, long loOff) {
  const long i = (long)blockIdx.x * 256 + threadIdx.x;
  const long bn = i >> 8; const int d = i & 255;
  const float uu = urb[bn * 512 + d];
  const float v = (1.f - uu) * cur[i] + uu * m[i];
  cur[i] = v;
  f16 h = (f16)v;
  cur_h[i] = h;
  cur_h[loOff + i] = (f16)(v - (float)h);
}

__global__ void maxpool1(const float* __restrict__ pooled, float* __restrict__ part) {
  const int d = threadIdx.x, c = blockIdx.x, b = blockIdx.y;
  const float* p = pooled + ((long)b * Nn + c * 256) * Dd + d;
  float m = -INFINITY;
  for (int n = 0; n < 256; n++) m = fmaxf(m, p[(long)n * Dd]);
  part[(b * 8 + c) * Dd + d] = m;
}
__global__ void maxpool2(const float* __restrict__ part, float* __restrict__ out1) {
  const int d = threadIdx.x, b = blockIdx.x;
  float m = -INFINITY;
  #pragma unroll
  for (int c = 0; c < 8; c++) m = fmaxf(m, part[(b * 8 + c) * Dd + d]);
  out1[b * Dd + d] = m;
}
__global__ void transpose_out(const float* __restrict__ cur, float* __restrict__ out0) {
  const long i = (long)blockIdx.x * 256 + threadIdx.x;
  const int d = i & 255;
  const long nb = i >> 8;
  const int b = nb & 7;
  const long n = nb >> 3;
  out0[i] = cur[((long)b * Nn + n) * Dd + d];
}

extern "C" void kernel_launch(void* const* d_in, const int* in_sizes, int n_in,
                              void* d_out, int out_size, void* d_ws, size_t ws_size,
                              hipStream_t stream) {
  const float* node_vec = (const float*)d_in[0];
  const float* edge_vec = (const float*)d_in[1];
  const float* n2e      = (const float*)d_in[2];   // [B,E,N]
  const float* e2n      = (const float*)d_in[3];   // [B,N,E]
  const float* W_fuse   = (const float*)d_in[5];   // [256,512]
  const float* b_fuse   = (const float*)d_in[6];
  const float* W_z      = (const float*)d_in[7];   // [256,1024]
  const float* b_z      = (const float*)d_in[8];
  const float* W_u      = (const float*)d_in[9];
  const float* W_r      = (const float*)d_in[10];
  const float* W_m      = (const float*)d_in[11];
  const float* W_max    = (const float*)d_in[12];  // [256,256]

  const long ND  = (long)Bb * Nn * Dd;   // 4194304
  const long EDb = (long)Ee * Dd;        // 1048576
  const long NDb = (long)Nn * Dd;        // 524288
  const long ED  = (long)Bb * EDb;       // 8388608
  const long ADJb = (long)Ee * Nn;       // 8388608 (per batch)
  const long ADJ = (long)Bb * ADJb;      // 67108864
  const int  BN  = Bb * Nn;

  // ---- arena ----
  char* p = (char*)d_ws;
  auto alloc = [&](size_t bytes) { char* r = p; p += (bytes + 255) & ~(size_t)255; return r; };

  const size_t need_full =
      (size_t)4 * ADJ * 2
      + (size_t)ED * 2
      + (size_t)4 * ED * 2
      + (size_t)ED * 4
      + (size_t)4 * ND * 2
      + (size_t)(2 * 131072 + 2 * 65536) * 2
      + (size_t)(2 * 262144 + 2 * 262144 + 2 * 131072) * 2   // gate weight splits
      + (size_t)5 * ND * 4
      + (size_t)BN * 512 * 4
      + (size_t)(2 * BN + 16 * BN + BN) * 4
      + 64 * 1024;
  const bool full = ws_size >= need_full;

  f16 *adjEO = nullptr, *adjAG = nullptr;
  f16 *n2e_h = nullptr, *e2n_hT = nullptr, *e2n_h = nullptr, *n2e_hT = nullptr;
  if (full) {
    adjEO = (f16*)alloc((size_t)2 * ADJ * 2);
    adjAG = (f16*)alloc((size_t)2 * ADJ * 2);
    n2e_h = adjEO;  e2n_hT = adjEO + ADJ;
    e2n_h = adjAG;  n2e_hT = adjAG + ADJ;
  }
  f16* ev_h    = (f16*)alloc(ED * 2);
  f16* E1h2    = (f16*)alloc((size_t)2 * ED * 2);  // 16 slabs [Ee][256]
  f16* E2T2    = (f16*)alloc((size_t)2 * ED * 2);  // 16 slabs [256][Ee]
  float* EVW   = (float*)alloc(ED * 4);            // 8 slabs [Ee][256] f32
  f16* cur_h   = (f16*)alloc(2 * ND * 2);
  f16* cur_hT  = (f16*)alloc(2 * ND * 2);
  f16* Wf_h    = (f16*)alloc(2 * 131072 * 2);
  f16* Wmax_h  = (f16*)alloc(2 * 65536 * 2);
  short* Wz_s  = (short*)alloc((size_t)2 * 262144 * 2);  // [256][1024] hi+lo
  short* Wur_s = (short*)alloc((size_t)2 * 262144 * 2);  // [512][512] (Wu;Wr) hi+lo
  short* Wm_s  = (short*)alloc((size_t)2 * 131072 * 2);  // [256][512] hi+lo
  float* cur   = (float*)alloc(ND * 4);
  float* outv  = (float*)alloc(2 * ND * 4);        // outv|inv contiguous
  float* inv   = outv + ND;
  float* nv    = (float*)alloc(ND * 4);
  float* urb   = (float*)alloc((size_t)BN * 512 * 4);
  float* mb    = (float*)alloc(ND * 4);
  float* rno   = (float*)alloc(2 * BN * 4);        // rno|rni contiguous
  float* rni   = rno + BN;
  float* colpart = (float*)alloc((size_t)16 * BN * 4);
  float* maxpart = (float*)alloc(BN * 4);

  float* out0 = (float*)d_out;
  float* out1 = out0 + ND;

  // ---- one-time conversions + norms + transposed adjacency caches ----
  if (full) {
    cvt_n2e_colsum<<<dim3(Nn / 256, 16, Bb), 256, 0, stream>>>(n2e, n2e_h, colpart);
    colfin_kernel<<<BN / 256, 256, 0, stream>>>(colpart, rni);
    cvt_e2n_rowsum<<<BN, 256, 0, stream>>>(e2n, e2n_h, rno);
    adjT<<<dim3(Ee / 64, Nn / 64, Bb), 256, 0, stream>>>(n2e_h, n2e_hT, Ee, Nn);
    adjT<<<dim3(Nn / 64, Ee / 64, Bb), 256, 0, stream>>>(e2n_h, e2n_hT, Nn, Ee);
  } else {
    colsum_kernel<<<dim3(Nn / 256, 16, Bb), 256, 0, stream>>>(n2e, colpart);
    colfin_kernel<<<BN / 256, 256, 0, stream>>>(colpart, rni);
    rowsum_kernel<<<BN / 4, 256, 0, stream>>>(e2n, rno);
  }
  cvt_half<<<(int)(ED / 1024), 256, 0, stream>>>(edge_vec, ev_h);
  cvt_half_split<<<131072 / 1024, 256, 0, stream>>>(W_fuse, Wf_h, 131072);
  cvt_half_split<<<65536 / 1024, 256, 0, stream>>>(W_max, Wmax_h, 65536);
  cvt_bf_split<<<262144 / 1024, 256, 0, stream>>>(W_z, Wz_s, 262144);
  cvt_bf_split<<<131072 / 1024, 256, 0, stream>>>(W_u, Wur_s, 262144);
  cvt_bf_split<<<131072 / 1024, 256, 0, stream>>>(W_r, Wur_s + 131072, 262144);
  cvt_bf_split<<<131072 / 1024, 256, 0, stream>>>(W_m, Wm_s, 131072);
  init_cur<<<(int)(ND / 1024), 256, 0, stream>>>(node_vec, cur, cur_h, ND);
  transposeT<<<dim3(Nn / 64, 4, Bb), 256, 0, stream>>>(cur, cur_hT, ND);

  // EVW = ev @ Wf[:,256:]^T + b_fuse  (hop-invariant, K=256, split-B) -> f32
  hgemm<HN, true, 1, EP_BIAS, OF><<<dim3(2, Ee / 64, Bb), 256, 0, stream>>>(
      ev_h, Wf_h + 256, EVW, nullptr, nullptr, b_fuse,
      Ee, 256, 256, 256, 512, 256, EDb, 0, EDb, 0, 0, 0, 131072, 0, 0);

  for (int h = 0; h < HOPS; h++) {
    if (full) {
      // EO1|EI1 = (n2e_h | e2n_hT) @ cur -> E1h2 ; B=cur_hT split, wraps@8
      hgemm<HN, true, 1, EP_NONE, OH><<<dim3(2, Ee / 64, 2 * Bb), 256, 0, stream>>>(
          adjEO, cur_hT, E1h2, nullptr, nullptr, nullptr,
          Ee, 256, Nn, Nn, Nn, 256, ADJb, NDb, EDb, 0, 0, 0, ND, 7, 0);
      // EO2|EI2 = relu(E1 @ Wf1^T + EVW) -> E2T2 (f16-T)
      hgemm<HN, true, 1, EP_ADDRELU, OHT><<<dim3(2, Ee / 64, 2 * Bb), 256, 0, stream>>>(
          E1h2, Wf_h, E2T2, EVW, nullptr, nullptr,
          Ee, 256, 256, 256, 512, Ee, EDb, 0, EDb, EDb, 0, 0, 131072, 0, 7);
      // out|in = ((e2n_h | n2e_hT) @ E2 + cur) * (rno|rni) -> outv|inv
      hgemm<HN, true, 0, EP_AGG, OF><<<dim3(2, Nn / 64, 2 * Bb), 256, 0, stream>>>(
          adjAG, E2T2, outv, cur, rno, nullptr,
          Nn, 256, Ee, Ee, Ee, 256, ADJb, EDb, NDb, NDb, (long)Nn, 0, 0, 15, 7);
    } else {
      hgemm<HN, false, 1, EP_NONE, OH><<<dim3(2, Ee / 64, Bb), 256, 0, stream>>>(
          n2e, cur_hT, E1h2, nullptr, nullptr, nullptr,
          Ee, 256, Nn, Nn, Nn, 256, ADJb, NDb, EDb, 0, 0, 0, ND, 7, 0);
      hgemm<HT, false, 1, EP_NONE, OH><<<dim3(2, Ee / 64, Bb), 256, 0, stream>>>(
          e2n, cur_hT, E1h2 + ED, nullptr, nullptr, nullptr,
          Ee, 256, Nn, Ee, Nn, 256, ADJb, NDb, EDb, 0, 0, 0, ND, 7, 0);
      hgemm<HN, true, 1, EP_ADDRELU, OHT><<<dim3(2, Ee / 64, 2 * Bb), 256, 0, stream>>>(
          E1h2, Wf_h, E2T2, EVW, nullptr, nullptr,
          Ee, 256, 256, 256, 512, Ee, EDb, 0, EDb, EDb, 0, 0, 131072, 0, 7);
      hgemm<HN, false, 0, EP_AGG, OF><<<dim3(2, Nn / 64, Bb), 256, 0, stream>>>(
          e2n, E2T2, outv, cur, rno, nullptr,
          Nn, 256, Ee, Ee, Ee, 256, (long)Nn * Ee, EDb, NDb, NDb, (long)Nn, 0, 0, 15, 7);
      hgemm<HT, false, 0, EP_AGG, OF><<<dim3(2, Nn / 64, Bb), 256, 0, stream>>>(
          n2e, E2T2 + ED, inv, cur, rni, nullptr,
          Nn, 256, Ee, Nn, Ee, 256, (long)Ee * Nn, EDb, NDb, NDb, (long)Nn, 0, 0, 15, 7);
    }
    // gated fusion: nv = (1-z)*inv + z*outv  [split-bf16]
    ggemm<SM_G4, SE_GATE><<<dim3(2, BN / 64, 1), 256, 0, stream>>>(
        inv, outv, nullptr, Wz_s, nv, inv, outv, b_z, 256, 1024, 256, 1024, 256, 262144);
    // u|r = sigmoid(concat(cur,nv) @ [W_u;W_r]^T) -> urb [BN,512]
    ggemm<SM_CN, SE_SIG><<<dim3(4, BN / 64, 1), 256, 0, stream>>>(
        cur, nv, nullptr, Wur_s, urb, nullptr, nullptr, nullptr, 512, 512, 256, 512, 512, 262144);
    // m = tanh(concat(r*cur, nv) @ W_m^T) -> mb
    ggemm<SM_RC, SE_TANH><<<dim3(2, BN / 64, 1), 256, 0, stream>>>(
        urb + 256, cur, nv, Wm_s, mb, nullptr, nullptr, nullptr, 256, 512, 512, 512, 256, 131072);
    // cur = (1-u)*cur + u*m  (+ split halves)
    gruf_kernel<<<(int)(ND / 256), 256, 0, stream>>>(urb, mb, cur, cur_h, ND);
    if (h < HOPS - 1)
      transposeT<<<dim3(Nn / 64, 4, Bb), 256, 0, stream>>>(cur, cur_hT, ND);
  }

  // pooled = cur @ W_max^T -> urb (f32); both operands split
  hgemm<HN, true, 3, EP_NONE, OF><<<dim3(2, BN / 64, 1), 256, 0, stream>>>(
      cur_h, Wmax_h, urb, nullptr, nullptr, nullptr,
      BN, 256, 256, 256, 256, 256, 0, 0, 0, 0, 0, ND, 65536, 0, 0);
  maxpool1<<<dim3(8, Bb), 256, 0, stream>>>(urb, maxpart);
  maxpool2<<<Bb, 256, 0, stream>>>(maxpart, out1);

  transpose_out<<<(int)(ND / 256), 256, 0, stream>>>(cur, out0);
}

// Round 10
// 1688.420 us; speedup vs baseline: 1.9585x; 1.1773x over previous
//
#include <hip/hip_runtime.h>
#include <math.h>

#define Bb 8
#define Nn 2048
#define Ee 4096
#define Dd 256
#define HOPS 3

typedef __attribute__((ext_vector_type(4))) float f32x4;
typedef _Float16 f16;
typedef __attribute__((ext_vector_type(8))) _Float16 f16x8;
typedef __attribute__((ext_vector_type(4))) _Float16 f16x4;
typedef __attribute__((ext_vector_type(8))) short s16x8;
typedef __attribute__((ext_vector_type(4))) short s16x4;

__device__ __forceinline__ short f2bf(float f){
  union{float f; unsigned u;} x; x.f=f;
  unsigned r = (x.u + 0x7fffu + ((x.u>>16)&1u)) >> 16;
  return (short)r;
}
__device__ __forceinline__ float bf2f(short h){
  union{unsigned u; float f;} x; x.u = ((unsigned)(unsigned short)h) << 16; return x.f;
}
// XOR-swizzle on 16B granules within a row-major [R][64] 16-bit LDS tile (T2)
__device__ __forceinline__ int swz(int row, int idx){ return idx ^ ((row & 7) << 3); }

enum { HN=0, HT=1 };                             // hgemm A modes
enum { OF=0, OH=1, OHT=2 };                      // output: f32 / f16 / f16-transposed
enum { EP_NONE=0, EP_BIAS, EP_ADDRELU, EP_AGG }; // hgemm epilogues
enum { SM_CN=0, SM_G4, SM_RC };                  // ggemm A modes
enum { SE_GATE=0, SE_SIG, SE_TANH };             // ggemm epilogues

// -------------- fp16 MFMA GEMM: tile 128x128, BK=64, 8 waves (4x2), 512 thr --------------
// Reg-staged 2-phase; swizzled LDS (48KB @ SPL=1 -> 3 blocks/CU, 24 waves).
template<int AMODE, bool AH, int SPL, int EPI, int OUTM>
__global__ __launch_bounds__(512) void hgemm(
    const void* __restrict__ Av, const f16* __restrict__ Bh, void* __restrict__ Cv,
    const float* __restrict__ aux1, const float* __restrict__ aux2,
    const float* __restrict__ bias,
    int M, int Nd, int K, int lda, int ldb, int ldc,
    long sA, long sB, long sC, long sAux1, long sAux2,
    long aLo, long bLo, int maskB, int mask1)
{
  const int bz = blockIdx.z;
  const char* Ab = (const char*)Av + (AH ? bz * sA * 2 : bz * sA * 4);
  Bh += (long)(bz & maskB) * sB;
  char* Cb = (char*)Cv + ((OUTM == OF) ? bz * sC * 4 : bz * sC * 2);
  if (aux1) aux1 += (long)(bz & mask1) * sAux1;
  if (aux2) aux2 += bz * sAux2;
  const int m0 = blockIdx.y * 128;
  const int n0 = blockIdx.x * 128;

  constexpr int HLA = 128 * 64;
  constexpr int HLB = 128 * 64;
  __shared__ f16 As[128 * 64 * ((SPL & 2) ? 2 : 1)];
  __shared__ f16 Bs[128 * 64 * ((SPL & 1) ? 2 : 1)];

  const int tid = threadIdx.x;
  const int wid = tid >> 6, lane = tid & 63;
  const int wm = (wid >> 1) * 32, wn = (wid & 1) * 64;
  const int r = lane & 15, g = lane >> 4;

  f32x4 acc[2][4];
  #pragma unroll
  for (int i = 0; i < 2; i++)
    #pragma unroll
    for (int j = 0; j < 4; j++) acc[i][j] = (f32x4){0.f, 0.f, 0.f, 0.f};

  f16x8 ra0, ra1, rl0, rl1;   // staged A (16 f16 + lo)
  f16x8 rb0, rb1, rbl0, rbl1; // staged B (16 f16 + lo)

  auto loadA = [&](int k0) {
    if (AMODE == HN && AH) {
      const f16* Ah = (const f16*)Ab;
      const int row = tid >> 2, kc = (tid & 3) * 16;
      const long off = (long)(m0 + row) * lda + k0 + kc;
      ra0 = *(const f16x8*)&Ah[off];
      ra1 = *(const f16x8*)&Ah[off + 8];
      if (SPL & 2) { rl0 = *(const f16x8*)&Ah[aLo + off]; rl1 = *(const f16x8*)&Ah[aLo + off + 8]; }
    } else if (AMODE == HN && !AH) {
      const float* Af = (const float*)Ab;
      const int row = tid >> 2, kc = (tid & 3) * 16;
      const float* s = &Af[(long)(m0 + row) * lda + k0 + kc];
      f32x4 v0 = *(const f32x4*)s,       v1 = *(const f32x4*)(s + 4);
      f32x4 v2 = *(const f32x4*)(s + 8), v3 = *(const f32x4*)(s + 12);
      ra0 = (f16x8){(f16)v0.x,(f16)v0.y,(f16)v0.z,(f16)v0.w,(f16)v1.x,(f16)v1.y,(f16)v1.z,(f16)v1.w};
      ra1 = (f16x8){(f16)v2.x,(f16)v2.y,(f16)v2.z,(f16)v2.w,(f16)v3.x,(f16)v3.y,(f16)v3.z,(f16)v3.w};
    } else { // HT (fallback path)
      const int mm = tid & 127, kh = (tid >> 7) * 16;
      if (AH) {
        const f16* s = &((const f16*)Ab)[(long)(k0 + kh) * lda + m0 + mm];
        #pragma unroll
        for (int j = 0; j < 8; j++) ra0[j] = s[(long)j * lda];
        #pragma unroll
        for (int j = 0; j < 8; j++) ra1[j] = s[(long)(j + 8) * lda];
      } else {
        const float* s = &((const float*)Ab)[(long)(k0 + kh) * lda + m0 + mm];
        #pragma unroll
        for (int j = 0; j < 8; j++) ra0[j] = (f16)s[(long)j * lda];
        #pragma unroll
        for (int j = 0; j < 8; j++) ra1[j] = (f16)s[(long)(j + 8) * lda];
      }
    }
  };
  auto storeA = [&]() {
    if (AMODE == HT) {
      const int mm = tid & 127, kh = (tid >> 7) * 16;
      *(f16x8*)&As[swz(mm, mm * 64 + kh)]     = ra0;
      *(f16x8*)&As[swz(mm, mm * 64 + kh + 8)] = ra1;
    } else {
      const int row = tid >> 2, kc = (tid & 3) * 16;
      const int i0 = swz(row, row * 64 + kc), i1 = swz(row, row * 64 + kc + 8);
      *(f16x8*)&As[i0] = ra0;
      *(f16x8*)&As[i1] = ra1;
      if (SPL & 2) { *(f16x8*)&As[HLA + i0] = rl0; *(f16x8*)&As[HLA + i1] = rl1; }
    }
  };
  auto loadB = [&](int k0) {
    const int row = tid >> 2, kc = (tid & 3) * 16;
    const long off = (long)(n0 + row) * ldb + k0 + kc;
    rb0 = *(const f16x8*)&Bh[off];
    rb1 = *(const f16x8*)&Bh[off + 8];
    if (SPL & 1) { rbl0 = *(const f16x8*)&Bh[bLo + off]; rbl1 = *(const f16x8*)&Bh[bLo + off + 8]; }
  };
  auto storeB = [&]() {
    const int row = tid >> 2, kc = (tid & 3) * 16;
    const int i0 = swz(row, row * 64 + kc), i1 = swz(row, row * 64 + kc + 8);
    *(f16x8*)&Bs[i0] = rb0;
    *(f16x8*)&Bs[i1] = rb1;
    if (SPL & 1) { *(f16x8*)&Bs[HLB + i0] = rbl0; *(f16x8*)&Bs[HLB + i1] = rbl1; }
  };

  loadA(0); loadB(0);
  storeA(); storeB();
  __syncthreads();

  const int NT = K >> 6;
  for (int t = 0; t < NT; t++) {
    const bool more = (t + 1 < NT);
    if (more) { loadA((t + 1) << 6); loadB((t + 1) << 6); }  // issue early
    #pragma unroll
    for (int ks = 0; ks < 2; ks++) {
      f16x8 af[2], bf[4], afl[2], bfl[4];
      #pragma unroll
      for (int i = 0; i < 2; i++) {
        const int rw = wm + i * 16 + r;
        const int ix = swz(rw, rw * 64 + ks * 32 + g * 8);
        af[i] = *(const f16x8*)&As[ix];
        if (SPL & 2) afl[i] = *(const f16x8*)&As[HLA + ix];
      }
      #pragma unroll
      for (int j = 0; j < 4; j++) {
        const int rw = wn + j * 16 + r;
        const int ix = swz(rw, rw * 64 + ks * 32 + g * 8);
        bf[j] = *(const f16x8*)&Bs[ix];
        if (SPL & 1) bfl[j] = *(const f16x8*)&Bs[HLB + ix];
      }
      #pragma unroll
      for (int i = 0; i < 2; i++)
        #pragma unroll
        for (int j = 0; j < 4; j++) {
          acc[i][j] = __builtin_amdgcn_mfma_f32_16x16x32_f16(af[i], bf[j], acc[i][j], 0, 0, 0);
          if (SPL & 1)
            acc[i][j] = __builtin_amdgcn_mfma_f32_16x16x32_f16(af[i], bfl[j], acc[i][j], 0, 0, 0);
          if (SPL & 2)
            acc[i][j] = __builtin_amdgcn_mfma_f32_16x16x32_f16(afl[i], bf[j], acc[i][j], 0, 0, 0);
        }
    }
    __syncthreads();
    if (more) { storeA(); storeB(); __syncthreads(); }
  }

  // ---- epilogue: acc map col=lane&15, row=(lane>>4)*4+t
  if (OUTM == OHT) {
    // two-pass 128x64 transpose through Bs, 64B-contiguous column writes
    f16* tile = (f16*)Bs;   // [128 cols][72 pad] = 18KB, fits
    #pragma unroll
    for (int half = 0; half < 2; half++) {
      __syncthreads();
      if ((wm >> 6) == half) {
        #pragma unroll
        for (int i = 0; i < 2; i++)
          #pragma unroll
          for (int j = 0; j < 4; j++) {
            const int rowl = wm + i * 16 + g * 4 - 64 * half;
            const int coll = wn + j * 16 + r;
            #pragma unroll
            for (int t = 0; t < 4; t++) {
              float v = acc[i][j][t];
              if (EPI == EP_ADDRELU) {
                v += aux1[(long)(m0 + 64 * half + rowl + t) * 256 + n0 + coll];
                v = v > 0.f ? v : 0.f;
              } else if (EPI == EP_BIAS) { v += bias[n0 + coll]; }
              tile[coll * 72 + rowl + t] = (f16)v;
            }
          }
      }
      __syncthreads();
      const int c2 = tid >> 2, rs = (tid & 3) * 16;
      f16* dst = &((f16*)Cb)[(long)(n0 + c2) * ldc + m0 + 64 * half + rs];
      *(f16x8*)dst       = *(const f16x8*)&tile[c2 * 72 + rs];
      *(f16x8*)(dst + 8) = *(const f16x8*)&tile[c2 * 72 + rs + 8];
    }
  } else {
    #pragma unroll
    for (int i = 0; i < 2; i++) {
      #pragma unroll
      for (int j = 0; j < 4; j++) {
        const int rowb = m0 + wm + i * 16 + g * 4;
        const int col = n0 + wn + j * 16 + r;
        #pragma unroll
        for (int t = 0; t < 4; t++) {
          const int row = rowb + t;
          const long idx = (long)row * ldc + col;
          float v = acc[i][j][t];
          if (EPI == EP_BIAS)         { v += bias[col]; }
          else if (EPI == EP_ADDRELU) { v += aux1[(long)row * 256 + col]; v = v > 0.f ? v : 0.f; }
          else if (EPI == EP_AGG)     { v = (v + aux1[idx]) * aux2[row]; }
          if (OUTM == OH) ((f16*)Cb)[idx] = (f16)v;
          else            ((float*)Cb)[idx] = v;
        }
      }
    }
  }
}

// ------------- split-bf16 gate GEMM, reg-staged 2-phase, tile 64x128, BK=64 -------------
// B = pre-split bf16 weight planes (hi at Bw, lo at Bw+bLo). A features split in regs.
template<int AMODE, int EPI>
__global__ __launch_bounds__(256) void ggemm(
    const float* __restrict__ A, const float* __restrict__ A2, const float* __restrict__ A3,
    const short* __restrict__ Bw, float* __restrict__ C,
    const float* __restrict__ aux1, const float* __restrict__ aux2, const float* __restrict__ bias,
    int Nd, int K, int lda, int ldb, int ldc, long bLo)
{
  const int m0 = blockIdx.y * 64;
  const int n0 = blockIdx.x * 128;
  constexpr int HLA = 64 * 64;
  constexpr int HLB = 128 * 64;
  __shared__ short As[64 * 64 * 2];
  __shared__ short Bs[128 * 64 * 2];

  const int tid = threadIdx.x;
  const int wid = tid >> 6, lane = tid & 63;
  const int wm = (wid >> 1) * 32, wn = (wid & 1) * 64;
  const int r = lane & 15, g = lane >> 4;

  f32x4 acc[2][4];
  #pragma unroll
  for (int i = 0; i < 2; i++)
    #pragma unroll
    for (int j = 0; j < 4; j++) acc[i][j] = (f32x4){0.f, 0.f, 0.f, 0.f};

  s16x4 rah[4], ral[4];
  s16x8 rbh[4], rbl[4];

  auto loadA = [&](int k0) {
    const int row = tid >> 2, kc = (tid & 3) * 16;
    const int kk = k0 + kc, q = kk >> 8, kd = kk & 255;
    const long base = (long)(m0 + row) * 256 + kd;
    const long baseA = (long)(m0 + row) * lda + kd;
    #pragma unroll
    for (int u = 0; u < 4; u++) {
      f32x4 v;
      if (AMODE == SM_CN) {
        v = (q == 0) ? *(const f32x4*)(A + base + 4 * u)
                     : *(const f32x4*)(A2 + base + 4 * u);
      } else if (AMODE == SM_G4) {
        if (q == 0)      v = *(const f32x4*)(A  + base + 4 * u);
        else if (q == 1) v = *(const f32x4*)(A2 + base + 4 * u);
        else {
          f32x4 x = *(const f32x4*)(A  + base + 4 * u);
          f32x4 y = *(const f32x4*)(A2 + base + 4 * u);
          v = (q == 2) ? x * y : x - y;
        }
      } else { // SM_RC
        if (q == 0) {
          f32x4 x = *(const f32x4*)(A  + baseA + 4 * u);
          f32x4 y = *(const f32x4*)(A2 + base + 4 * u);
          v = x * y;
        } else v = *(const f32x4*)(A3 + base + 4 * u);
      }
      s16x4 h = { f2bf(v.x), f2bf(v.y), f2bf(v.z), f2bf(v.w) };
      rah[u] = h;
      ral[u] = (s16x4){ f2bf(v.x - bf2f(h.x)), f2bf(v.y - bf2f(h.y)),
                        f2bf(v.z - bf2f(h.z)), f2bf(v.w - bf2f(h.w)) };
    }
  };
  auto storeA = [&]() {
    const int row = tid >> 2, kc = (tid & 3) * 16;
    const int i0 = swz(row, row * 64 + kc), i1 = swz(row, row * 64 + kc + 8);
    *(s16x4*)&As[i0]     = rah[0]; *(s16x4*)&As[i0 + 4] = rah[1];
    *(s16x4*)&As[i1]     = rah[2]; *(s16x4*)&As[i1 + 4] = rah[3];
    *(s16x4*)&As[HLA + i0]     = ral[0]; *(s16x4*)&As[HLA + i0 + 4] = ral[1];
    *(s16x4*)&As[HLA + i1]     = ral[2]; *(s16x4*)&As[HLA + i1 + 4] = ral[3];
  };
  auto loadB = [&](int k0) {
    const int row = tid >> 1, kc = (tid & 1) * 32;
    const long off = (long)(n0 + row) * ldb + k0 + kc;
    #pragma unroll
    for (int u = 0; u < 4; u++) {
      rbh[u] = *(const s16x8*)&Bw[off + 8 * u];
      rbl[u] = *(const s16x8*)&Bw[bLo + off + 8 * u];
    }
  };
  auto storeB = [&]() {
    const int row = tid >> 1, kc = (tid & 1) * 32;
    #pragma unroll
    for (int u = 0; u < 4; u++) {
      const int bx = swz(row, row * 64 + kc + 8 * u);
      *(s16x8*)&Bs[bx] = rbh[u];
      *(s16x8*)&Bs[HLB + bx] = rbl[u];
    }
  };

  loadA(0); loadB(0);
  storeA(); storeB();
  __syncthreads();

  const int NT = K >> 6;
  for (int t = 0; t < NT; t++) {
    const bool more = (t + 1 < NT);
    if (more) { loadA((t + 1) << 6); loadB((t + 1) << 6); }
    #pragma unroll
    for (int ks = 0; ks < 2; ks++) {
      s16x8 ah[2], al[2], bh[4], bl[4];
      #pragma unroll
      for (int i = 0; i < 2; i++) {
        const int rw = wm + i * 16 + r;
        const int ix = swz(rw, rw * 64 + ks * 32 + g * 8);
        ah[i] = *(const s16x8*)&As[ix];
        al[i] = *(const s16x8*)&As[HLA + ix];
      }
      #pragma unroll
      for (int j = 0; j < 4; j++) {
        const int rw = wn + j * 16 + r;
        const int ix = swz(rw, rw * 64 + ks * 32 + g * 8);
        bh[j] = *(const s16x8*)&Bs[ix];
        bl[j] = *(const s16x8*)&Bs[HLB + ix];
      }
      #pragma unroll
      for (int i = 0; i < 2; i++)
        #pragma unroll
        for (int j = 0; j < 4; j++) {
          acc[i][j] = __builtin_amdgcn_mfma_f32_16x16x32_bf16(ah[i], bh[j], acc[i][j], 0, 0, 0);
          acc[i][j] = __builtin_amdgcn_mfma_f32_16x16x32_bf16(ah[i], bl[j], acc[i][j], 0, 0, 0);
          acc[i][j] = __builtin_amdgcn_mfma_f32_16x16x32_bf16(al[i], bh[j], acc[i][j], 0, 0, 0);
        }
    }
    __syncthreads();
    if (more) { storeA(); storeB(); __syncthreads(); }
  }

  #pragma unroll
  for (int i = 0; i < 2; i++) {
    #pragma unroll
    for (int j = 0; j < 4; j++) {
      #pragma unroll
      for (int t = 0; t < 4; t++) {
        const int row = m0 + wm + i * 16 + g * 4 + t;
        const int col = n0 + wn + j * 16 + r;
        float v = acc[i][j][t];
        if (EPI == SE_GATE) {
          v += bias[col];
          float z = 1.f / (1.f + __expf(-v));
          const long ix = (long)row * 256 + col;
          v = (1.f - z) * aux1[ix] + z * aux2[ix];
        } else if (EPI == SE_SIG) {
          v = 1.f / (1.f + __expf(-v));
        } else { // SE_TANH
          v = tanhf(v);
        }
        C[(long)row * ldc + col] = v;
      }
    }
  }
}

// ---------------- small kernels ----------------

__global__ void cvt_n2e_colsum(const float* __restrict__ n2e, f16* __restrict__ n2e_h,
                               float* __restrict__ part) {
  const int n = blockIdx.x * 256 + threadIdx.x;
  const int c = blockIdx.y, b = blockIdx.z;
  const long base = (long)b * Ee * Nn + (long)c * 256 * Nn + n;
  float s = 0.f;
  for (int e = 0; e < 256; e++) {
    float v = n2e[base + (long)e * Nn];
    n2e_h[base + (long)e * Nn] = (f16)v;
    s += v;
  }
  part[((long)b * 16 + c) * Nn + n] = s;
}

__global__ void cvt_e2n_rowsum(const float* __restrict__ e2n, f16* __restrict__ e2n_h,
                               float* __restrict__ rno) {
  const long row = blockIdx.x;
  const int tid = threadIdx.x, lane = tid & 63, wid = tid >> 6;
  const float* p = e2n + row * Ee;
  f16* ph = e2n_h + row * Ee;
  float s = 0.f;
  for (int e = tid; e < Ee; e += 256) { float v = p[e]; ph[e] = (f16)v; s += v; }
  #pragma unroll
  for (int off = 32; off; off >>= 1) s += __shfl_down(s, off);
  __shared__ float wsum[4];
  if (lane == 0) wsum[wid] = s;
  __syncthreads();
  if (tid == 0) rno[row] = 1.f / (1.f + wsum[0] + wsum[1] + wsum[2] + wsum[3]);
}

// f16 [R][C] -> [C][R] transpose, 64x64 LDS tiles
__global__ void adjT(const f16* __restrict__ in, f16* __restrict__ out, int R, int C) {
  __shared__ f16 t[64][72];
  const long boff = (long)blockIdx.z * R * C;
  const int r0 = blockIdx.x * 64, c0 = blockIdx.y * 64;
  const int tid = threadIdx.x;
  const int rl = tid >> 2, cl = (tid & 3) * 16;
  const f16* src = in + boff + (long)(r0 + rl) * C + c0 + cl;
  *(f16x8*)&t[rl][cl]     = *(const f16x8*)src;
  *(f16x8*)&t[rl][cl + 8] = *(const f16x8*)(src + 8);
  __syncthreads();
  const int cl2 = tid >> 2, rl2 = (tid & 3) * 16;
  f16x8 o0, o1;
  #pragma unroll
  for (int v = 0; v < 8; v++) { o0[v] = t[rl2 + v][cl2]; o1[v] = t[rl2 + 8 + v][cl2]; }
  f16* dst = out + boff + (long)(c0 + cl2) * R + r0 + rl2;
  *(f16x8*)dst = o0;
  *(f16x8*)(dst + 8) = o1;
}

__global__ void rowsum_kernel(const float* __restrict__ e2n, float* __restrict__ out) {
  const int gw = blockIdx.x * 4 + (threadIdx.x >> 6);
  const int lane = threadIdx.x & 63;
  const float* p = e2n + (long)gw * Ee;
  float s = 0.f;
  for (int e = lane; e < Ee; e += 64) s += p[e];
  #pragma unroll
  for (int off = 32; off; off >>= 1) s += __shfl_down(s, off);
  if (lane == 0) out[gw] = 1.f / (1.f + s);
}
__global__ void colsum_kernel(const float* __restrict__ n2e, float* __restrict__ part) {
  const int n = blockIdx.x * 256 + threadIdx.x;
  const int c = blockIdx.y, b = blockIdx.z;
  const float* p = n2e + (long)b * Ee * Nn + (long)c * 256 * Nn + n;
  float s = 0.f;
  for (int e = 0; e < 256; e++) s += p[(long)e * Nn];
  part[((long)b * 16 + c) * Nn + n] = s;
}
__global__ void colfin_kernel(const float* __restrict__ part, float* __restrict__ rni) {
  const int i = blockIdx.x * 256 + threadIdx.x;
  const int b = i >> 11, n = i & 2047;
  float s = 0.f;
  #pragma unroll
  for (int c = 0; c < 16; c++) s += part[((long)b * 16 + c) * Nn + n];
  rni[i] = 1.f / (1.f + s);
}

__global__ void cvt_half(const float* __restrict__ src, f16* __restrict__ dst) {
  const long i4 = (long)blockIdx.x * 256 + threadIdx.x;
  f32x4 v = *(const f32x4*)&src[i4 * 4];
  *(f16x4*)&dst[i4 * 4] = (f16x4){(f16)v.x, (f16)v.y, (f16)v.z, (f16)v.w};
}

__global__ void cvt_half_split(const float* __restrict__ src, f16* __restrict__ dst, long loOff) {
  const long i4 = (long)blockIdx.x * 256 + threadIdx.x;
  f32x4 v = *(const f32x4*)&src[i4 * 4];
  f16x4 h = {(f16)v.x, (f16)v.y, (f16)v.z, (f16)v.w};
  *(f16x4*)&dst[i4 * 4] = h;
  f16x4 l = {(f16)(v.x - (float)h[0]), (f16)(v.y - (float)h[1]),
             (f16)(v.z - (float)h[2]), (f16)(v.w - (float)h[3])};
  *(f16x4*)&dst[loOff + i4 * 4] = l;
}

// fp32 -> split-bf16 (hi plane at dst, lo at dst+loOff)
__global__ void cvt_bf_split(const float* __restrict__ src, short* __restrict__ dst, long loOff) {
  const long i4 = (long)blockIdx.x * 256 + threadIdx.x;
  f32x4 v = *(const f32x4*)&src[i4 * 4];
  s16x4 h = { f2bf(v.x), f2bf(v.y), f2bf(v.z), f2bf(v.w) };
  *(s16x4*)&dst[i4 * 4] = h;
  s16x4 l = { f2bf(v.x - bf2f(h.x)), f2bf(v.y - bf2f(h.y)),
              f2bf(v.z - bf2f(h.z)), f2bf(v.w - bf2f(h.w)) };
  *(s16x4*)&dst[loOff + i4 * 4] = l;
}

__global__ void init_cur(const float* __restrict__ node_vec, float* __restrict__ cur,
                         f16* __restrict__ cur_h, long loOff) {
  const long i4 = (long)blockIdx.x * 256 + threadIdx.x;
  f32x4 v = *(const f32x4*)&node_vec[i4 * 4];
  *(f32x4*)&cur[i4 * 4] = v;
  f16x4 h = {(f16)v.x, (f16)v.y, (f16)v.z, (f16)v.w};
  *(f16x4*)&cur_h[i4 * 4] = h;
  f16x4 l = {(f16)(v.x - (float)h[0]), (f16)(v.y - (float)h[1]),
             (f16)(v.z - (float)h[2]), (f16)(v.w - (float)h[3])};
  *(f16x4*)&cur_h[loOff + i4 * 4] = l;
}

// cur [B*N,256] f32 -> cur_hT hi/lo planes [B][256][2048] halves
__global__ void transposeT(const float* __restrict__ cur, f16* __restrict__ curT, long loOff) {
  __shared__ f16 th[64][72];
  __shared__ f16 tl[64][72];
  const int b = blockIdx.z, nt = blockIdx.x * 64, dt = blockIdx.y * 64;
  const int tid = threadIdx.x;
  const int nl = tid >> 2, d0 = (tid & 3) * 16;
  const float* src = cur + ((long)b * Nn + nt + nl) * 256 + dt + d0;
  #pragma unroll
  for (int u = 0; u < 4; u++) {
    f32x4 v = *(const f32x4*)(src + 4 * u);
    f16x4 h = {(f16)v.x, (f16)v.y, (f16)v.z, (f16)v.w};
    *(f16x4*)&th[nl][d0 + 4 * u] = h;
    f16x4 l = {(f16)(v.x - (float)h[0]), (f16)(v.y - (float)h[1]),
               (f16)(v.z - (float)h[2]), (f16)(v.w - (float)h[3])};
    *(f16x4*)&tl[nl][d0 + 4 * u] = l;
  }
  __syncthreads();
  const int dl = tid >> 2, n0l = (tid & 3) * 16;
  f16x8 o0, o1, p0, p1;
  #pragma unroll
  for (int v = 0; v < 8; v++) {
    o0[v] = th[n0l + v][dl];     o1[v] = th[n0l + 8 + v][dl];
    p0[v] = tl[n0l + v][dl];     p1[v] = tl[n0l + 8 + v][dl];
  }
  f16* dst = curT + (long)b * (256 * Nn) + (long)(dt + dl) * Nn + nt + n0l;
  *(f16x8*)dst = o0;
  *(f16x8*)(dst + 8) = o1;
  *(f16x8*)(dst + loOff) = p0;
  *(f16x8*)(dst + loOff + 8) = p1;
}

__global__ void gruf_kernel(const float* __restrict__ urb, const float* __restrict__ m,
                            float* __restrict__ cur, f16* __restrict__ cur_h, long loOff) {
  const long i = (long)blockIdx.x * 256 + threadIdx.x;
  const long bn = i >> 8; const int d = i & 255;
  const float uu = urb[bn * 512 + d];
  const float v = (1.f - uu) * cur[i] + uu * m[i];
  cur[i] = v;
  f16 h = (f16)v;
  cur_h[i] = h;
  cur_h[loOff + i] = (f16)(v - (float)h);
}

__global__ void maxpool1(const float* __restrict__ pooled, float* __restrict__ part) {
  const int d = threadIdx.x, c = blockIdx.x, b = blockIdx.y;
  const float* p = pooled + ((long)b * Nn + c * 256) * Dd + d;
  float m = -INFINITY;
  for (int n = 0; n < 256; n++) m = fmaxf(m, p[(long)n * Dd]);
  part[(b * 8 + c) * Dd + d] = m;
}
__global__ void maxpool2(const float* __restrict__ part, float* __restrict__ out1) {
  const int d = threadIdx.x, b = blockIdx.x;
  float m = -INFINITY;
  #pragma unroll
  for (int c = 0; c < 8; c++) m = fmaxf(m, part[(b * 8 + c) * Dd + d]);
  out1[b * Dd + d] = m;
}
__global__ void transpose_out(const float* __restrict__ cur, float* __restrict__ out0) {
  const long i = (long)blockIdx.x * 256 + threadIdx.x;
  const int d = i & 255;
  const long nb = i >> 8;
  const int b = nb & 7;
  const long n = nb >> 3;
  out0[i] = cur[((long)b * Nn + n) * Dd + d];
}

extern "C" void kernel_launch(void* const* d_in, const int* in_sizes, int n_in,
                              void* d_out, int out_size, void* d_ws, size_t ws_size,
                              hipStream_t stream) {
  const float* node_vec = (const float*)d_in[0];
  const float* edge_vec = (const float*)d_in[1];
  const float* n2e      = (const float*)d_in[2];   // [B,E,N]
  const float* e2n      = (const float*)d_in[3];   // [B,N,E]
  const float* W_fuse   = (const float*)d_in[5];   // [256,512]
  const float* b_fuse   = (const float*)d_in[6];
  const float* W_z      = (const float*)d_in[7];   // [256,1024]
  const float* b_z      = (const float*)d_in[8];
  const float* W_u      = (const float*)d_in[9];
  const float* W_r      = (const float*)d_in[10];
  const float* W_m      = (const float*)d_in[11];
  const float* W_max    = (const float*)d_in[12];  // [256,256]

  const long ND  = (long)Bb * Nn * Dd;   // 4194304
  const long EDb = (long)Ee * Dd;        // 1048576
  const long NDb = (long)Nn * Dd;        // 524288
  const long ED  = (long)Bb * EDb;       // 8388608
  const long ADJb = (long)Ee * Nn;       // 8388608 (per batch)
  const long ADJ = (long)Bb * ADJb;      // 67108864
  const int  BN  = Bb * Nn;

  // ---- arena ----
  char* p = (char*)d_ws;
  auto alloc = [&](size_t bytes) { char* r = p; p += (bytes + 255) & ~(size_t)255; return r; };

  const size_t need_full =
      (size_t)4 * ADJ * 2
      + (size_t)ED * 2
      + (size_t)4 * ED * 2
      + (size_t)ED * 4
      + (size_t)4 * ND * 2
      + (size_t)(2 * 131072 + 2 * 65536) * 2
      + (size_t)(2 * 262144 + 2 * 262144 + 2 * 131072) * 2
      + (size_t)5 * ND * 4
      + (size_t)BN * 512 * 4
      + (size_t)(2 * BN + 16 * BN + BN) * 4
      + 64 * 1024;
  const bool full = ws_size >= need_full;

  f16 *adjEO = nullptr, *adjAG = nullptr;
  f16 *n2e_h = nullptr, *e2n_hT = nullptr, *e2n_h = nullptr, *n2e_hT = nullptr;
  if (full) {
    adjEO = (f16*)alloc((size_t)2 * ADJ * 2);
    adjAG = (f16*)alloc((size_t)2 * ADJ * 2);
    n2e_h = adjEO;  e2n_hT = adjEO + ADJ;
    e2n_h = adjAG;  n2e_hT = adjAG + ADJ;
  }
  f16* ev_h    = (f16*)alloc(ED * 2);
  f16* E1h2    = (f16*)alloc((size_t)2 * ED * 2);  // 16 slabs [Ee][256]
  f16* E2T2    = (f16*)alloc((size_t)2 * ED * 2);  // 16 slabs [256][Ee]
  float* EVW   = (float*)alloc(ED * 4);            // 8 slabs [Ee][256] f32
  f16* cur_h   = (f16*)alloc(2 * ND * 2);
  f16* cur_hT  = (f16*)alloc(2 * ND * 2);
  f16* Wf_h    = (f16*)alloc(2 * 131072 * 2);
  f16* Wmax_h  = (f16*)alloc(2 * 65536 * 2);
  short* Wz_s  = (short*)alloc((size_t)2 * 262144 * 2);  // [256][1024] hi+lo
  short* Wur_s = (short*)alloc((size_t)2 * 262144 * 2);  // [512][512] (Wu;Wr) hi+lo
  short* Wm_s  = (short*)alloc((size_t)2 * 131072 * 2);  // [256][512] hi+lo
  float* cur   = (float*)alloc(ND * 4);
  float* outv  = (float*)alloc(2 * ND * 4);        // outv|inv contiguous
  float* inv   = outv + ND;
  float* nv    = (float*)alloc(ND * 4);
  float* urb   = (float*)alloc((size_t)BN * 512 * 4);
  float* mb    = (float*)alloc(ND * 4);
  float* rno   = (float*)alloc(2 * BN * 4);        // rno|rni contiguous
  float* rni   = rno + BN;
  float* colpart = (float*)alloc((size_t)16 * BN * 4);
  float* maxpart = (float*)alloc(BN * 4);

  float* out0 = (float*)d_out;
  float* out1 = out0 + ND;

  // ---- one-time conversions + norms + transposed adjacency caches ----
  if (full) {
    cvt_n2e_colsum<<<dim3(Nn / 256, 16, Bb), 256, 0, stream>>>(n2e, n2e_h, colpart);
    colfin_kernel<<<BN / 256, 256, 0, stream>>>(colpart, rni);
    cvt_e2n_rowsum<<<BN, 256, 0, stream>>>(e2n, e2n_h, rno);
    adjT<<<dim3(Ee / 64, Nn / 64, Bb), 256, 0, stream>>>(n2e_h, n2e_hT, Ee, Nn);
    adjT<<<dim3(Nn / 64, Ee / 64, Bb), 256, 0, stream>>>(e2n_h, e2n_hT, Nn, Ee);
  } else {
    colsum_kernel<<<dim3(Nn / 256, 16, Bb), 256, 0, stream>>>(n2e, colpart);
    colfin_kernel<<<BN / 256, 256, 0, stream>>>(colpart, rni);
    rowsum_kernel<<<BN / 4, 256, 0, stream>>>(e2n, rno);
  }
  cvt_half<<<(int)(ED / 1024), 256, 0, stream>>>(edge_vec, ev_h);
  cvt_half_split<<<131072 / 1024, 256, 0, stream>>>(W_fuse, Wf_h, 131072);
  cvt_half_split<<<65536 / 1024, 256, 0, stream>>>(W_max, Wmax_h, 65536);
  cvt_bf_split<<<262144 / 1024, 256, 0, stream>>>(W_z, Wz_s, 262144);
  cvt_bf_split<<<131072 / 1024, 256, 0, stream>>>(W_u, Wur_s, 262144);
  cvt_bf_split<<<131072 / 1024, 256, 0, stream>>>(W_r, Wur_s + 131072, 262144);
  cvt_bf_split<<<131072 / 1024, 256, 0, stream>>>(W_m, Wm_s, 131072);
  init_cur<<<(int)(ND / 1024), 256, 0, stream>>>(node_vec, cur, cur_h, ND);
  transposeT<<<dim3(Nn / 64, 4, Bb), 256, 0, stream>>>(cur, cur_hT, ND);

  // EVW = ev @ Wf[:,256:]^T + b_fuse  (hop-invariant, K=256, split-B) -> f32
  hgemm<HN, true, 1, EP_BIAS, OF><<<dim3(2, Ee / 128, Bb), 512, 0, stream>>>(
      ev_h, Wf_h + 256, EVW, nullptr, nullptr, b_fuse,
      Ee, 256, 256, 256, 512, 256, EDb, 0, EDb, 0, 0, 0, 131072, 0, 0);

  for (int h = 0; h < HOPS; h++) {
    if (full) {
      // EO1|EI1 = (n2e_h | e2n_hT) @ cur -> E1h2 ; B=cur_hT split, wraps@8
      hgemm<HN, true, 1, EP_NONE, OH><<<dim3(2, Ee / 128, 2 * Bb), 512, 0, stream>>>(
          adjEO, cur_hT, E1h2, nullptr, nullptr, nullptr,
          Ee, 256, Nn, Nn, Nn, 256, ADJb, NDb, EDb, 0, 0, 0, ND, 7, 0);
      // EO2|EI2 = relu(E1 @ Wf1^T + EVW) -> E2T2 (f16-T)
      hgemm<HN, true, 1, EP_ADDRELU, OHT><<<dim3(2, Ee / 128, 2 * Bb), 512, 0, stream>>>(
          E1h2, Wf_h, E2T2, EVW, nullptr, nullptr,
          Ee, 256, 256, 256, 512, Ee, EDb, 0, EDb, EDb, 0, 0, 131072, 0, 7);
      // out|in = ((e2n_h | n2e_hT) @ E2 + cur) * (rno|rni) -> outv|inv
      hgemm<HN, true, 0, EP_AGG, OF><<<dim3(2, Nn / 128, 2 * Bb), 512, 0, stream>>>(
          adjAG, E2T2, outv, cur, rno, nullptr,
          Nn, 256, Ee, Ee, Ee, 256, ADJb, EDb, NDb, NDb, (long)Nn, 0, 0, 15, 7);
    } else {
      hgemm<HN, false, 1, EP_NONE, OH><<<dim3(2, Ee / 128, Bb), 512, 0, stream>>>(
          n2e, cur_hT, E1h2, nullptr, nullptr, nullptr,
          Ee, 256, Nn, Nn, Nn, 256, ADJb, NDb, EDb, 0, 0, 0, ND, 7, 0);
      hgemm<HT, false, 1, EP_NONE, OH><<<dim3(2, Ee / 128, Bb), 512, 0, stream>>>(
          e2n, cur_hT, E1h2 + ED, nullptr, nullptr, nullptr,
          Ee, 256, Nn, Ee, Nn, 256, ADJb, NDb, EDb, 0, 0, 0, ND, 7, 0);
      hgemm<HN, true, 1, EP_ADDRELU, OHT><<<dim3(2, Ee / 128, 2 * Bb), 512, 0, stream>>>(
          E1h2, Wf_h, E2T2, EVW, nullptr, nullptr,
          Ee, 256, 256, 256, 512, Ee, EDb, 0, EDb, EDb, 0, 0, 131072, 0, 7);
      hgemm<HN, false, 0, EP_AGG, OF><<<dim3(2, Nn / 128, Bb), 512, 0, stream>>>(
          e2n, E2T2, outv, cur, rno, nullptr,
          Nn, 256, Ee, Ee, Ee, 256, (long)Nn * Ee, EDb, NDb, NDb, (long)Nn, 0, 0, 15, 7);
      hgemm<HT, false, 0, EP_AGG, OF><<<dim3(2, Nn / 128, Bb), 512, 0, stream>>>(
          n2e, E2T2 + ED, inv, cur, rni, nullptr,
          Nn, 256, Ee, Nn, Ee, 256, (long)Ee * Nn, EDb, NDb, NDb, (long)Nn, 0, 0, 15, 7);
    }
    // gated fusion: nv = (1-z)*inv + z*outv  [split-bf16]
    ggemm<SM_G4, SE_GATE><<<dim3(2, BN / 64, 1), 256, 0, stream>>>(
        inv, outv, nullptr, Wz_s, nv, inv, outv, b_z, 256, 1024, 256, 1024, 256, 262144);
    // u|r = sigmoid(concat(cur,nv) @ [W_u;W_r]^T) -> urb [BN,512]
    ggemm<SM_CN, SE_SIG><<<dim3(4, BN / 64, 1), 256, 0, stream>>>(
        cur, nv, nullptr, Wur_s, urb, nullptr, nullptr, nullptr, 512, 512, 256, 512, 512, 262144);
    // m = tanh(concat(r*cur, nv) @ W_m^T) -> mb
    ggemm<SM_RC, SE_TANH><<<dim3(2, BN / 64, 1), 256, 0, stream>>>(
        urb + 256, cur, nv, Wm_s, mb, nullptr, nullptr, nullptr, 256, 512, 512, 512, 256, 131072);
    // cur = (1-u)*cur + u*m  (+ split halves)
    gruf_kernel<<<(int)(ND / 256), 256, 0, stream>>>(urb, mb, cur, cur_h, ND);
    if (h < HOPS - 1)
      transposeT<<<dim3(Nn / 64, 4, Bb), 256, 0, stream>>>(cur, cur_hT, ND);
  }

  // pooled = cur @ W_max^T -> urb (f32); both operands split
  hgemm<HN, true, 3, EP_NONE, OF><<<dim3(2, BN / 128, 1), 512, 0, stream>>>(
      cur_h, Wmax_h, urb, nullptr, nullptr, nullptr,
      BN, 256, 256, 256, 256, 256, 0, 0, 0, 0, 0, ND, 65536, 0, 0);
  maxpool1<<<dim3(8, Bb), 256, 0, stream>>>(urb, maxpart);
  maxpool2<<<Bb, 256, 0, stream>>>(maxpart, out1);

  transpose_out<<<(int)(ND / 256), 256, 0, stream>>>(cur, out0);
}